// Round 2
// baseline (6979.636 us; speedup 1.0000x reference)
//
#include <hip/hip_runtime.h>
#include <math.h>

#define D_IN 63
#define D_MODEL 256
#define N_CLS 14
#define NL 4
#define D_INNER 512
#define D_STATE 128
#define NH 8
#define HP 64
#define DCONV 4
#define CONV_CH 768
#define PROJ 1288
#define XBCDT 776      /* CONV_CH + NH columns of the in-proj */
#define EPS 1e-5f
#define BSZ 32
#define LSEQ 1024
#define NTOK (BSZ*LSEQ)

__device__ __forceinline__ float silu_f(float x) { return x / (1.f + expf(-x)); }

// two-value block reduction (blockDim == 256)
__device__ __forceinline__ float2 block_reduce2(float a, float b, float* sred) {
    #pragma unroll
    for (int off = 32; off >= 1; off >>= 1) {
        a += __shfl_xor(a, off);
        b += __shfl_xor(b, off);
    }
    int wid = threadIdx.x >> 6, lane = threadIdx.x & 63;
    if (lane == 0) { sred[wid * 2] = a; sred[wid * 2 + 1] = b; }
    __syncthreads();
    a = sred[0] + sred[2] + sred[4] + sred[6];
    b = sred[1] + sred[3] + sred[5] + sred[7];
    __syncthreads();
    return make_float2(a, b);
}

// ---------------- K0: h = LN(x @ in_w.T + in_b) ----------------
__global__ __launch_bounds__(256)
void k_in_ln(const float* __restrict__ x, const float* __restrict__ w,
             const float* __restrict__ bias, const float* __restrict__ gw,
             const float* __restrict__ gb, float* __restrict__ h) {
    int m = blockIdx.x;
    int o = threadIdx.x;
    __shared__ float sx[D_IN];
    __shared__ float sred[8];
    if (o < D_IN) sx[o] = x[(size_t)m * D_IN + o];
    __syncthreads();
    float acc = bias[o];
    const float* wr = w + (size_t)o * D_IN;
    #pragma unroll 7
    for (int k = 0; k < D_IN; k++) acc = fmaf(sx[k], wr[k], acc);
    float2 s = block_reduce2(acc, acc * acc, sred);
    float mu = s.x * (1.f / D_MODEL);
    float var = s.y * (1.f / D_MODEL) - mu * mu;
    float r = rsqrtf(var + EPS);
    h[(size_t)m * D_MODEL + o] = (acc - mu) * r * gw[o] + gb[o];
}

// ---------------- tiled fp32 GEMM: C[m,n] = sum_k A[m,k] * B[n,k] ----------------
#define BM 64
#define BN 64
#define BK 16
__global__ __launch_bounds__(256)
void k_gemm_nt(const float* __restrict__ A, const float* __restrict__ B,
               float* __restrict__ C, int M, int N, int K) {
    __shared__ __align__(16) float As[BK][BM];
    __shared__ __align__(16) float Bs[BK][BN];
    int n0 = blockIdx.x * BN;
    int m0 = blockIdx.y * BM;
    int tid = threadIdx.x;
    int lr = tid >> 2;        // 0..63
    int lc = tid & 3;         // float4 slot in a BK row
    int tx = tid & 15, ty = tid >> 4;
    float acc[4][4] = {};
    const float* Ap = A + (size_t)(m0 + lr) * K + lc * 4;
    const float* Bp = B + (size_t)(n0 + lr) * K + lc * 4;
    bool bvalid = (n0 + lr) < N;
    for (int k0 = 0; k0 < K; k0 += BK) {
        float4 a4 = *(const float4*)(Ap + k0);
        float4 b4 = bvalid ? *(const float4*)(Bp + k0) : make_float4(0.f, 0.f, 0.f, 0.f);
        __syncthreads();
        As[lc * 4 + 0][lr] = a4.x; As[lc * 4 + 1][lr] = a4.y;
        As[lc * 4 + 2][lr] = a4.z; As[lc * 4 + 3][lr] = a4.w;
        Bs[lc * 4 + 0][lr] = b4.x; Bs[lc * 4 + 1][lr] = b4.y;
        Bs[lc * 4 + 2][lr] = b4.z; Bs[lc * 4 + 3][lr] = b4.w;
        __syncthreads();
        #pragma unroll
        for (int kk = 0; kk < BK; kk++) {
            float av[4], bv[4];
            *(float4*)av = *(const float4*)&As[kk][ty * 4];
            *(float4*)bv = *(const float4*)&Bs[kk][tx * 4];
            #pragma unroll
            for (int i = 0; i < 4; i++)
                #pragma unroll
                for (int j = 0; j < 4; j++)
                    acc[i][j] = fmaf(av[i], bv[j], acc[i][j]);
        }
    }
    int cn = n0 + tx * 4;
    #pragma unroll
    for (int i = 0; i < 4; i++) {
        size_t row = (size_t)(m0 + ty * 4 + i) * N;
        if (cn + 3 < N) {
            float4 v = make_float4(acc[i][0], acc[i][1], acc[i][2], acc[i][3]);
            *(float4*)&C[row + cn] = v;
        } else {
            #pragma unroll
            for (int j = 0; j < 4; j++)
                if (cn + j < N) C[row + cn + j] = acc[i][j];
        }
    }
}

// ---------------- conv (causal depthwise k=4) + silu + dt/dA ----------------
// xbc: NTOK x XBCDT rows = [xBC raw (768) | dt raw (8)]
__global__ __launch_bounds__(256)
void k_conv(const float* __restrict__ xbc, const float* __restrict__ cw,
            const float* __restrict__ cb, const float* __restrict__ dtb,
            const float* __restrict__ Alog, float* __restrict__ xs,
            float* __restrict__ Bm, float* __restrict__ Cm,
            float* __restrict__ dtv, float* __restrict__ dAv) {
    int m = blockIdx.x;
    int l = m & (LSEQ - 1);
    int tid = threadIdx.x;
    #pragma unroll
    for (int it = 0; it < 3; it++) {
        int c = tid + it * 256;
        float acc = cb[c];
        #pragma unroll
        for (int k = 0; k < DCONV; k++) {
            int lp = l - (DCONV - 1) + k;
            if (lp >= 0)
                acc = fmaf(cw[k * CONV_CH + c],
                           xbc[(size_t)(m - (DCONV - 1) + k) * XBCDT + c], acc);
        }
        float v = silu_f(acc);
        if (c < D_INNER) xs[(size_t)m * D_INNER + c] = v;
        else if (c < D_INNER + D_STATE) Bm[(size_t)m * D_STATE + (c - D_INNER)] = v;
        else Cm[(size_t)m * D_STATE + (c - D_INNER - D_STATE)] = v;
    }
    if (tid < NH) {
        float draw = xbc[(size_t)m * XBCDT + CONV_CH + tid] + dtb[tid];
        float dt = draw > 20.f ? draw : log1pf(expf(draw));
        float A = -expf(Alog[tid]);
        dtv[m * NH + tid] = dt;
        dAv[m * NH + tid] = expf(dt * A);
    }
}

// ---------------- sequential SSM scan, one block per (b,h) ----------------
#define CT 8
__global__ __launch_bounds__(256)
void k_scan(const float* __restrict__ xs, const float* __restrict__ Bm,
            const float* __restrict__ Cm, const float* __restrict__ dtv,
            const float* __restrict__ dAv, const float* __restrict__ Dvec,
            float* __restrict__ y) {
    int bh = blockIdx.x;
    int b = bh >> 3, hh = bh & 7;
    int tid = threadIdx.x;
    int p = tid >> 2, q = tid & 3, n0 = q * 32;
    __shared__ __align__(16) float sB[CT][D_STATE];
    __shared__ __align__(16) float sC[CT][D_STATE];
    __shared__ __align__(16) float sX[CT][HP];
    __shared__ __align__(16) float sY[CT][HP];
    __shared__ float sdt[CT], sdA[CT];
    float hst[32];
    #pragma unroll
    for (int i = 0; i < 32; i++) hst[i] = 0.f;
    float Dh = Dvec[hh];
    const size_t base = (size_t)b * LSEQ;
    for (int c = 0; c < LSEQ / CT; c++) {
        #pragma unroll
        for (int s = 0; s < CT; s++) {
            size_t m = base + c * CT + s;
            if (tid < 128) sB[s][tid] = Bm[m * D_STATE + tid];
            else sC[s][tid - 128] = Cm[m * D_STATE + (tid - 128)];
            if (tid < 64) sX[s][tid] = xs[m * D_INNER + hh * HP + tid];
            else if (tid == 64) sdt[s] = dtv[m * NH + hh];
            else if (tid == 65) sdA[s] = dAv[m * NH + hh];
        }
        __syncthreads();
        #pragma unroll 1
        for (int s = 0; s < CT; s++) {
            float dtl = sdt[s], dAl = sdA[s];
            float xv = sX[s][p];
            float tmp = dtl * xv;
            const float4* B4 = (const float4*)&sB[s][n0];
            const float4* C4 = (const float4*)&sC[s][n0];
            float yp = 0.f;
            #pragma unroll
            for (int i = 0; i < 8; i++) {
                float4 bv = B4[i], cv = C4[i];
                hst[4*i+0] = fmaf(hst[4*i+0], dAl, tmp * bv.x); yp = fmaf(hst[4*i+0], cv.x, yp);
                hst[4*i+1] = fmaf(hst[4*i+1], dAl, tmp * bv.y); yp = fmaf(hst[4*i+1], cv.y, yp);
                hst[4*i+2] = fmaf(hst[4*i+2], dAl, tmp * bv.z); yp = fmaf(hst[4*i+2], cv.z, yp);
                hst[4*i+3] = fmaf(hst[4*i+3], dAl, tmp * bv.w); yp = fmaf(hst[4*i+3], cv.w, yp);
            }
            yp += __shfl_xor(yp, 1);
            yp += __shfl_xor(yp, 2);
            if (q == 0) sY[s][p] = fmaf(Dh, xv, yp);
        }
        __syncthreads();
        for (int i = tid; i < CT * HP; i += 256) {
            int s = i >> 6, pp = i & 63;
            y[(base + c * CT + s) * D_INNER + hh * HP + pp] = sY[s][pp];
        }
        __syncthreads();
    }
}

// ---------------- gated RMSNorm (in-place on y); z has row stride D_INNER ----------------
__global__ __launch_bounds__(256)
void k_gate(float* __restrict__ y, const float* __restrict__ zbuf,
            const float* __restrict__ nw) {
    int m = blockIdx.x, tid = threadIdx.x;
    __shared__ float sred[8];
    float g[2];
    #pragma unroll
    for (int j = 0; j < 2; j++) {
        int d = tid + j * 256;
        float z = zbuf[(size_t)m * D_INNER + d];
        g[j] = y[(size_t)m * D_INNER + d] * silu_f(z);
    }
    float2 s = block_reduce2(g[0] * g[0] + g[1] * g[1], 0.f, sred);
    float r = rsqrtf(s.x * (1.f / D_INNER) + EPS);
    #pragma unroll
    for (int j = 0; j < 2; j++) {
        int d = tid + j * 256;
        y[(size_t)m * D_INNER + d] = g[j] * r * nw[d];
    }
}

// ---------------- h = LN(mo + h) ----------------
__global__ __launch_bounds__(256)
void k_addln(const float* __restrict__ mo, float* __restrict__ h,
             const float* __restrict__ w, const float* __restrict__ bias) {
    int m = blockIdx.x, o = threadIdx.x;
    __shared__ float sred[8];
    float v = mo[(size_t)m * D_MODEL + o] + h[(size_t)m * D_MODEL + o];
    float2 s = block_reduce2(v, v * v, sred);
    float mu = s.x * (1.f / D_MODEL);
    float var = s.y * (1.f / D_MODEL) - mu * mu;
    h[(size_t)m * D_MODEL + o] = (v - mu) * rsqrtf(var + EPS) * w[o] + bias[o];
}

// ---------------- masked mean pool + head ----------------
__global__ __launch_bounds__(256)
void k_pool_head(const float* __restrict__ h, const int* __restrict__ len,
                 const float* __restrict__ hw, const float* __restrict__ hb,
                 float* __restrict__ out) {
    int b = blockIdx.x, d = threadIdx.x;
    __shared__ float sp[D_MODEL];
    int Lb = len[b];
    float acc = 0.f;
    for (int l = 0; l < Lb; l++) acc += h[((size_t)b * LSEQ + l) * D_MODEL + d];
    sp[d] = acc / (float)Lb;
    __syncthreads();
    if (d < N_CLS) {
        float o = hb[d];
        const float* wr = hw + (size_t)d * D_MODEL;
        #pragma unroll 8
        for (int k = 0; k < D_MODEL; k++) o = fmaf(sp[k], wr[k], o);
        out[b * N_CLS + d] = o;
    }
}

extern "C" void kernel_launch(void* const* d_in, const int* in_sizes, int n_in,
                              void* d_out, int out_size, void* d_ws, size_t ws_size,
                              hipStream_t stream) {
    const float* x      = (const float*)d_in[0];
    const float* in_w   = (const float*)d_in[1];
    const float* in_b   = (const float*)d_in[2];
    const float* lnin_w = (const float*)d_in[3];
    const float* lnin_b = (const float*)d_in[4];
    const float* inproj = (const float*)d_in[5];
    const float* conv_w = (const float*)d_in[6];
    const float* conv_b = (const float*)d_in[7];
    const float* dt_bias= (const float*)d_in[8];
    const float* A_log  = (const float*)d_in[9];
    const float* Dv     = (const float*)d_in[10];
    const float* norm_w = (const float*)d_in[11];
    const float* outp_w = (const float*)d_in[12];
    const float* ln_w   = (const float*)d_in[13];
    const float* ln_b   = (const float*)d_in[14];
    const float* head_w = (const float*)d_in[15];
    const float* head_b = (const float*)d_in[16];
    const int*   lengths= (const int*)d_in[17];
    float* out = (float*)d_out;

    // Workspace layout (floats/token): h 256 | buf1 776 | buf2 784  => 238 MB total
    float* ws   = (float*)d_ws;
    float* h    = ws;                               // NTOK*256
    float* buf1 = h    + (size_t)NTOK * D_MODEL;    // NTOK*776: xBC+dt raw, later reused for z
    float* xs   = buf1 + (size_t)NTOK * XBCDT;      // NTOK*512 (y written in-place)
    float* Bm   = xs   + (size_t)NTOK * D_INNER;    // NTOK*128
    float* Cm   = Bm   + (size_t)NTOK * D_STATE;    // NTOK*128
    float* dtv  = Cm   + (size_t)NTOK * D_STATE;    // NTOK*8
    float* dAv  = dtv  + (size_t)NTOK * NH;         // NTOK*8
    float* zbuf = buf1; // z (NTOK*512) overwrites dead raw-xBC region after conv
    float* mo   = Bm;   // out-proj result (NTOK*256) overwrites dead Bm+Cm after scan

    k_in_ln<<<NTOK, 256, 0, stream>>>(x, in_w, in_b, lnin_w, lnin_b, h);

    for (int i = 0; i < NL; i++) {
        const float* W = inproj + (size_t)i * PROJ * D_MODEL;
        // 1a: xBC + dt columns (rows 512..1287 of W)
        dim3 g1a((XBCDT + BN - 1) / BN, NTOK / BM);
        k_gemm_nt<<<g1a, 256, 0, stream>>>(h, W + (size_t)D_INNER * D_MODEL,
                                           buf1, NTOK, XBCDT, D_MODEL);
        k_conv<<<NTOK, 256, 0, stream>>>(buf1, conv_w + i * DCONV * CONV_CH,
                                         conv_b + i * CONV_CH, dt_bias + i * NH,
                                         A_log + i * NH, xs, Bm, Cm, dtv, dAv);
        // 1b: z columns (rows 0..511 of W) — reuses buf1 (raw xBC now dead)
        dim3 g1b(D_INNER / BN, NTOK / BM);
        k_gemm_nt<<<g1b, 256, 0, stream>>>(h, W, zbuf, NTOK, D_INNER, D_MODEL);
        k_scan<<<BSZ * NH, 256, 0, stream>>>(xs, Bm, Cm, dtv, dAv, Dv + i * NH, xs);
        k_gate<<<NTOK, 256, 0, stream>>>(xs, zbuf, norm_w + i * D_INNER);
        dim3 g2(D_MODEL / BN, NTOK / BM);
        k_gemm_nt<<<g2, 256, 0, stream>>>(xs, outp_w + (size_t)i * D_MODEL * D_INNER,
                                          mo, NTOK, D_MODEL, D_INNER);
        k_addln<<<NTOK, 256, 0, stream>>>(mo, h, ln_w + i * D_MODEL, ln_b + i * D_MODEL);
    }

    k_pool_head<<<BSZ, 256, 0, stream>>>(h, lengths, head_w, head_b, out);
}

// Round 3
// 4552.608 us; speedup vs baseline: 1.5331x; 1.5331x over previous
//
#include <hip/hip_runtime.h>
#include <math.h>

#define D_IN 63
#define D_MODEL 256
#define N_CLS 14
#define NL 4
#define D_INNER 512
#define D_STATE 128
#define NH 8
#define HP 64
#define DCONV 4
#define CONV_CH 768
#define PROJ 1288
#define XBCDT 776      /* CONV_CH + NH columns of the in-proj */
#define EPS 1e-5f
#define BSZ 32
#define LSEQ 1024
#define NTOK (BSZ*LSEQ)

#define SSEG 4
#define TSEG (LSEQ/SSEG)   /* 256 tokens per segment */
#define CT 16              /* staged steps per chunk */

__device__ __forceinline__ float silu_f(float x) { return x / (1.f + expf(-x)); }

// bank-conflict-free position for state-dim vectors: value n lives at
// pos = q*32 + ((i+2q)&7)*4 + j  (q=n>>5, i=(n>>2)&7, j=n&3), so that at
// inner iteration i the 4 q-groups read disjoint bank quads.
__device__ __forceinline__ int swz128(int n) {
    int q = n >> 5, i = (n >> 2) & 7, j = n & 3;
    return (q << 5) + (((i + 2 * q) & 7) << 2) + j;
}

// two-value block reduction (blockDim == 256)
__device__ __forceinline__ float2 block_reduce2(float a, float b, float* sred) {
    #pragma unroll
    for (int off = 32; off >= 1; off >>= 1) {
        a += __shfl_xor(a, off);
        b += __shfl_xor(b, off);
    }
    int wid = threadIdx.x >> 6, lane = threadIdx.x & 63;
    if (lane == 0) { sred[wid * 2] = a; sred[wid * 2 + 1] = b; }
    __syncthreads();
    a = sred[0] + sred[2] + sred[4] + sred[6];
    b = sred[1] + sred[3] + sred[5] + sred[7];
    __syncthreads();
    return make_float2(a, b);
}

// ---------------- K0: h = LN(x @ in_w.T + in_b) ----------------
__global__ __launch_bounds__(256)
void k_in_ln(const float* __restrict__ x, const float* __restrict__ w,
             const float* __restrict__ bias, const float* __restrict__ gw,
             const float* __restrict__ gb, float* __restrict__ h) {
    int m = blockIdx.x;
    int o = threadIdx.x;
    __shared__ float sx[D_IN];
    __shared__ float sred[8];
    if (o < D_IN) sx[o] = x[(size_t)m * D_IN + o];
    __syncthreads();
    float acc = bias[o];
    const float* wr = w + (size_t)o * D_IN;
    #pragma unroll 7
    for (int k = 0; k < D_IN; k++) acc = fmaf(sx[k], wr[k], acc);
    float2 s = block_reduce2(acc, acc * acc, sred);
    float mu = s.x * (1.f / D_MODEL);
    float var = s.y * (1.f / D_MODEL) - mu * mu;
    float r = rsqrtf(var + EPS);
    h[(size_t)m * D_MODEL + o] = (acc - mu) * r * gw[o] + gb[o];
}

// ---------------- fp32 GEMM: C[m,n] = sum_k A[m,k] * B[n,k] ----------------
// 128x128 tile, BK=16, 256 threads, 8x8 micro-tile (split 4+4 to avoid
// 4-way LDS read conflicts: columns tx*4 and tx*4+64).
#define GBM 128
#define GBN 128
#define GBK 16
__global__ __launch_bounds__(256, 2)
void k_gemm_nt(const float* __restrict__ A, const float* __restrict__ B,
               float* __restrict__ C, int M, int N, int K) {
    __shared__ __align__(16) float As[GBK][GBM];
    __shared__ __align__(16) float Bs[GBK][GBN];
    int n0 = blockIdx.x * GBN;
    int m0 = blockIdx.y * GBM;
    int tid = threadIdx.x;
    int r = tid >> 1;            // 0..127
    int c = (tid & 1) * 4;       // 0 or 4 (k-offset of first float4)
    int tx = tid & 15, ty = tid >> 4;
    float acc[8][8];
    #pragma unroll
    for (int i = 0; i < 8; i++)
        #pragma unroll
        for (int j = 0; j < 8; j++) acc[i][j] = 0.f;
    const float* Ap = A + (size_t)(m0 + r) * K + c;
    const float* Bp = B + (size_t)(n0 + r) * K + c;
    bool bval = (n0 + r) < N;
    for (int k0 = 0; k0 < K; k0 += GBK) {
        float4 a0 = *(const float4*)(Ap + k0);
        float4 a1 = *(const float4*)(Ap + k0 + 8);
        float4 b0 = bval ? *(const float4*)(Bp + k0) : make_float4(0.f,0.f,0.f,0.f);
        float4 b1 = bval ? *(const float4*)(Bp + k0 + 8) : make_float4(0.f,0.f,0.f,0.f);
        __syncthreads();
        As[c+0][r] = a0.x; As[c+1][r] = a0.y; As[c+2][r] = a0.z; As[c+3][r] = a0.w;
        As[c+8][r] = a1.x; As[c+9][r] = a1.y; As[c+10][r] = a1.z; As[c+11][r] = a1.w;
        Bs[c+0][r] = b0.x; Bs[c+1][r] = b0.y; Bs[c+2][r] = b0.z; Bs[c+3][r] = b0.w;
        Bs[c+8][r] = b1.x; Bs[c+9][r] = b1.y; Bs[c+10][r] = b1.z; Bs[c+11][r] = b1.w;
        __syncthreads();
        #pragma unroll
        for (int kk = 0; kk < GBK; kk++) {
            float av[8], bv[8];
            *(float4*)&av[0] = *(const float4*)&As[kk][ty * 4];
            *(float4*)&av[4] = *(const float4*)&As[kk][ty * 4 + 64];
            *(float4*)&bv[0] = *(const float4*)&Bs[kk][tx * 4];
            *(float4*)&bv[4] = *(const float4*)&Bs[kk][tx * 4 + 64];
            #pragma unroll
            for (int i = 0; i < 8; i++)
                #pragma unroll
                for (int j = 0; j < 8; j++)
                    acc[i][j] = fmaf(av[i], bv[j], acc[i][j]);
        }
    }
    int cn0 = n0 + tx * 4;
    int cn1 = n0 + 64 + tx * 4;
    #pragma unroll
    for (int ii = 0; ii < 8; ii++) {
        int m = m0 + (ii >> 2) * 64 + ty * 4 + (ii & 3);
        size_t row = (size_t)m * N;
        if (cn0 + 3 < N) {
            *(float4*)&C[row + cn0] = make_float4(acc[ii][0], acc[ii][1], acc[ii][2], acc[ii][3]);
        } else {
            #pragma unroll
            for (int j = 0; j < 4; j++) if (cn0 + j < N) C[row + cn0 + j] = acc[ii][j];
        }
        if (cn1 + 3 < N) {
            *(float4*)&C[row + cn1] = make_float4(acc[ii][4], acc[ii][5], acc[ii][6], acc[ii][7]);
        } else {
            #pragma unroll
            for (int j = 0; j < 4; j++) if (cn1 + j < N) C[row + cn1 + j] = acc[ii][4 + j];
        }
    }
}

// ---------------- conv (causal depthwise k=4) + silu + dt ----------------
__global__ __launch_bounds__(256)
void k_conv(const float* __restrict__ xbc, const float* __restrict__ cw,
            const float* __restrict__ cb, const float* __restrict__ dtb,
            float* __restrict__ xs, float* __restrict__ Bm, float* __restrict__ Cm,
            float* __restrict__ dtv) {
    int m = blockIdx.x;
    int l = m & (LSEQ - 1);
    int tid = threadIdx.x;
    #pragma unroll
    for (int it = 0; it < 3; it++) {
        int c = tid + it * 256;
        float acc = cb[c];
        #pragma unroll
        for (int k = 0; k < DCONV; k++) {
            int lp = l - (DCONV - 1) + k;
            if (lp >= 0)
                acc = fmaf(cw[k * CONV_CH + c],
                           xbc[(size_t)(m - (DCONV - 1) + k) * XBCDT + c], acc);
        }
        float v = silu_f(acc);
        if (c < D_INNER) xs[(size_t)m * D_INNER + c] = v;
        else if (c < D_INNER + D_STATE) Bm[(size_t)m * D_STATE + (c - D_INNER)] = v;
        else Cm[(size_t)m * D_STATE + (c - D_INNER - D_STATE)] = v;
    }
    if (tid < NH) {
        float draw = xbc[(size_t)m * XBCDT + CONV_CH + tid] + dtb[tid];
        float dt = draw > 20.f ? draw : log1pf(expf(draw));
        dtv[m * NH + tid] = dt;
    }
}

// ---------------- Pass A: segment-local scan ----------------
// grid = 256 (b,h) * SSEG; block 256. Each block scans TSEG tokens from h=0,
// writes local y (in-place over xs), final state F[bh][seg], and cumdA.
__global__ __launch_bounds__(256, 4)
void k_scan_seg(const float* __restrict__ xs, const float* __restrict__ Bm,
                const float* __restrict__ Cm, const float* __restrict__ dtv,
                const float* __restrict__ Alog, const float* __restrict__ Dvec,
                float* __restrict__ y, float* __restrict__ F,
                float* __restrict__ cumdA) {
    int blk = blockIdx.x;
    int bh = blk >> 2;            // /SSEG
    int seg = blk & (SSEG - 1);
    int b = bh >> 3, hh = bh & 7;
    int tid = threadIdx.x;
    int p = tid >> 2, q = tid & 3;
    int q2 = q << 1;
    __shared__ __align__(16) float sB[CT][D_STATE];
    __shared__ __align__(16) float sC[CT][D_STATE];
    __shared__ __align__(16) float sX[CT][HP];
    __shared__ float sdt[CT], sdA[CT];
    float hst[32];
    #pragma unroll
    for (int i = 0; i < 32; i++) hst[i] = 0.f;
    float Dh = Dvec[hh];
    float Ah = -expf(Alog[hh]);
    float c_run = 1.f;
    const size_t base = (size_t)b * LSEQ + (size_t)seg * TSEG;
    int col = tid & 127, half = tid >> 7;
    int sw = swz128(col);
    int xc = tid & 63, xh = tid >> 6;

    for (int c0 = 0; c0 < TSEG; c0 += CT) {
        // stage B, C (swizzled), x, dt, dA
        #pragma unroll
        for (int u = 0; u < 8; u++) {
            int s = 2 * u + half;
            size_t m = base + c0 + s;
            sB[s][sw] = Bm[m * D_STATE + col];
            sC[s][sw] = Cm[m * D_STATE + col];
        }
        #pragma unroll
        for (int u = 0; u < 4; u++) {
            int s = 4 * u + xh;
            size_t m = base + c0 + s;
            sX[s][xc] = xs[m * D_INNER + hh * HP + xc];
        }
        if (tid < CT) {
            size_t m = base + c0 + tid;
            float dtl = dtv[m * NH + hh];
            sdt[tid] = dtl;
            sdA[tid] = expf(dtl * Ah);
        }
        __syncthreads();
        if (tid == 0) {
            float cc = c_run;
            for (int s = 0; s < CT; s++) {
                cc *= sdA[s];
                cumdA[(base + c0 + s) * NH + hh] = cc;
            }
            c_run = cc;
        }
        #pragma unroll 1
        for (int s = 0; s < CT; s++) {
            float dtl = sdt[s], dAl = sdA[s];
            float xv = sX[s][p];
            float tmp = dtl * xv;
            float yp = 0.f;
            #pragma unroll
            for (int i = 0; i < 8; i++) {
                int off = (q << 5) + (((i + q2) & 7) << 2);
                float4 bv = *(const float4*)&sB[s][off];
                float4 cv = *(const float4*)&sC[s][off];
                hst[4*i+0] = fmaf(hst[4*i+0], dAl, tmp * bv.x); yp = fmaf(hst[4*i+0], cv.x, yp);
                hst[4*i+1] = fmaf(hst[4*i+1], dAl, tmp * bv.y); yp = fmaf(hst[4*i+1], cv.y, yp);
                hst[4*i+2] = fmaf(hst[4*i+2], dAl, tmp * bv.z); yp = fmaf(hst[4*i+2], cv.z, yp);
                hst[4*i+3] = fmaf(hst[4*i+3], dAl, tmp * bv.w); yp = fmaf(hst[4*i+3], cv.w, yp);
            }
            yp += __shfl_xor(yp, 1);
            yp += __shfl_xor(yp, 2);
            if (q == 0) y[(base + c0 + s) * D_INNER + hh * HP + p] = fmaf(Dh, xv, yp);
        }
        __syncthreads();
    }
    // store final local state
    float* Fp = F + (((size_t)bh * SSEG + seg) * HP + p) * D_STATE + (q << 5);
    #pragma unroll
    for (int i = 0; i < 8; i++)
        *(float4*)(Fp + 4 * i) = make_float4(hst[4*i], hst[4*i+1], hst[4*i+2], hst[4*i+3]);
}

// ---------------- Pass B: combine segment states ----------------
// h_in[s+1] = P_s * h_in[s] + F[s]; stored in-place into F[s].
__global__ __launch_bounds__(256)
void k_seg_comb(float* __restrict__ F, const float* __restrict__ cumdA) {
    int bh = blockIdx.x, b = bh >> 3, hh = bh & 7;
    int tid = threadIdx.x, p = tid >> 2, q = tid & 3;
    float h[32];
    #pragma unroll
    for (int i = 0; i < 32; i++) h[i] = 0.f;
    for (int s = 0; s < SSEG - 1; s++) {
        float P = cumdA[((size_t)b * LSEQ + (size_t)(s + 1) * TSEG - 1) * NH + hh];
        float* Fp = F + (((size_t)bh * SSEG + s) * HP + p) * D_STATE + (q << 5);
        #pragma unroll
        for (int i = 0; i < 8; i++) {
            float4 f = *(const float4*)(Fp + 4 * i);
            h[4*i+0] = fmaf(h[4*i+0], P, f.x);
            h[4*i+1] = fmaf(h[4*i+1], P, f.y);
            h[4*i+2] = fmaf(h[4*i+2], P, f.z);
            h[4*i+3] = fmaf(h[4*i+3], P, f.w);
        }
        #pragma unroll
        for (int i = 0; i < 8; i++)
            *(float4*)(Fp + 4 * i) = make_float4(h[4*i], h[4*i+1], h[4*i+2], h[4*i+3]);
    }
}

// ---------------- Pass C: y_t += cumdA_t * (C_t . h_in[seg]) ----------------
__global__ __launch_bounds__(256, 4)
void k_seg_fix(const float* __restrict__ Cm, const float* __restrict__ cumdA,
               const float* __restrict__ F, float* __restrict__ y) {
    int blk = blockIdx.x;
    int bh = blk / (SSEG - 1);
    int seg = blk - bh * (SSEG - 1) + 1;
    int b = bh >> 3, hh = bh & 7;
    int tid = threadIdx.x, p = tid >> 2, q = tid & 3;
    int q2 = q << 1;
    float hin[32];
    const float* Fp = F + (((size_t)bh * SSEG + (seg - 1)) * HP + p) * D_STATE + (q << 5);
    #pragma unroll
    for (int i = 0; i < 8; i++) {
        float4 f = *(const float4*)(Fp + 4 * i);
        hin[4*i+0] = f.x; hin[4*i+1] = f.y; hin[4*i+2] = f.z; hin[4*i+3] = f.w;
    }
    __shared__ __align__(16) float sC[CT][D_STATE];
    __shared__ float scd[CT];
    const size_t base = (size_t)b * LSEQ + (size_t)seg * TSEG;
    int col = tid & 127, half = tid >> 7;
    int sw = swz128(col);
    for (int c0 = 0; c0 < TSEG; c0 += CT) {
        #pragma unroll
        for (int u = 0; u < 8; u++) {
            int s = 2 * u + half;
            sC[s][sw] = Cm[(base + c0 + s) * D_STATE + col];
        }
        if (tid < CT) scd[tid] = cumdA[(base + c0 + tid) * NH + hh];
        __syncthreads();
        #pragma unroll 1
        for (int s = 0; s < CT; s++) {
            float yp = 0.f;
            #pragma unroll
            for (int i = 0; i < 8; i++) {
                int off = (q << 5) + (((i + q2) & 7) << 2);
                float4 cv = *(const float4*)&sC[s][off];
                yp = fmaf(hin[4*i+0], cv.x, yp);
                yp = fmaf(hin[4*i+1], cv.y, yp);
                yp = fmaf(hin[4*i+2], cv.z, yp);
                yp = fmaf(hin[4*i+3], cv.w, yp);
            }
            yp += __shfl_xor(yp, 1);
            yp += __shfl_xor(yp, 2);
            if (q == 0) {
                size_t idx = (base + c0 + s) * D_INNER + hh * HP + p;
                y[idx] += scd[s] * yp;
            }
        }
        __syncthreads();
    }
}

// ---------------- gated RMSNorm (in-place on y) ----------------
__global__ __launch_bounds__(256)
void k_gate(float* __restrict__ y, const float* __restrict__ zbuf,
            const float* __restrict__ nw) {
    int m = blockIdx.x, tid = threadIdx.x;
    __shared__ float sred[8];
    float g[2];
    #pragma unroll
    for (int j = 0; j < 2; j++) {
        int d = tid + j * 256;
        float z = zbuf[(size_t)m * D_INNER + d];
        g[j] = y[(size_t)m * D_INNER + d] * silu_f(z);
    }
    float2 s = block_reduce2(g[0] * g[0] + g[1] * g[1], 0.f, sred);
    float r = rsqrtf(s.x * (1.f / D_INNER) + EPS);
    #pragma unroll
    for (int j = 0; j < 2; j++) {
        int d = tid + j * 256;
        y[(size_t)m * D_INNER + d] = g[j] * r * nw[d];
    }
}

// ---------------- h = LN(mo + h) ----------------
__global__ __launch_bounds__(256)
void k_addln(const float* __restrict__ mo, float* __restrict__ h,
             const float* __restrict__ w, const float* __restrict__ bias) {
    int m = blockIdx.x, o = threadIdx.x;
    __shared__ float sred[8];
    float v = mo[(size_t)m * D_MODEL + o] + h[(size_t)m * D_MODEL + o];
    float2 s = block_reduce2(v, v * v, sred);
    float mu = s.x * (1.f / D_MODEL);
    float var = s.y * (1.f / D_MODEL) - mu * mu;
    h[(size_t)m * D_MODEL + o] = (v - mu) * rsqrtf(var + EPS) * w[o] + bias[o];
}

// ---------------- masked mean pool + head ----------------
__global__ __launch_bounds__(256)
void k_pool_head(const float* __restrict__ h, const int* __restrict__ len,
                 const float* __restrict__ hw, const float* __restrict__ hb,
                 float* __restrict__ out) {
    int b = blockIdx.x, d = threadIdx.x;
    __shared__ float sp[D_MODEL];
    int Lb = len[b];
    float acc = 0.f;
    for (int l = 0; l < Lb; l++) acc += h[((size_t)b * LSEQ + l) * D_MODEL + d];
    sp[d] = acc / (float)Lb;
    __syncthreads();
    if (d < N_CLS) {
        float o = hb[d];
        const float* wr = hw + (size_t)d * D_MODEL;
        #pragma unroll 8
        for (int k = 0; k < D_MODEL; k++) o = fmaf(sp[k], wr[k], o);
        out[b * N_CLS + d] = o;
    }
}

extern "C" void kernel_launch(void* const* d_in, const int* in_sizes, int n_in,
                              void* d_out, int out_size, void* d_ws, size_t ws_size,
                              hipStream_t stream) {
    const float* x      = (const float*)d_in[0];
    const float* in_w   = (const float*)d_in[1];
    const float* in_b   = (const float*)d_in[2];
    const float* lnin_w = (const float*)d_in[3];
    const float* lnin_b = (const float*)d_in[4];
    const float* inproj = (const float*)d_in[5];
    const float* conv_w = (const float*)d_in[6];
    const float* conv_b = (const float*)d_in[7];
    const float* dt_bias= (const float*)d_in[8];
    const float* A_log  = (const float*)d_in[9];
    const float* Dv     = (const float*)d_in[10];
    const float* norm_w = (const float*)d_in[11];
    const float* outp_w = (const float*)d_in[12];
    const float* ln_w   = (const float*)d_in[13];
    const float* ln_b   = (const float*)d_in[14];
    const float* head_w = (const float*)d_in[15];
    const float* head_b = (const float*)d_in[16];
    const int*   lengths= (const int*)d_in[17];
    float* out = (float*)d_out;

    // Workspace (floats/token): h 256 | buf1 776 | xs 512 | Bm 128 | Cm 128
    //                           | dtv 8 | cumdA 8   => 238 MB total (proven fit)
    float* ws    = (float*)d_ws;
    float* h     = ws;                               // NTOK*256
    float* buf1  = h    + (size_t)NTOK * D_MODEL;    // NTOK*776
    float* xs    = buf1 + (size_t)NTOK * XBCDT;      // NTOK*512 (y in-place)
    float* Bm    = xs   + (size_t)NTOK * D_INNER;    // NTOK*128
    float* Cm    = Bm   + (size_t)NTOK * D_STATE;    // NTOK*128
    float* dtv   = Cm   + (size_t)NTOK * D_STATE;    // NTOK*8
    float* cumdA = dtv  + (size_t)NTOK * NH;         // NTOK*8
    float* zbuf  = buf1;                             // z reuses buf1[0 .. NTOK*512)
    // F: 256*SSEG*8192 = 8.39M floats in the dead flat tail of buf1
    float* F     = buf1 + (size_t)NTOK * D_INNER;    // NTOK*264 = 8.65M floats avail
    float* mo    = Bm;                               // out-proj result over dead Bm/Cm

    k_in_ln<<<NTOK, 256, 0, stream>>>(x, in_w, in_b, lnin_w, lnin_b, h);

    for (int i = 0; i < NL; i++) {
        const float* W = inproj + (size_t)i * PROJ * D_MODEL;
        // in-proj, xBC+dt columns (rows 512..1287 of W)
        dim3 g1a((XBCDT + GBN - 1) / GBN, NTOK / GBM);
        k_gemm_nt<<<g1a, 256, 0, stream>>>(h, W + (size_t)D_INNER * D_MODEL,
                                           buf1, NTOK, XBCDT, D_MODEL);
        k_conv<<<NTOK, 256, 0, stream>>>(buf1, conv_w + i * DCONV * CONV_CH,
                                         conv_b + i * CONV_CH, dt_bias + i * NH,
                                         xs, Bm, Cm, dtv);
        // in-proj, z columns (rows 0..511) — overwrites dead raw-xBC flat region
        dim3 g1b(D_INNER / GBN, NTOK / GBM);
        k_gemm_nt<<<g1b, 256, 0, stream>>>(h, W, zbuf, NTOK, D_INNER, D_MODEL);
        // segmented scan
        k_scan_seg<<<BSZ * NH * SSEG, 256, 0, stream>>>(xs, Bm, Cm, dtv,
                                                        A_log + i * NH, Dv + i * NH,
                                                        xs, F, cumdA);
        k_seg_comb<<<BSZ * NH, 256, 0, stream>>>(F, cumdA);
        k_seg_fix<<<BSZ * NH * (SSEG - 1), 256, 0, stream>>>(Cm, cumdA, F, xs);
        k_gate<<<NTOK, 256, 0, stream>>>(xs, zbuf, norm_w + i * D_INNER);
        dim3 g2(D_MODEL / GBN, NTOK / GBM);
        k_gemm_nt<<<g2, 256, 0, stream>>>(xs, outp_w + (size_t)i * D_MODEL * D_INNER,
                                          mo, NTOK, D_MODEL, D_INNER);
        k_addln<<<NTOK, 256, 0, stream>>>(mo, h, ln_w + i * D_MODEL, ln_b + i * D_MODEL);
    }

    k_pool_head<<<BSZ, 256, 0, stream>>>(h, lengths, head_w, head_b, out);
}

// Round 4
// 3227.382 us; speedup vs baseline: 2.1626x; 1.4106x over previous
//
#include <hip/hip_runtime.h>
#include <math.h>

#define D_IN 63
#define D_MODEL 256
#define N_CLS 14
#define NL 4
#define D_INNER 512
#define D_STATE 128
#define NH 8
#define HP 64
#define DCONV 4
#define CONV_CH 768
#define PROJ 1288
#define XBCDT 776      /* CONV_CH + NH columns of the in-proj */
#define EPS 1e-5f
#define BSZ 32
#define LSEQ 1024
#define NTOK (BSZ*LSEQ)

#define SSEG 4
#define TSEG (LSEQ/SSEG)   /* 256 tokens per segment */
#define CT 16              /* staged steps per chunk */

typedef __attribute__((ext_vector_type(8))) short bf16x8;
typedef __attribute__((ext_vector_type(4))) float f32x4;

__device__ __forceinline__ float silu_f(float x) { return x / (1.f + expf(-x)); }

__device__ __forceinline__ unsigned short f2bf(float x) {
    union { float f; unsigned u; } v; v.f = x;
    unsigned r = v.u + 0x7FFFu + ((v.u >> 16) & 1u);
    return (unsigned short)(r >> 16);
}
__device__ __forceinline__ float bf2f(unsigned short h) {
    union { float f; unsigned u; } v; v.u = ((unsigned)h) << 16; return v.f;
}

// bank-conflict-free position for state-dim vectors (scan kernels)
__device__ __forceinline__ int swz128(int n) {
    int q = n >> 5, i = (n >> 2) & 7, j = n & 3;
    return (q << 5) + (((i + 2 * q) & 7) << 2) + j;
}

// two-value block reduction (blockDim == 256)
__device__ __forceinline__ float2 block_reduce2(float a, float b, float* sred) {
    #pragma unroll
    for (int off = 32; off >= 1; off >>= 1) {
        a += __shfl_xor(a, off);
        b += __shfl_xor(b, off);
    }
    int wid = threadIdx.x >> 6, lane = threadIdx.x & 63;
    if (lane == 0) { sred[wid * 2] = a; sred[wid * 2 + 1] = b; }
    __syncthreads();
    a = sred[0] + sred[2] + sred[4] + sred[6];
    b = sred[1] + sred[3] + sred[5] + sred[7];
    __syncthreads();
    return make_float2(a, b);
}

// ---------------- split-bf16 MFMA GEMM: C[m,n] = sum_k A[m,k]*B[n,k] ----------------
// fp32 inputs, hi/lo bf16 split, 3 MFMAs per fragment pair (~fp32 precision).
// 128x128 block tile, 4 waves of 64x64, K chunk 32. M%128==0, K%32==0; N guarded.
#define LDKP 40   /* padded k-stride in bf16 elements (80 B rows, 16B aligned) */
__global__ __launch_bounds__(256, 2)
void k_gemm_mfma(const float* __restrict__ A, const float* __restrict__ B,
                 float* __restrict__ C, int M, int N, int K) {
    __shared__ unsigned short Ah[128][LDKP], Al[128][LDKP];
    __shared__ unsigned short Bh[128][LDKP], Bl[128][LDKP];
    int n0 = blockIdx.x * 128, m0 = blockIdx.y * 128;
    int tid = threadIdx.x;
    int srow = tid >> 1, sk = (tid & 1) * 16;
    int lane = tid & 63, wave = tid >> 6;
    int wm = (wave >> 1) * 64, wn = (wave & 1) * 64;
    int ln = lane & 15, quad = lane >> 4;
    f32x4 acc[4][4];
    #pragma unroll
    for (int i = 0; i < 4; i++)
        #pragma unroll
        for (int j = 0; j < 4; j++) acc[i][j] = (f32x4){0.f, 0.f, 0.f, 0.f};
    const float* Ap = A + (size_t)(m0 + srow) * K + sk;
    const float* Bp = B + (size_t)(n0 + srow) * K + sk;
    bool bval = (n0 + srow) < N;
    for (int k0 = 0; k0 < K; k0 += 32) {
        float av[16], bv[16];
        #pragma unroll
        for (int i = 0; i < 4; i++) {
            *(float4*)&av[4 * i] = *(const float4*)(Ap + k0 + 4 * i);
            *(float4*)&bv[4 * i] = bval ? *(const float4*)(Bp + k0 + 4 * i)
                                        : make_float4(0.f, 0.f, 0.f, 0.f);
        }
        __syncthreads();
        #pragma unroll
        for (int g = 0; g < 2; g++) {
            unsigned hiA[4], loA[4], hiB[4], loB[4];
            #pragma unroll
            for (int j = 0; j < 4; j++) {
                float a0 = av[8 * g + 2 * j], a1 = av[8 * g + 2 * j + 1];
                unsigned short h0 = f2bf(a0), h1 = f2bf(a1);
                unsigned short l0 = f2bf(a0 - bf2f(h0)), l1 = f2bf(a1 - bf2f(h1));
                hiA[j] = (unsigned)h0 | ((unsigned)h1 << 16);
                loA[j] = (unsigned)l0 | ((unsigned)l1 << 16);
                float b0 = bv[8 * g + 2 * j], b1 = bv[8 * g + 2 * j + 1];
                unsigned short g0 = f2bf(b0), g1 = f2bf(b1);
                unsigned short m0s = f2bf(b0 - bf2f(g0)), m1s = f2bf(b1 - bf2f(g1));
                hiB[j] = (unsigned)g0 | ((unsigned)g1 << 16);
                loB[j] = (unsigned)m0s | ((unsigned)m1s << 16);
            }
            *(uint4*)&Ah[srow][sk + 8 * g] = *(uint4*)hiA;
            *(uint4*)&Al[srow][sk + 8 * g] = *(uint4*)loA;
            *(uint4*)&Bh[srow][sk + 8 * g] = *(uint4*)hiB;
            *(uint4*)&Bl[srow][sk + 8 * g] = *(uint4*)loB;
        }
        __syncthreads();
        bf16x8 fah[4], fal[4], fbh[4], fbl[4];
        #pragma unroll
        for (int t = 0; t < 4; t++) {
            fah[t] = *(const bf16x8*)&Ah[wm + t * 16 + ln][quad * 8];
            fal[t] = *(const bf16x8*)&Al[wm + t * 16 + ln][quad * 8];
            fbh[t] = *(const bf16x8*)&Bh[wn + t * 16 + ln][quad * 8];
            fbl[t] = *(const bf16x8*)&Bl[wn + t * 16 + ln][quad * 8];
        }
        #pragma unroll
        for (int mt = 0; mt < 4; mt++)
            #pragma unroll
            for (int nt = 0; nt < 4; nt++) {
                acc[mt][nt] = __builtin_amdgcn_mfma_f32_16x16x32_bf16(fal[mt], fbh[nt], acc[mt][nt], 0, 0, 0);
                acc[mt][nt] = __builtin_amdgcn_mfma_f32_16x16x32_bf16(fah[mt], fbl[nt], acc[mt][nt], 0, 0, 0);
                acc[mt][nt] = __builtin_amdgcn_mfma_f32_16x16x32_bf16(fah[mt], fbh[nt], acc[mt][nt], 0, 0, 0);
            }
    }
    #pragma unroll
    for (int mt = 0; mt < 4; mt++)
        #pragma unroll
        for (int nt = 0; nt < 4; nt++) {
            int cn = n0 + wn + nt * 16 + ln;
            if (cn < N) {
                #pragma unroll
                for (int r = 0; r < 4; r++) {
                    int cm = m0 + wm + mt * 16 + quad * 4 + r;
                    C[(size_t)cm * N + cn] = acc[mt][nt][r];
                }
            }
        }
}

// ---------------- pack x (NTOKx63 -> NTOKx64, zero pad) ----------------
__global__ __launch_bounds__(256)
void k_pack_x(const float* __restrict__ x, float* __restrict__ xp) {
    size_t idx = (size_t)blockIdx.x * 256 + threadIdx.x;
    int k = (int)(idx & 63);
    size_t m = idx >> 6;
    xp[idx] = (k < D_IN) ? x[m * D_IN + k] : 0.f;
}
// ---------------- pack in_w (256x63 -> 256x64, zero pad) ----------------
__global__ __launch_bounds__(256)
void k_pack_w(const float* __restrict__ w, float* __restrict__ wp) {
    int idx = blockIdx.x * 256 + threadIdx.x;   // 64 blocks
    int k = idx & 63, n = idx >> 6;
    wp[idx] = (k < D_IN) ? w[n * D_IN + k] : 0.f;
}

// ---------------- h = LN(pre + in_b) ----------------
__global__ __launch_bounds__(256)
void k_lnio(const float* __restrict__ pre, const float* __restrict__ bias,
            const float* __restrict__ gw, const float* __restrict__ gb,
            float* __restrict__ h) {
    int m = blockIdx.x, o = threadIdx.x;
    __shared__ float sred[8];
    float v = pre[(size_t)m * D_MODEL + o] + bias[o];
    float2 s = block_reduce2(v, v * v, sred);
    float mu = s.x * (1.f / D_MODEL);
    float var = s.y * (1.f / D_MODEL) - mu * mu;
    h[(size_t)m * D_MODEL + o] = (v - mu) * rsqrtf(var + EPS) * gw[o] + gb[o];
}

// ---------------- conv (causal depthwise k=4) + silu + dt ----------------
__global__ __launch_bounds__(256)
void k_conv(const float* __restrict__ xbc, const float* __restrict__ cw,
            const float* __restrict__ cb, const float* __restrict__ dtb,
            float* __restrict__ xs, float* __restrict__ Bm, float* __restrict__ Cm,
            float* __restrict__ dtv) {
    int m = blockIdx.x;
    int l = m & (LSEQ - 1);
    int tid = threadIdx.x;
    #pragma unroll
    for (int it = 0; it < 3; it++) {
        int c = tid + it * 256;
        float acc = cb[c];
        #pragma unroll
        for (int k = 0; k < DCONV; k++) {
            int lp = l - (DCONV - 1) + k;
            if (lp >= 0)
                acc = fmaf(cw[k * CONV_CH + c],
                           xbc[(size_t)(m - (DCONV - 1) + k) * XBCDT + c], acc);
        }
        float v = silu_f(acc);
        if (c < D_INNER) xs[(size_t)m * D_INNER + c] = v;
        else if (c < D_INNER + D_STATE) Bm[(size_t)m * D_STATE + (c - D_INNER)] = v;
        else Cm[(size_t)m * D_STATE + (c - D_INNER - D_STATE)] = v;
    }
    if (tid < NH) {
        float draw = xbc[(size_t)m * XBCDT + CONV_CH + tid] + dtb[tid];
        float dt = draw > 20.f ? draw : log1pf(expf(draw));
        dtv[m * NH + tid] = dt;
    }
}

// ---------------- Pass A: segment-local scan ----------------
__global__ __launch_bounds__(256, 4)
void k_scan_seg(const float* __restrict__ xs, const float* __restrict__ Bm,
                const float* __restrict__ Cm, const float* __restrict__ dtv,
                const float* __restrict__ Alog, const float* __restrict__ Dvec,
                float* __restrict__ y, float* __restrict__ F,
                float* __restrict__ cumdA) {
    int blk = blockIdx.x;
    int bh = blk >> 2;            // /SSEG
    int seg = blk & (SSEG - 1);
    int b = bh >> 3, hh = bh & 7;
    int tid = threadIdx.x;
    int p = tid >> 2, q = tid & 3;
    int q2 = q << 1;
    __shared__ __align__(16) float sB[CT][D_STATE];
    __shared__ __align__(16) float sC[CT][D_STATE];
    __shared__ __align__(16) float sX[CT][HP];
    __shared__ float sdt[CT], sdA[CT];
    float hst[32];
    #pragma unroll
    for (int i = 0; i < 32; i++) hst[i] = 0.f;
    float Dh = Dvec[hh];
    float Ah = -expf(Alog[hh]);
    float c_run = 1.f;
    const size_t base = (size_t)b * LSEQ + (size_t)seg * TSEG;
    int col = tid & 127, half = tid >> 7;
    int sw = swz128(col);
    int xc = tid & 63, xh = tid >> 6;

    for (int c0 = 0; c0 < TSEG; c0 += CT) {
        #pragma unroll
        for (int u = 0; u < 8; u++) {
            int s = 2 * u + half;
            size_t m = base + c0 + s;
            sB[s][sw] = Bm[m * D_STATE + col];
            sC[s][sw] = Cm[m * D_STATE + col];
        }
        #pragma unroll
        for (int u = 0; u < 4; u++) {
            int s = 4 * u + xh;
            size_t m = base + c0 + s;
            sX[s][xc] = xs[m * D_INNER + hh * HP + xc];
        }
        if (tid < CT) {
            size_t m = base + c0 + tid;
            float dtl = dtv[m * NH + hh];
            sdt[tid] = dtl;
            sdA[tid] = expf(dtl * Ah);
        }
        __syncthreads();
        if (tid == 0) {
            float cc = c_run;
            for (int s = 0; s < CT; s++) {
                cc *= sdA[s];
                cumdA[(base + c0 + s) * NH + hh] = cc;
            }
            c_run = cc;
        }
        #pragma unroll 1
        for (int s = 0; s < CT; s++) {
            float dtl = sdt[s], dAl = sdA[s];
            float xv = sX[s][p];
            float tmp = dtl * xv;
            float yp = 0.f;
            #pragma unroll
            for (int i = 0; i < 8; i++) {
                int off = (q << 5) + (((i + q2) & 7) << 2);
                float4 bvv = *(const float4*)&sB[s][off];
                float4 cvv = *(const float4*)&sC[s][off];
                hst[4*i+0] = fmaf(hst[4*i+0], dAl, tmp * bvv.x); yp = fmaf(hst[4*i+0], cvv.x, yp);
                hst[4*i+1] = fmaf(hst[4*i+1], dAl, tmp * bvv.y); yp = fmaf(hst[4*i+1], cvv.y, yp);
                hst[4*i+2] = fmaf(hst[4*i+2], dAl, tmp * bvv.z); yp = fmaf(hst[4*i+2], cvv.z, yp);
                hst[4*i+3] = fmaf(hst[4*i+3], dAl, tmp * bvv.w); yp = fmaf(hst[4*i+3], cvv.w, yp);
            }
            yp += __shfl_xor(yp, 1);
            yp += __shfl_xor(yp, 2);
            if (q == 0) y[(base + c0 + s) * D_INNER + hh * HP + p] = fmaf(Dh, xv, yp);
        }
        __syncthreads();
    }
    float* Fp = F + (((size_t)bh * SSEG + seg) * HP + p) * D_STATE + (q << 5);
    #pragma unroll
    for (int i = 0; i < 8; i++)
        *(float4*)(Fp + 4 * i) = make_float4(hst[4*i], hst[4*i+1], hst[4*i+2], hst[4*i+3]);
}

// ---------------- Pass B: combine segment states ----------------
__global__ __launch_bounds__(256)
void k_seg_comb(float* __restrict__ F, const float* __restrict__ cumdA) {
    int bh = blockIdx.x, b = bh >> 3, hh = bh & 7;
    int tid = threadIdx.x, p = tid >> 2, q = tid & 3;
    float h[32];
    #pragma unroll
    for (int i = 0; i < 32; i++) h[i] = 0.f;
    for (int s = 0; s < SSEG - 1; s++) {
        float P = cumdA[((size_t)b * LSEQ + (size_t)(s + 1) * TSEG - 1) * NH + hh];
        float* Fp = F + (((size_t)bh * SSEG + s) * HP + p) * D_STATE + (q << 5);
        #pragma unroll
        for (int i = 0; i < 8; i++) {
            float4 f = *(const float4*)(Fp + 4 * i);
            h[4*i+0] = fmaf(h[4*i+0], P, f.x);
            h[4*i+1] = fmaf(h[4*i+1], P, f.y);
            h[4*i+2] = fmaf(h[4*i+2], P, f.z);
            h[4*i+3] = fmaf(h[4*i+3], P, f.w);
        }
        #pragma unroll
        for (int i = 0; i < 8; i++)
            *(float4*)(Fp + 4 * i) = make_float4(h[4*i], h[4*i+1], h[4*i+2], h[4*i+3]);
    }
}

// ---------------- Pass C: y_t += cumdA_t * (C_t . h_in[seg]) ----------------
__global__ __launch_bounds__(256, 4)
void k_seg_fix(const float* __restrict__ Cm, const float* __restrict__ cumdA,
               const float* __restrict__ F, float* __restrict__ y) {
    int blk = blockIdx.x;
    int bh = blk / (SSEG - 1);
    int seg = blk - bh * (SSEG - 1) + 1;
    int b = bh >> 3, hh = bh & 7;
    int tid = threadIdx.x, p = tid >> 2, q = tid & 3;
    int q2 = q << 1;
    float hin[32];
    const float* Fp = F + (((size_t)bh * SSEG + (seg - 1)) * HP + p) * D_STATE + (q << 5);
    #pragma unroll
    for (int i = 0; i < 8; i++) {
        float4 f = *(const float4*)(Fp + 4 * i);
        hin[4*i+0] = f.x; hin[4*i+1] = f.y; hin[4*i+2] = f.z; hin[4*i+3] = f.w;
    }
    __shared__ __align__(16) float sC[CT][D_STATE];
    __shared__ float scd[CT];
    const size_t base = (size_t)b * LSEQ + (size_t)seg * TSEG;
    int col = tid & 127, half = tid >> 7;
    int sw = swz128(col);
    for (int c0 = 0; c0 < TSEG; c0 += CT) {
        #pragma unroll
        for (int u = 0; u < 8; u++) {
            int s = 2 * u + half;
            sC[s][sw] = Cm[(base + c0 + s) * D_STATE + col];
        }
        if (tid < CT) scd[tid] = cumdA[(base + c0 + tid) * NH + hh];
        __syncthreads();
        #pragma unroll 1
        for (int s = 0; s < CT; s++) {
            float yp = 0.f;
            #pragma unroll
            for (int i = 0; i < 8; i++) {
                int off = (q << 5) + (((i + q2) & 7) << 2);
                float4 cvv = *(const float4*)&sC[s][off];
                yp = fmaf(hin[4*i+0], cvv.x, yp);
                yp = fmaf(hin[4*i+1], cvv.y, yp);
                yp = fmaf(hin[4*i+2], cvv.z, yp);
                yp = fmaf(hin[4*i+3], cvv.w, yp);
            }
            yp += __shfl_xor(yp, 1);
            yp += __shfl_xor(yp, 2);
            if (q == 0) {
                size_t idx = (base + c0 + s) * D_INNER + hh * HP + p;
                y[idx] += scd[s] * yp;
            }
        }
        __syncthreads();
    }
}

// ---------------- gated RMSNorm (in-place on y) ----------------
__global__ __launch_bounds__(256)
void k_gate(float* __restrict__ y, const float* __restrict__ zbuf,
            const float* __restrict__ nw) {
    int m = blockIdx.x, tid = threadIdx.x;
    __shared__ float sred[8];
    float g[2];
    #pragma unroll
    for (int j = 0; j < 2; j++) {
        int d = tid + j * 256;
        float z = zbuf[(size_t)m * D_INNER + d];
        g[j] = y[(size_t)m * D_INNER + d] * silu_f(z);
    }
    float2 s = block_reduce2(g[0] * g[0] + g[1] * g[1], 0.f, sred);
    float r = rsqrtf(s.x * (1.f / D_INNER) + EPS);
    #pragma unroll
    for (int j = 0; j < 2; j++) {
        int d = tid + j * 256;
        y[(size_t)m * D_INNER + d] = g[j] * r * nw[d];
    }
}

// ---------------- h = LN(mo + h) ----------------
__global__ __launch_bounds__(256)
void k_addln(const float* __restrict__ mo, float* __restrict__ h,
             const float* __restrict__ w, const float* __restrict__ bias) {
    int m = blockIdx.x, o = threadIdx.x;
    __shared__ float sred[8];
    float v = mo[(size_t)m * D_MODEL + o] + h[(size_t)m * D_MODEL + o];
    float2 s = block_reduce2(v, v * v, sred);
    float mu = s.x * (1.f / D_MODEL);
    float var = s.y * (1.f / D_MODEL) - mu * mu;
    h[(size_t)m * D_MODEL + o] = (v - mu) * rsqrtf(var + EPS) * w[o] + bias[o];
}

// ---------------- masked mean pool + head ----------------
__global__ __launch_bounds__(256)
void k_pool_head(const float* __restrict__ h, const int* __restrict__ len,
                 const float* __restrict__ hw, const float* __restrict__ hb,
                 float* __restrict__ out) {
    int b = blockIdx.x, d = threadIdx.x;
    __shared__ float sp[D_MODEL];
    int Lb = len[b];
    float acc = 0.f;
    for (int l = 0; l < Lb; l++) acc += h[((size_t)b * LSEQ + l) * D_MODEL + d];
    sp[d] = acc / (float)Lb;
    __syncthreads();
    if (d < N_CLS) {
        float o = hb[d];
        const float* wr = hw + (size_t)d * D_MODEL;
        #pragma unroll 8
        for (int k = 0; k < D_MODEL; k++) o = fmaf(sp[k], wr[k], o);
        out[b * N_CLS + d] = o;
    }
}

extern "C" void kernel_launch(void* const* d_in, const int* in_sizes, int n_in,
                              void* d_out, int out_size, void* d_ws, size_t ws_size,
                              hipStream_t stream) {
    const float* x      = (const float*)d_in[0];
    const float* in_w   = (const float*)d_in[1];
    const float* in_b   = (const float*)d_in[2];
    const float* lnin_w = (const float*)d_in[3];
    const float* lnin_b = (const float*)d_in[4];
    const float* inproj = (const float*)d_in[5];
    const float* conv_w = (const float*)d_in[6];
    const float* conv_b = (const float*)d_in[7];
    const float* dt_bias= (const float*)d_in[8];
    const float* A_log  = (const float*)d_in[9];
    const float* Dv     = (const float*)d_in[10];
    const float* norm_w = (const float*)d_in[11];
    const float* outp_w = (const float*)d_in[12];
    const float* ln_w   = (const float*)d_in[13];
    const float* ln_b   = (const float*)d_in[14];
    const float* head_w = (const float*)d_in[15];
    const float* head_b = (const float*)d_in[16];
    const int*   lengths= (const int*)d_in[17];
    float* out = (float*)d_out;

    // Workspace (floats/token): h 256 | buf1 776 | xs 512 | Bm 128 | Cm 128
    //                           | dtv 8 | cumdA 8   => 238 MB total (proven fit)
    float* ws    = (float*)d_ws;
    float* h     = ws;                               // NTOK*256
    float* buf1  = h    + (size_t)NTOK * D_MODEL;    // NTOK*776
    float* xs    = buf1 + (size_t)NTOK * XBCDT;      // NTOK*512 (y in-place)
    float* Bm    = xs   + (size_t)NTOK * D_INNER;    // NTOK*128
    float* Cm    = Bm   + (size_t)NTOK * D_STATE;    // NTOK*128
    float* dtv   = Cm   + (size_t)NTOK * D_STATE;    // NTOK*8
    float* cumdA = dtv  + (size_t)NTOK * NH;         // NTOK*8
    float* zbuf  = buf1;                             // z reuses buf1[0 .. NTOK*512)
    float* F     = buf1 + (size_t)NTOK * D_INNER;    // scan carry states (8.39M fl)
    float* mo    = Bm;                               // out-proj result over dead Bm/Cm
    // input-stage scratch (buf1 is dead before layer 0):
    float* xp    = buf1;                             // NTOK*64
    float* pre   = buf1 + (size_t)NTOK * 64;         // NTOK*256
    float* wp    = Bm;                               // 256*64 (dead at start)

    // ---- input projection + LN via MFMA GEMM ----
    k_pack_x<<<NTOK * 64 / 256, 256, 0, stream>>>(x, xp);
    k_pack_w<<<64, 256, 0, stream>>>(in_w, wp);
    {
        dim3 g(D_MODEL / 128, NTOK / 128);
        k_gemm_mfma<<<g, 256, 0, stream>>>(xp, wp, pre, NTOK, D_MODEL, 64);
    }
    k_lnio<<<NTOK, 256, 0, stream>>>(pre, in_b, lnin_w, lnin_b, h);

    for (int i = 0; i < NL; i++) {
        const float* W = inproj + (size_t)i * PROJ * D_MODEL;
        // in-proj, xBC+dt columns (rows 512..1287 of W)
        dim3 g1a((XBCDT + 127) / 128, NTOK / 128);
        k_gemm_mfma<<<g1a, 256, 0, stream>>>(h, W + (size_t)D_INNER * D_MODEL,
                                             buf1, NTOK, XBCDT, D_MODEL);
        k_conv<<<NTOK, 256, 0, stream>>>(buf1, conv_w + i * DCONV * CONV_CH,
                                         conv_b + i * CONV_CH, dt_bias + i * NH,
                                         xs, Bm, Cm, dtv);
        // in-proj, z columns (rows 0..511) — overwrites dead raw-xBC flat region
        dim3 g1b(D_INNER / 128, NTOK / 128);
        k_gemm_mfma<<<g1b, 256, 0, stream>>>(h, W, zbuf, NTOK, D_INNER, D_MODEL);
        // segmented scan
        k_scan_seg<<<BSZ * NH * SSEG, 256, 0, stream>>>(xs, Bm, Cm, dtv,
                                                        A_log + i * NH, Dv + i * NH,
                                                        xs, F, cumdA);
        k_seg_comb<<<BSZ * NH, 256, 0, stream>>>(F, cumdA);
        k_seg_fix<<<BSZ * NH * (SSEG - 1), 256, 0, stream>>>(Cm, cumdA, F, xs);
        k_gate<<<NTOK, 256, 0, stream>>>(xs, zbuf, norm_w + i * D_INNER);
        dim3 g2(D_MODEL / 128, NTOK / 128);
        k_gemm_mfma<<<g2, 256, 0, stream>>>(xs, outp_w + (size_t)i * D_MODEL * D_INNER,
                                            mo, NTOK, D_MODEL, D_INNER);
        k_addln<<<NTOK, 256, 0, stream>>>(mo, h, ln_w + i * D_MODEL, ln_b + i * D_MODEL);
    }

    k_pool_head<<<BSZ, 256, 0, stream>>>(h, lengths, head_w, head_b, out);
}

// Round 5
// 3013.734 us; speedup vs baseline: 2.3159x; 1.0709x over previous
//
#include <hip/hip_runtime.h>
#include <math.h>

#define D_IN 63
#define D_MODEL 256
#define N_CLS 14
#define NL 4
#define D_INNER 512
#define D_STATE 128
#define NH 8
#define HP 64
#define DCONV 4
#define CONV_CH 768
#define PROJ 1288
#define XBCDT 776
#define EPS 1e-5f
#define BSZ 32
#define LSEQ 1024
#define NTOK (BSZ*LSEQ)

#define SSEG 4
#define TSEG (LSEQ/SSEG)
#define CT 16
#define RS 8

// weight-pack region (ushort offsets)
#define S_IN   16384
#define S_IP   1318912
#define S_OP   524288
#define IN_HI  0
#define IN_LO  16384
#define IP_HI  32768
#define IP_LO  (32768 + S_IP)
#define OP_HI  (32768 + 2*S_IP)
#define OP_LO  (OP_HI + S_OP)
#define TOTPK  (S_IN + S_IP + S_OP)          /* 1,859,584 elements */
#define WS_BASE ((size_t)NTOK * 1816)
#define WS_NEED ((WS_BASE + (size_t)TOTPK) * 4)

typedef __attribute__((ext_vector_type(8))) short bf16x8;
typedef __attribute__((ext_vector_type(4))) float f32x4;

__device__ __forceinline__ float silu_f(float x) { return x / (1.f + expf(-x)); }

__device__ __forceinline__ unsigned short f2bf(float x) {
    union { float f; unsigned u; } v; v.f = x;
    unsigned r = v.u + 0x7FFFu + ((v.u >> 16) & 1u);
    return (unsigned short)(r >> 16);
}
__device__ __forceinline__ float bf2f(unsigned short h) {
    union { float f; unsigned u; } v; v.u = ((unsigned)h) << 16; return v.f;
}

__device__ __forceinline__ int swz128(int n) {
    int q = n >> 5, i = (n >> 2) & 7, j = n & 3;
    return (q << 5) + (((i + 2 * q) & 7) << 2) + j;
}

__device__ __forceinline__ float2 block_reduce2(float a, float b, float* sred) {
    #pragma unroll
    for (int off = 32; off >= 1; off >>= 1) {
        a += __shfl_xor(a, off);
        b += __shfl_xor(b, off);
    }
    int wid = threadIdx.x >> 6, lane = threadIdx.x & 63;
    if (lane == 0) { sred[wid * 2] = a; sred[wid * 2 + 1] = b; }
    __syncthreads();
    a = sred[0] + sred[2] + sred[4] + sred[6];
    b = sred[1] + sred[3] + sred[5] + sred[7];
    __syncthreads();
    return make_float2(a, b);
}

// ---------------- pack all weights to bf16 hi/lo planes (round-nearest split) --------
__global__ __launch_bounds__(256)
void k_pack_weights(const float* __restrict__ in_w, const float* __restrict__ inproj,
                    const float* __restrict__ outp, unsigned short* __restrict__ WP) {
    int idx = blockIdx.x * 256 + threadIdx.x;
    float v; int hi_off, lo_off;
    if (idx < S_IN) {
        int n = idx >> 6, k = idx & 63;
        v = (k < D_IN) ? in_w[n * D_IN + k] : 0.f;
        hi_off = IN_HI + idx; lo_off = IN_LO + idx;
    } else if (idx < S_IN + S_IP) {
        int j = idx - S_IN;
        v = inproj[j];
        hi_off = IP_HI + j; lo_off = IP_LO + j;
    } else {
        int j = idx - S_IN - S_IP;
        v = outp[j];
        hi_off = OP_HI + j; lo_off = OP_LO + j;
    }
    unsigned short h = f2bf(v);
    unsigned short l = f2bf(v - bf2f(h));
    WP[hi_off] = h; WP[lo_off] = l;
}

// ---------------- MFMA GEMM, A fp32 (in-kernel trunc split), B pre-packed ----------
#define LDKP 40
__global__ __launch_bounds__(256, 2)
void k_gemm_as(const float* __restrict__ A, const unsigned short* __restrict__ Bhg,
               const unsigned short* __restrict__ Blg, float* __restrict__ C,
               int M, int N, int K) {
    __shared__ unsigned short Ah[128][LDKP], Al[128][LDKP];
    __shared__ unsigned short Bh[128][LDKP], Bl[128][LDKP];
    int n0 = blockIdx.x * 128, m0 = blockIdx.y * 128;
    int tid = threadIdx.x;
    int srow = tid >> 1, sk = (tid & 1) * 16;
    int lane = tid & 63, wave = tid >> 6;
    int wm = (wave >> 1) * 64, wn = (wave & 1) * 64;
    int ln = lane & 15, quad = lane >> 4;
    f32x4 acc[4][4];
    #pragma unroll
    for (int i = 0; i < 4; i++)
        #pragma unroll
        for (int j = 0; j < 4; j++) acc[i][j] = (f32x4){0.f, 0.f, 0.f, 0.f};
    const float* Ap = A + (size_t)(m0 + srow) * K + sk;
    const unsigned short* Bhp = Bhg + (size_t)(n0 + srow) * K + sk;
    const unsigned short* Blp = Blg + (size_t)(n0 + srow) * K + sk;
    bool bval = (n0 + srow) < N;
    uint4 z4 = make_uint4(0u, 0u, 0u, 0u);
    for (int k0 = 0; k0 < K; k0 += 32) {
        float av[16];
        #pragma unroll
        for (int i = 0; i < 4; i++)
            *(float4*)&av[4 * i] = *(const float4*)(Ap + k0 + 4 * i);
        uint4 bh0 = bval ? *(const uint4*)(Bhp + k0) : z4;
        uint4 bh1 = bval ? *(const uint4*)(Bhp + k0 + 8) : z4;
        uint4 bl0 = bval ? *(const uint4*)(Blp + k0) : z4;
        uint4 bl1 = bval ? *(const uint4*)(Blp + k0 + 8) : z4;
        unsigned hp[8], lp[8];
        #pragma unroll
        for (int j = 0; j < 8; j++) {
            float a0 = av[2 * j], a1 = av[2 * j + 1];
            unsigned u0 = __float_as_uint(a0), u1 = __float_as_uint(a1);
            unsigned h0 = u0 & 0xFFFF0000u, h1 = u1 & 0xFFFF0000u;
            float r0 = a0 - __uint_as_float(h0);
            float r1 = a1 - __uint_as_float(h1);
            hp[j] = (u0 >> 16) | h1;
            lp[j] = (__float_as_uint(r0) >> 16) | (__float_as_uint(r1) & 0xFFFF0000u);
        }
        __syncthreads();
        *(uint4*)&Ah[srow][sk]     = *(uint4*)&hp[0];
        *(uint4*)&Ah[srow][sk + 8] = *(uint4*)&hp[4];
        *(uint4*)&Al[srow][sk]     = *(uint4*)&lp[0];
        *(uint4*)&Al[srow][sk + 8] = *(uint4*)&lp[4];
        *(uint4*)&Bh[srow][sk]     = bh0;
        *(uint4*)&Bh[srow][sk + 8] = bh1;
        *(uint4*)&Bl[srow][sk]     = bl0;
        *(uint4*)&Bl[srow][sk + 8] = bl1;
        __syncthreads();
        bf16x8 fah[4], fal[4], fbh[4], fbl[4];
        #pragma unroll
        for (int t = 0; t < 4; t++) {
            fah[t] = *(const bf16x8*)&Ah[wm + t * 16 + ln][quad * 8];
            fal[t] = *(const bf16x8*)&Al[wm + t * 16 + ln][quad * 8];
            fbh[t] = *(const bf16x8*)&Bh[wn + t * 16 + ln][quad * 8];
            fbl[t] = *(const bf16x8*)&Bl[wn + t * 16 + ln][quad * 8];
        }
        #pragma unroll
        for (int mt = 0; mt < 4; mt++)
            #pragma unroll
            for (int nt = 0; nt < 4; nt++) {
                acc[mt][nt] = __builtin_amdgcn_mfma_f32_16x16x32_bf16(fal[mt], fbh[nt], acc[mt][nt], 0, 0, 0);
                acc[mt][nt] = __builtin_amdgcn_mfma_f32_16x16x32_bf16(fah[mt], fbl[nt], acc[mt][nt], 0, 0, 0);
                acc[mt][nt] = __builtin_amdgcn_mfma_f32_16x16x32_bf16(fah[mt], fbh[nt], acc[mt][nt], 0, 0, 0);
            }
    }
    #pragma unroll
    for (int mt = 0; mt < 4; mt++)
        #pragma unroll
        for (int nt = 0; nt < 4; nt++) {
            int cn = n0 + wn + nt * 16 + ln;
            if (cn < N) {
                #pragma unroll
                for (int r = 0; r < 4; r++) {
                    int cm = m0 + wm + mt * 16 + quad * 4 + r;
                    C[(size_t)cm * N + cn] = acc[mt][nt][r];
                }
            }
        }
}

// ---------------- fallback GEMM (round-4 proven): fp32 A and B, in-kernel split -----
__global__ __launch_bounds__(256, 2)
void k_gemm_mfma(const float* __restrict__ A, const float* __restrict__ B,
                 float* __restrict__ C, int M, int N, int K) {
    __shared__ unsigned short Ah[128][LDKP], Al[128][LDKP];
    __shared__ unsigned short Bh[128][LDKP], Bl[128][LDKP];
    int n0 = blockIdx.x * 128, m0 = blockIdx.y * 128;
    int tid = threadIdx.x;
    int srow = tid >> 1, sk = (tid & 1) * 16;
    int lane = tid & 63, wave = tid >> 6;
    int wm = (wave >> 1) * 64, wn = (wave & 1) * 64;
    int ln = lane & 15, quad = lane >> 4;
    f32x4 acc[4][4];
    #pragma unroll
    for (int i = 0; i < 4; i++)
        #pragma unroll
        for (int j = 0; j < 4; j++) acc[i][j] = (f32x4){0.f, 0.f, 0.f, 0.f};
    const float* Ap = A + (size_t)(m0 + srow) * K + sk;
    const float* Bp = B + (size_t)(n0 + srow) * K + sk;
    bool bval = (n0 + srow) < N;
    for (int k0 = 0; k0 < K; k0 += 32) {
        float av[16], bv[16];
        #pragma unroll
        for (int i = 0; i < 4; i++) {
            *(float4*)&av[4 * i] = *(const float4*)(Ap + k0 + 4 * i);
            *(float4*)&bv[4 * i] = bval ? *(const float4*)(Bp + k0 + 4 * i)
                                        : make_float4(0.f, 0.f, 0.f, 0.f);
        }
        __syncthreads();
        #pragma unroll
        for (int g = 0; g < 2; g++) {
            unsigned hiA[4], loA[4], hiB[4], loB[4];
            #pragma unroll
            for (int j = 0; j < 4; j++) {
                float a0 = av[8 * g + 2 * j], a1 = av[8 * g + 2 * j + 1];
                unsigned short h0 = f2bf(a0), h1 = f2bf(a1);
                unsigned short l0 = f2bf(a0 - bf2f(h0)), l1 = f2bf(a1 - bf2f(h1));
                hiA[j] = (unsigned)h0 | ((unsigned)h1 << 16);
                loA[j] = (unsigned)l0 | ((unsigned)l1 << 16);
                float b0 = bv[8 * g + 2 * j], b1 = bv[8 * g + 2 * j + 1];
                unsigned short g0 = f2bf(b0), g1 = f2bf(b1);
                unsigned short m0s = f2bf(b0 - bf2f(g0)), m1s = f2bf(b1 - bf2f(g1));
                hiB[j] = (unsigned)g0 | ((unsigned)g1 << 16);
                loB[j] = (unsigned)m0s | ((unsigned)m1s << 16);
            }
            *(uint4*)&Ah[srow][sk + 8 * g] = *(uint4*)hiA;
            *(uint4*)&Al[srow][sk + 8 * g] = *(uint4*)loA;
            *(uint4*)&Bh[srow][sk + 8 * g] = *(uint4*)hiB;
            *(uint4*)&Bl[srow][sk + 8 * g] = *(uint4*)loB;
        }
        __syncthreads();
        bf16x8 fah[4], fal[4], fbh[4], fbl[4];
        #pragma unroll
        for (int t = 0; t < 4; t++) {
            fah[t] = *(const bf16x8*)&Ah[wm + t * 16 + ln][quad * 8];
            fal[t] = *(const bf16x8*)&Al[wm + t * 16 + ln][quad * 8];
            fbh[t] = *(const bf16x8*)&Bh[wn + t * 16 + ln][quad * 8];
            fbl[t] = *(const bf16x8*)&Bl[wn + t * 16 + ln][quad * 8];
        }
        #pragma unroll
        for (int mt = 0; mt < 4; mt++)
            #pragma unroll
            for (int nt = 0; nt < 4; nt++) {
                acc[mt][nt] = __builtin_amdgcn_mfma_f32_16x16x32_bf16(fal[mt], fbh[nt], acc[mt][nt], 0, 0, 0);
                acc[mt][nt] = __builtin_amdgcn_mfma_f32_16x16x32_bf16(fah[mt], fbl[nt], acc[mt][nt], 0, 0, 0);
                acc[mt][nt] = __builtin_amdgcn_mfma_f32_16x16x32_bf16(fah[mt], fbh[nt], acc[mt][nt], 0, 0, 0);
            }
    }
    #pragma unroll
    for (int mt = 0; mt < 4; mt++)
        #pragma unroll
        for (int nt = 0; nt < 4; nt++) {
            int cn = n0 + wn + nt * 16 + ln;
            if (cn < N) {
                #pragma unroll
                for (int r = 0; r < 4; r++) {
                    int cm = m0 + wm + mt * 16 + quad * 4 + r;
                    C[(size_t)cm * N + cn] = acc[mt][nt][r];
                }
            }
        }
}

// ---------------- pack x (NTOKx63 -> NTOKx64, zero pad) ----------------
__global__ __launch_bounds__(256)
void k_pack_x(const float* __restrict__ x, float* __restrict__ xp) {
    size_t idx = (size_t)blockIdx.x * 256 + threadIdx.x;
    int k = (int)(idx & 63);
    size_t m = idx >> 6;
    xp[idx] = (k < D_IN) ? x[m * D_IN + k] : 0.f;
}
// ---------------- pack in_w fp32 (fallback path only) ----------------
__global__ __launch_bounds__(256)
void k_pack_w(const float* __restrict__ w, float* __restrict__ wp) {
    int idx = blockIdx.x * 256 + threadIdx.x;
    int k = idx & 63, n = idx >> 6;
    wp[idx] = (k < D_IN) ? w[n * D_IN + k] : 0.f;
}

// ---------------- h = LN(pre + in_b) ----------------
__global__ __launch_bounds__(256)
void k_lnio(const float* __restrict__ pre, const float* __restrict__ bias,
            const float* __restrict__ gw, const float* __restrict__ gb,
            float* __restrict__ h) {
    int m = blockIdx.x, o = threadIdx.x;
    __shared__ float sred[8];
    float v = pre[(size_t)m * D_MODEL + o] + bias[o];
    float2 s = block_reduce2(v, v * v, sred);
    float mu = s.x * (1.f / D_MODEL);
    float var = s.y * (1.f / D_MODEL) - mu * mu;
    h[(size_t)m * D_MODEL + o] = (v - mu) * rsqrtf(var + EPS) * gw[o] + gb[o];
}

// ---------------- conv (causal depthwise k=4) + silu + dt ----------------
__global__ __launch_bounds__(256)
void k_conv(const float* __restrict__ xbc, const float* __restrict__ cw,
            const float* __restrict__ cb, const float* __restrict__ dtb,
            float* __restrict__ xs, float* __restrict__ Bm, float* __restrict__ Cm,
            float* __restrict__ dtv) {
    int m = blockIdx.x;
    int l = m & (LSEQ - 1);
    int tid = threadIdx.x;
    #pragma unroll
    for (int it = 0; it < 3; it++) {
        int c = tid + it * 256;
        float acc = cb[c];
        #pragma unroll
        for (int k = 0; k < DCONV; k++) {
            int lp = l - (DCONV - 1) + k;
            if (lp >= 0)
                acc = fmaf(cw[k * CONV_CH + c],
                           xbc[(size_t)(m - (DCONV - 1) + k) * XBCDT + c], acc);
        }
        float v = silu_f(acc);
        if (c < D_INNER) xs[(size_t)m * D_INNER + c] = v;
        else if (c < D_INNER + D_STATE) Bm[(size_t)m * D_STATE + (c - D_INNER)] = v;
        else Cm[(size_t)m * D_STATE + (c - D_INNER - D_STATE)] = v;
    }
    if (tid < NH) {
        float draw = xbc[(size_t)m * XBCDT + CONV_CH + tid] + dtb[tid];
        float dt = draw > 20.f ? draw : log1pf(expf(draw));
        dtv[m * NH + tid] = dt;
    }
}

// ---------------- Pass A: segment-local scan (rescaled inner loop) ----------------
__global__ __launch_bounds__(256, 4)
void k_scan_seg(const float* __restrict__ xs, const float* __restrict__ Bm,
                const float* __restrict__ Cm, const float* __restrict__ dtv,
                const float* __restrict__ Alog, const float* __restrict__ Dvec,
                float* __restrict__ y, float* __restrict__ F,
                float* __restrict__ cumdA) {
    int blk = blockIdx.x;
    int bh = blk >> 2;
    int seg = blk & (SSEG - 1);
    int b = bh >> 3, hh = bh & 7;
    int tid = threadIdx.x;
    int p = tid >> 2, q = tid & 3;
    int q2 = q << 1;
    __shared__ __align__(16) float sBC[2 * CT * 128];
    __shared__ __align__(16) float sX[CT][HP];
    __shared__ float sdt[CT], sdA[CT], srdA[CT];
    float hst[32];
    #pragma unroll
    for (int i = 0; i < 32; i++) hst[i] = 0.f;
    float Dh = Dvec[hh];
    float Ahv = -expf(Alog[hh]);
    float c_run = 1.f;
    const size_t base = (size_t)b * LSEQ + (size_t)seg * TSEG;
    int col = tid & 127, half = tid >> 7;
    int sw = swz128(col);
    int xc = tid & 63, xh = tid >> 6;

    for (int c0 = 0; c0 < TSEG; c0 += CT) {
        #pragma unroll
        for (int u = 0; u < 8; u++) {
            int s = 2 * u + half;
            size_t m = base + c0 + s;
            sBC[s * 128 + sw] = Bm[m * D_STATE + col];
            sBC[(CT + s) * 128 + sw] = Cm[m * D_STATE + col];
        }
        #pragma unroll
        for (int u = 0; u < 4; u++) {
            int s = 4 * u + xh;
            sX[s][xc] = xs[(base + c0 + s) * D_INNER + hh * HP + xc];
        }
        if (tid < CT) {
            float dtl = dtv[(base + c0 + tid) * NH + hh];
            float e = fmaxf(dtl * Ahv, -37.f);
            sdt[tid] = dtl;
            sdA[tid] = expf(e);
            srdA[tid] = expf(-e);
        }
        __syncthreads();
        if (tid == 0) {
            float cg = c_run;
            for (int s = 0; s < CT; s++) {
                cg *= sdA[s];
                cumdA[(base + c0 + s) * NH + hh] = cg;
            }
            c_run = cg;
        }
        float cc = 1.f, rc = 1.f;
        #pragma unroll
        for (int s = 0; s < CT; s++) {
            float dAl = sdA[s], dtl = sdt[s];
            float ccn = cc * dAl;
            if (ccn < 1e-18f) {          // rare, wave-uniform: rebase now
                #pragma unroll
                for (int i = 0; i < 32; i++) hst[i] *= cc;
                rc = srdA[s];
                ccn = dAl;
            } else {
                rc *= srdA[s];
            }
            cc = ccn;
            float xv = sX[s][p];
            float tmp = dtl * xv * rc;
            float yp = 0.f;
            #pragma unroll
            for (int i = 0; i < 8; i++) {
                int off = (q << 5) + (((i + q2) & 7) << 2);
                float4 bv = *(const float4*)&sBC[s * 128 + off];
                float4 cv = *(const float4*)&sBC[(CT + s) * 128 + off];
                hst[4*i+0] = fmaf(tmp, bv.x, hst[4*i+0]); yp = fmaf(hst[4*i+0], cv.x, yp);
                hst[4*i+1] = fmaf(tmp, bv.y, hst[4*i+1]); yp = fmaf(hst[4*i+1], cv.y, yp);
                hst[4*i+2] = fmaf(tmp, bv.z, hst[4*i+2]); yp = fmaf(hst[4*i+2], cv.z, yp);
                hst[4*i+3] = fmaf(tmp, bv.w, hst[4*i+3]); yp = fmaf(hst[4*i+3], cv.w, yp);
            }
            yp += __shfl_xor(yp, 1);
            yp += __shfl_xor(yp, 2);
            if (q == 0) y[(base + c0 + s) * D_INNER + hh * HP + p] = fmaf(Dh, xv, cc * yp);
            if ((s & (RS - 1)) == RS - 1) {   // sub-chunk flush -> hst = true state
                #pragma unroll
                for (int i = 0; i < 32; i++) hst[i] *= cc;
                cc = 1.f; rc = 1.f;
            }
        }
        __syncthreads();
    }
    if (seg < SSEG - 1) {
        float* Fp = F + (((size_t)bh * (SSEG - 1) + seg) * HP + p) * D_STATE + (q << 5);
        #pragma unroll
        for (int i = 0; i < 8; i++)
            *(float4*)(Fp + 4 * i) = make_float4(hst[4*i], hst[4*i+1], hst[4*i+2], hst[4*i+3]);
    }
}

// ---------------- Pass C (with fused combine): y_t += cumdA_t * (C_t . h_in[seg]) ----
__global__ __launch_bounds__(256, 4)
void k_seg_fix(const float* __restrict__ Cm, const float* __restrict__ cumdA,
               const float* __restrict__ F, float* __restrict__ y) {
    int blk = blockIdx.x;
    int bh = blk / (SSEG - 1);
    int seg = blk - bh * (SSEG - 1) + 1;
    int b = bh >> 3, hh = bh & 7;
    int tid = threadIdx.x, p = tid >> 2, q = tid & 3;
    int q2 = q << 1;
    float hin[32];
    #pragma unroll
    for (int i = 0; i < 32; i++) hin[i] = 0.f;
    for (int s = 0; s < seg; s++) {
        float P = cumdA[((size_t)b * LSEQ + (size_t)(s + 1) * TSEG - 1) * NH + hh];
        const float* Fp = F + (((size_t)bh * (SSEG - 1) + s) * HP + p) * D_STATE + (q << 5);
        #pragma unroll
        for (int i = 0; i < 8; i++) {
            float4 f = *(const float4*)(Fp + 4 * i);
            hin[4*i+0] = fmaf(hin[4*i+0], P, f.x);
            hin[4*i+1] = fmaf(hin[4*i+1], P, f.y);
            hin[4*i+2] = fmaf(hin[4*i+2], P, f.z);
            hin[4*i+3] = fmaf(hin[4*i+3], P, f.w);
        }
    }
    __shared__ __align__(16) float sC[CT][D_STATE];
    __shared__ float scd[CT];
    const size_t base = (size_t)b * LSEQ + (size_t)seg * TSEG;
    int col = tid & 127, half = tid >> 7;
    int sw = swz128(col);
    for (int c0 = 0; c0 < TSEG; c0 += CT) {
        #pragma unroll
        for (int u = 0; u < 8; u++) {
            int s = 2 * u + half;
            sC[s][sw] = Cm[(base + c0 + s) * D_STATE + col];
        }
        if (tid < CT) scd[tid] = cumdA[(base + c0 + tid) * NH + hh];
        __syncthreads();
        #pragma unroll 1
        for (int s = 0; s < CT; s++) {
            float yp = 0.f;
            #pragma unroll
            for (int i = 0; i < 8; i++) {
                int off = (q << 5) + (((i + q2) & 7) << 2);
                float4 cvv = *(const float4*)&sC[s][off];
                yp = fmaf(hin[4*i+0], cvv.x, yp);
                yp = fmaf(hin[4*i+1], cvv.y, yp);
                yp = fmaf(hin[4*i+2], cvv.z, yp);
                yp = fmaf(hin[4*i+3], cvv.w, yp);
            }
            yp += __shfl_xor(yp, 1);
            yp += __shfl_xor(yp, 2);
            if (q == 0) {
                size_t idx = (base + c0 + s) * D_INNER + hh * HP + p;
                y[idx] += scd[s] * yp;
            }
        }
        __syncthreads();
    }
}

// ---------------- gated RMSNorm (in-place on y) ----------------
__global__ __launch_bounds__(256)
void k_gate(float* __restrict__ y, const float* __restrict__ zbuf,
            const float* __restrict__ nw) {
    int m = blockIdx.x, tid = threadIdx.x;
    __shared__ float sred[8];
    float g[2];
    #pragma unroll
    for (int j = 0; j < 2; j++) {
        int d = tid + j * 256;
        float z = zbuf[(size_t)m * D_INNER + d];
        g[j] = y[(size_t)m * D_INNER + d] * silu_f(z);
    }
    float2 s = block_reduce2(g[0] * g[0] + g[1] * g[1], 0.f, sred);
    float r = rsqrtf(s.x * (1.f / D_INNER) + EPS);
    #pragma unroll
    for (int j = 0; j < 2; j++) {
        int d = tid + j * 256;
        y[(size_t)m * D_INNER + d] = g[j] * r * nw[d];
    }
}

// ---------------- h = LN(mo + h) ----------------
__global__ __launch_bounds__(256)
void k_addln(const float* __restrict__ mo, float* __restrict__ h,
             const float* __restrict__ w, const float* __restrict__ bias) {
    int m = blockIdx.x, o = threadIdx.x;
    __shared__ float sred[8];
    float v = mo[(size_t)m * D_MODEL + o] + h[(size_t)m * D_MODEL + o];
    float2 s = block_reduce2(v, v * v, sred);
    float mu = s.x * (1.f / D_MODEL);
    float var = s.y * (1.f / D_MODEL) - mu * mu;
    h[(size_t)m * D_MODEL + o] = (v - mu) * rsqrtf(var + EPS) * w[o] + bias[o];
}

// ---------------- masked mean pool + head ----------------
__global__ __launch_bounds__(256)
void k_pool_head(const float* __restrict__ h, const int* __restrict__ len,
                 const float* __restrict__ hw, const float* __restrict__ hb,
                 float* __restrict__ out) {
    int b = blockIdx.x, d = threadIdx.x;
    __shared__ float sp[D_MODEL];
    int Lb = len[b];
    float acc = 0.f;
    for (int l = 0; l < Lb; l++) acc += h[((size_t)b * LSEQ + l) * D_MODEL + d];
    sp[d] = acc / (float)Lb;
    __syncthreads();
    if (d < N_CLS) {
        float o = hb[d];
        const float* wr = hw + (size_t)d * D_MODEL;
        #pragma unroll 8
        for (int k = 0; k < D_MODEL; k++) o = fmaf(sp[k], wr[k], o);
        out[b * N_CLS + d] = o;
    }
}

extern "C" void kernel_launch(void* const* d_in, const int* in_sizes, int n_in,
                              void* d_out, int out_size, void* d_ws, size_t ws_size,
                              hipStream_t stream) {
    const float* x      = (const float*)d_in[0];
    const float* in_w   = (const float*)d_in[1];
    const float* in_b   = (const float*)d_in[2];
    const float* lnin_w = (const float*)d_in[3];
    const float* lnin_b = (const float*)d_in[4];
    const float* inproj = (const float*)d_in[5];
    const float* conv_w = (const float*)d_in[6];
    const float* conv_b = (const float*)d_in[7];
    const float* dt_bias= (const float*)d_in[8];
    const float* A_log  = (const float*)d_in[9];
    const float* Dv     = (const float*)d_in[10];
    const float* norm_w = (const float*)d_in[11];
    const float* outp_w = (const float*)d_in[12];
    const float* ln_w   = (const float*)d_in[13];
    const float* ln_b   = (const float*)d_in[14];
    const float* head_w = (const float*)d_in[15];
    const float* head_b = (const float*)d_in[16];
    const int*   lengths= (const int*)d_in[17];
    float* out = (float*)d_out;

    float* ws    = (float*)d_ws;
    float* h     = ws;
    float* buf1  = h    + (size_t)NTOK * D_MODEL;
    float* xs    = buf1 + (size_t)NTOK * XBCDT;
    float* Bm    = xs   + (size_t)NTOK * D_INNER;
    float* Cm    = Bm   + (size_t)NTOK * D_STATE;
    float* dtv   = Cm   + (size_t)NTOK * D_STATE;
    float* cumdA = dtv  + (size_t)NTOK * NH;
    float* zbuf  = buf1;
    float* F     = buf1 + (size_t)NTOK * D_INNER;   // 3 segs: 6.29M floats in buf1 tail
    float* mo    = Bm;
    float* xp    = buf1;
    float* pre   = buf1 + (size_t)NTOK * 64;
    unsigned short* WP = (unsigned short*)(ws + WS_BASE);
    bool use_pk = (ws_size >= WS_NEED);

    dim3 gIO(D_MODEL / 128, NTOK / 128);
    dim3 g1a((XBCDT + 127) / 128, NTOK / 128);
    dim3 g1b(D_INNER / 128, NTOK / 128);

    if (use_pk) {
        k_pack_weights<<<TOTPK / 256, 256, 0, stream>>>(in_w, inproj, outp_w, WP);
        k_pack_x<<<NTOK * 64 / 256, 256, 0, stream>>>(x, xp);
        k_gemm_as<<<gIO, 256, 0, stream>>>(xp, WP + IN_HI, WP + IN_LO, pre,
                                           NTOK, D_MODEL, 64);
        k_lnio<<<NTOK, 256, 0, stream>>>(pre, in_b, lnin_w, lnin_b, h);
        for (int i = 0; i < NL; i++) {
            const unsigned short* iph = WP + IP_HI + (size_t)i * PROJ * D_MODEL;
            const unsigned short* ipl = WP + IP_LO + (size_t)i * PROJ * D_MODEL;
            k_gemm_as<<<g1a, 256, 0, stream>>>(h, iph + (size_t)D_INNER * D_MODEL,
                                               ipl + (size_t)D_INNER * D_MODEL,
                                               buf1, NTOK, XBCDT, D_MODEL);
            k_conv<<<NTOK, 256, 0, stream>>>(buf1, conv_w + i * DCONV * CONV_CH,
                                             conv_b + i * CONV_CH, dt_bias + i * NH,
                                             xs, Bm, Cm, dtv);
            k_gemm_as<<<g1b, 256, 0, stream>>>(h, iph, ipl, zbuf, NTOK, D_INNER, D_MODEL);
            k_scan_seg<<<BSZ * NH * SSEG, 256, 0, stream>>>(xs, Bm, Cm, dtv,
                                                            A_log + i * NH, Dv + i * NH,
                                                            xs, F, cumdA);
            k_seg_fix<<<BSZ * NH * (SSEG - 1), 256, 0, stream>>>(Cm, cumdA, F, xs);
            k_gate<<<NTOK, 256, 0, stream>>>(xs, zbuf, norm_w + i * D_INNER);
            k_gemm_as<<<gIO, 256, 0, stream>>>(xs, WP + OP_HI + (size_t)i * D_MODEL * D_INNER,
                                               WP + OP_LO + (size_t)i * D_MODEL * D_INNER,
                                               mo, NTOK, D_MODEL, D_INNER);
            k_addln<<<NTOK, 256, 0, stream>>>(mo, h, ln_w + i * D_MODEL, ln_b + i * D_MODEL);
        }
    } else {
        // fallback: round-4 proven pipeline (no WP region needed)
        float* wp = Bm;
        k_pack_x<<<NTOK * 64 / 256, 256, 0, stream>>>(x, xp);
        k_pack_w<<<64, 256, 0, stream>>>(in_w, wp);
        k_gemm_mfma<<<gIO, 256, 0, stream>>>(xp, wp, pre, NTOK, D_MODEL, 64);
        k_lnio<<<NTOK, 256, 0, stream>>>(pre, in_b, lnin_w, lnin_b, h);
        for (int i = 0; i < NL; i++) {
            const float* W = inproj + (size_t)i * PROJ * D_MODEL;
            k_gemm_mfma<<<g1a, 256, 0, stream>>>(h, W + (size_t)D_INNER * D_MODEL,
                                                 buf1, NTOK, XBCDT, D_MODEL);
            k_conv<<<NTOK, 256, 0, stream>>>(buf1, conv_w + i * DCONV * CONV_CH,
                                             conv_b + i * CONV_CH, dt_bias + i * NH,
                                             xs, Bm, Cm, dtv);
            k_gemm_mfma<<<g1b, 256, 0, stream>>>(h, W, zbuf, NTOK, D_INNER, D_MODEL);
            k_scan_seg<<<BSZ * NH * SSEG, 256, 0, stream>>>(xs, Bm, Cm, dtv,
                                                            A_log + i * NH, Dv + i * NH,
                                                            xs, F, cumdA);
            k_seg_fix<<<BSZ * NH * (SSEG - 1), 256, 0, stream>>>(Cm, cumdA, F, xs);
            k_gate<<<NTOK, 256, 0, stream>>>(xs, zbuf, norm_w + i * D_INNER);
            k_gemm_mfma<<<gIO, 256, 0, stream>>>(xs, outp_w + (size_t)i * D_MODEL * D_INNER,
                                                 mo, NTOK, D_MODEL, D_INNER);
            k_addln<<<NTOK, 256, 0, stream>>>(mo, h, ln_w + i * D_MODEL, ln_b + i * D_MODEL);
        }
    }

    k_pool_head<<<BSZ, 256, 0, stream>>>(h, lengths, head_w, head_b, out);
}

// Round 6
// 3010.634 us; speedup vs baseline: 2.3183x; 1.0010x over previous
//
#include <hip/hip_runtime.h>
#include <math.h>

#define D_IN 63
#define D_MODEL 256
#define N_CLS 14
#define NL 4
#define D_INNER 512
#define D_STATE 128
#define NH 8
#define HP 64
#define DCONV 4
#define CONV_CH 768
#define PROJ 1288
#define XBCDT 776
#define EPS 1e-5f
#define BSZ 32
#define LSEQ 1024
#define NTOK (BSZ*LSEQ)

#define SSEG 4
#define TSEG (LSEQ/SSEG)
#define CTS 8              /* staged steps per chunk (scan kernels) */

// weight-pack region (ushort offsets)
#define S_IN   16384
#define S_IP   1318912
#define S_OP   524288
#define IN_HI  0
#define IN_LO  16384
#define IP_HI  32768
#define IP_LO  (32768 + S_IP)
#define OP_HI  (32768 + 2*S_IP)
#define OP_LO  (OP_HI + S_OP)
#define TOTPK  (S_IN + S_IP + S_OP)
#define WS_BASE ((size_t)NTOK * 1816)
#define WS_NEED ((WS_BASE + (size_t)TOTPK) * 4)

typedef __attribute__((ext_vector_type(8))) short bf16x8;
typedef __attribute__((ext_vector_type(4))) float f32x4;

__device__ __forceinline__ float silu_f(float x) { return x / (1.f + expf(-x)); }

__device__ __forceinline__ unsigned short f2bf(float x) {
    union { float f; unsigned u; } v; v.f = x;
    unsigned r = v.u + 0x7FFFu + ((v.u >> 16) & 1u);
    return (unsigned short)(r >> 16);
}
__device__ __forceinline__ float bf2f(unsigned short h) {
    union { float f; unsigned u; } v; v.u = ((unsigned)h) << 16; return v.f;
}

// swizzle for 8 groups of 16 values: value n -> LDS position, so that at inner
// iteration i the 8 q-groups' float4 reads hit 8 disjoint bank quads.
__device__ __forceinline__ int swz8(int n) {
    int g = n >> 4, j = (n >> 2) & 3, e = n & 3;
    return (g << 4) + (((j + (g >> 1)) & 3) << 2) + e;
}

__device__ __forceinline__ float2 block_reduce2(float a, float b, float* sred) {
    #pragma unroll
    for (int off = 32; off >= 1; off >>= 1) {
        a += __shfl_xor(a, off);
        b += __shfl_xor(b, off);
    }
    int wid = threadIdx.x >> 6, lane = threadIdx.x & 63;
    if (lane == 0) { sred[wid * 2] = a; sred[wid * 2 + 1] = b; }
    __syncthreads();
    a = sred[0] + sred[2] + sred[4] + sred[6];
    b = sred[1] + sred[3] + sred[5] + sred[7];
    __syncthreads();
    return make_float2(a, b);
}

// ---------------- pack all weights to bf16 hi/lo planes ----------------
__global__ __launch_bounds__(256)
void k_pack_weights(const float* __restrict__ in_w, const float* __restrict__ inproj,
                    const float* __restrict__ outp, unsigned short* __restrict__ WP) {
    int idx = blockIdx.x * 256 + threadIdx.x;
    float v; int hi_off, lo_off;
    if (idx < S_IN) {
        int n = idx >> 6, k = idx & 63;
        v = (k < D_IN) ? in_w[n * D_IN + k] : 0.f;
        hi_off = IN_HI + idx; lo_off = IN_LO + idx;
    } else if (idx < S_IN + S_IP) {
        int j = idx - S_IN;
        v = inproj[j];
        hi_off = IP_HI + j; lo_off = IP_LO + j;
    } else {
        int j = idx - S_IN - S_IP;
        v = outp[j];
        hi_off = OP_HI + j; lo_off = OP_LO + j;
    }
    unsigned short h = f2bf(v);
    unsigned short l = f2bf(v - bf2f(h));
    WP[hi_off] = h; WP[lo_off] = l;
}

// ---------------- MFMA GEMM, A fp32 (in-kernel trunc split), B pre-packed ----------
#define LDKP 40
__global__ __launch_bounds__(256, 2)
void k_gemm_as(const float* __restrict__ A, const unsigned short* __restrict__ Bhg,
               const unsigned short* __restrict__ Blg, float* __restrict__ C,
               int M, int N, int K) {
    __shared__ unsigned short Ah[128][LDKP], Al[128][LDKP];
    __shared__ unsigned short Bh[128][LDKP], Bl[128][LDKP];
    int n0 = blockIdx.x * 128, m0 = blockIdx.y * 128;
    int tid = threadIdx.x;
    int srow = tid >> 1, sk = (tid & 1) * 16;
    int lane = tid & 63, wave = tid >> 6;
    int wm = (wave >> 1) * 64, wn = (wave & 1) * 64;
    int ln = lane & 15, quad = lane >> 4;
    f32x4 acc[4][4];
    #pragma unroll
    for (int i = 0; i < 4; i++)
        #pragma unroll
        for (int j = 0; j < 4; j++) acc[i][j] = (f32x4){0.f, 0.f, 0.f, 0.f};
    const float* Ap = A + (size_t)(m0 + srow) * K + sk;
    const unsigned short* Bhp = Bhg + (size_t)(n0 + srow) * K + sk;
    const unsigned short* Blp = Blg + (size_t)(n0 + srow) * K + sk;
    bool bval = (n0 + srow) < N;
    uint4 z4 = make_uint4(0u, 0u, 0u, 0u);
    for (int k0 = 0; k0 < K; k0 += 32) {
        float av[16];
        #pragma unroll
        for (int i = 0; i < 4; i++)
            *(float4*)&av[4 * i] = *(const float4*)(Ap + k0 + 4 * i);
        uint4 bh0 = bval ? *(const uint4*)(Bhp + k0) : z4;
        uint4 bh1 = bval ? *(const uint4*)(Bhp + k0 + 8) : z4;
        uint4 bl0 = bval ? *(const uint4*)(Blp + k0) : z4;
        uint4 bl1 = bval ? *(const uint4*)(Blp + k0 + 8) : z4;
        unsigned hp[8], lp[8];
        #pragma unroll
        for (int j = 0; j < 8; j++) {
            float a0 = av[2 * j], a1 = av[2 * j + 1];
            unsigned u0 = __float_as_uint(a0), u1 = __float_as_uint(a1);
            unsigned h0 = u0 & 0xFFFF0000u, h1 = u1 & 0xFFFF0000u;
            float r0 = a0 - __uint_as_float(h0);
            float r1 = a1 - __uint_as_float(h1);
            hp[j] = (u0 >> 16) | h1;
            lp[j] = (__float_as_uint(r0) >> 16) | (__float_as_uint(r1) & 0xFFFF0000u);
        }
        __syncthreads();
        *(uint4*)&Ah[srow][sk]     = *(uint4*)&hp[0];
        *(uint4*)&Ah[srow][sk + 8] = *(uint4*)&hp[4];
        *(uint4*)&Al[srow][sk]     = *(uint4*)&lp[0];
        *(uint4*)&Al[srow][sk + 8] = *(uint4*)&lp[4];
        *(uint4*)&Bh[srow][sk]     = bh0;
        *(uint4*)&Bh[srow][sk + 8] = bh1;
        *(uint4*)&Bl[srow][sk]     = bl0;
        *(uint4*)&Bl[srow][sk + 8] = bl1;
        __syncthreads();
        bf16x8 fah[4], fal[4], fbh[4], fbl[4];
        #pragma unroll
        for (int t = 0; t < 4; t++) {
            fah[t] = *(const bf16x8*)&Ah[wm + t * 16 + ln][quad * 8];
            fal[t] = *(const bf16x8*)&Al[wm + t * 16 + ln][quad * 8];
            fbh[t] = *(const bf16x8*)&Bh[wn + t * 16 + ln][quad * 8];
            fbl[t] = *(const bf16x8*)&Bl[wn + t * 16 + ln][quad * 8];
        }
        #pragma unroll
        for (int mt = 0; mt < 4; mt++)
            #pragma unroll
            for (int nt = 0; nt < 4; nt++) {
                acc[mt][nt] = __builtin_amdgcn_mfma_f32_16x16x32_bf16(fal[mt], fbh[nt], acc[mt][nt], 0, 0, 0);
                acc[mt][nt] = __builtin_amdgcn_mfma_f32_16x16x32_bf16(fah[mt], fbl[nt], acc[mt][nt], 0, 0, 0);
                acc[mt][nt] = __builtin_amdgcn_mfma_f32_16x16x32_bf16(fah[mt], fbh[nt], acc[mt][nt], 0, 0, 0);
            }
    }
    #pragma unroll
    for (int mt = 0; mt < 4; mt++)
        #pragma unroll
        for (int nt = 0; nt < 4; nt++) {
            int cn = n0 + wn + nt * 16 + ln;
            if (cn < N) {
                #pragma unroll
                for (int r = 0; r < 4; r++) {
                    int cm = m0 + wm + mt * 16 + quad * 4 + r;
                    C[(size_t)cm * N + cn] = acc[mt][nt][r];
                }
            }
        }
}

// ---------------- fallback GEMM: fp32 A and B, in-kernel split ----------------
__global__ __launch_bounds__(256, 2)
void k_gemm_mfma(const float* __restrict__ A, const float* __restrict__ B,
                 float* __restrict__ C, int M, int N, int K) {
    __shared__ unsigned short Ah[128][LDKP], Al[128][LDKP];
    __shared__ unsigned short Bh[128][LDKP], Bl[128][LDKP];
    int n0 = blockIdx.x * 128, m0 = blockIdx.y * 128;
    int tid = threadIdx.x;
    int srow = tid >> 1, sk = (tid & 1) * 16;
    int lane = tid & 63, wave = tid >> 6;
    int wm = (wave >> 1) * 64, wn = (wave & 1) * 64;
    int ln = lane & 15, quad = lane >> 4;
    f32x4 acc[4][4];
    #pragma unroll
    for (int i = 0; i < 4; i++)
        #pragma unroll
        for (int j = 0; j < 4; j++) acc[i][j] = (f32x4){0.f, 0.f, 0.f, 0.f};
    const float* Ap = A + (size_t)(m0 + srow) * K + sk;
    const float* Bp = B + (size_t)(n0 + srow) * K + sk;
    bool bval = (n0 + srow) < N;
    for (int k0 = 0; k0 < K; k0 += 32) {
        float av[16], bv[16];
        #pragma unroll
        for (int i = 0; i < 4; i++) {
            *(float4*)&av[4 * i] = *(const float4*)(Ap + k0 + 4 * i);
            *(float4*)&bv[4 * i] = bval ? *(const float4*)(Bp + k0 + 4 * i)
                                        : make_float4(0.f, 0.f, 0.f, 0.f);
        }
        __syncthreads();
        #pragma unroll
        for (int g = 0; g < 2; g++) {
            unsigned hiA[4], loA[4], hiB[4], loB[4];
            #pragma unroll
            for (int j = 0; j < 4; j++) {
                float a0 = av[8 * g + 2 * j], a1 = av[8 * g + 2 * j + 1];
                unsigned short h0 = f2bf(a0), h1 = f2bf(a1);
                unsigned short l0 = f2bf(a0 - bf2f(h0)), l1 = f2bf(a1 - bf2f(h1));
                hiA[j] = (unsigned)h0 | ((unsigned)h1 << 16);
                loA[j] = (unsigned)l0 | ((unsigned)l1 << 16);
                float b0 = bv[8 * g + 2 * j], b1 = bv[8 * g + 2 * j + 1];
                unsigned short g0 = f2bf(b0), g1 = f2bf(b1);
                unsigned short m0s = f2bf(b0 - bf2f(g0)), m1s = f2bf(b1 - bf2f(g1));
                hiB[j] = (unsigned)g0 | ((unsigned)g1 << 16);
                loB[j] = (unsigned)m0s | ((unsigned)m1s << 16);
            }
            *(uint4*)&Ah[srow][sk + 8 * g] = *(uint4*)hiA;
            *(uint4*)&Al[srow][sk + 8 * g] = *(uint4*)loA;
            *(uint4*)&Bh[srow][sk + 8 * g] = *(uint4*)hiB;
            *(uint4*)&Bl[srow][sk + 8 * g] = *(uint4*)loB;
        }
        __syncthreads();
        bf16x8 fah[4], fal[4], fbh[4], fbl[4];
        #pragma unroll
        for (int t = 0; t < 4; t++) {
            fah[t] = *(const bf16x8*)&Ah[wm + t * 16 + ln][quad * 8];
            fal[t] = *(const bf16x8*)&Al[wm + t * 16 + ln][quad * 8];
            fbh[t] = *(const bf16x8*)&Bh[wn + t * 16 + ln][quad * 8];
            fbl[t] = *(const bf16x8*)&Bl[wn + t * 16 + ln][quad * 8];
        }
        #pragma unroll
        for (int mt = 0; mt < 4; mt++)
            #pragma unroll
            for (int nt = 0; nt < 4; nt++) {
                acc[mt][nt] = __builtin_amdgcn_mfma_f32_16x16x32_bf16(fal[mt], fbh[nt], acc[mt][nt], 0, 0, 0);
                acc[mt][nt] = __builtin_amdgcn_mfma_f32_16x16x32_bf16(fah[mt], fbl[nt], acc[mt][nt], 0, 0, 0);
                acc[mt][nt] = __builtin_amdgcn_mfma_f32_16x16x32_bf16(fah[mt], fbh[nt], acc[mt][nt], 0, 0, 0);
            }
    }
    #pragma unroll
    for (int mt = 0; mt < 4; mt++)
        #pragma unroll
        for (int nt = 0; nt < 4; nt++) {
            int cn = n0 + wn + nt * 16 + ln;
            if (cn < N) {
                #pragma unroll
                for (int r = 0; r < 4; r++) {
                    int cm = m0 + wm + mt * 16 + quad * 4 + r;
                    C[(size_t)cm * N + cn] = acc[mt][nt][r];
                }
            }
        }
}

// ---------------- pack x / pack w ----------------
__global__ __launch_bounds__(256)
void k_pack_x(const float* __restrict__ x, float* __restrict__ xp) {
    size_t idx = (size_t)blockIdx.x * 256 + threadIdx.x;
    int k = (int)(idx & 63);
    size_t m = idx >> 6;
    xp[idx] = (k < D_IN) ? x[m * D_IN + k] : 0.f;
}
__global__ __launch_bounds__(256)
void k_pack_w(const float* __restrict__ w, float* __restrict__ wp) {
    int idx = blockIdx.x * 256 + threadIdx.x;
    int k = idx & 63, n = idx >> 6;
    wp[idx] = (k < D_IN) ? w[n * D_IN + k] : 0.f;
}

// ---------------- h = LN(pre + in_b) ----------------
__global__ __launch_bounds__(256)
void k_lnio(const float* __restrict__ pre, const float* __restrict__ bias,
            const float* __restrict__ gw, const float* __restrict__ gb,
            float* __restrict__ h) {
    int m = blockIdx.x, o = threadIdx.x;
    __shared__ float sred[8];
    float v = pre[(size_t)m * D_MODEL + o] + bias[o];
    float2 s = block_reduce2(v, v * v, sred);
    float mu = s.x * (1.f / D_MODEL);
    float var = s.y * (1.f / D_MODEL) - mu * mu;
    h[(size_t)m * D_MODEL + o] = (v - mu) * rsqrtf(var + EPS) * gw[o] + gb[o];
}

// ---------------- conv (causal depthwise k=4) + silu + dt ----------------
__global__ __launch_bounds__(256)
void k_conv(const float* __restrict__ xbc, const float* __restrict__ cw,
            const float* __restrict__ cb, const float* __restrict__ dtb,
            float* __restrict__ xs, float* __restrict__ Bm, float* __restrict__ Cm,
            float* __restrict__ dtv) {
    int m = blockIdx.x;
    int l = m & (LSEQ - 1);
    int tid = threadIdx.x;
    #pragma unroll
    for (int it = 0; it < 3; it++) {
        int c = tid + it * 256;
        float acc = cb[c];
        #pragma unroll
        for (int k = 0; k < DCONV; k++) {
            int lp = l - (DCONV - 1) + k;
            if (lp >= 0)
                acc = fmaf(cw[k * CONV_CH + c],
                           xbc[(size_t)(m - (DCONV - 1) + k) * XBCDT + c], acc);
        }
        float v = silu_f(acc);
        if (c < D_INNER) xs[(size_t)m * D_INNER + c] = v;
        else if (c < D_INNER + D_STATE) Bm[(size_t)m * D_STATE + (c - D_INNER)] = v;
        else Cm[(size_t)m * D_STATE + (c - D_INNER - D_STATE)] = v;
    }
    if (tid < NH) {
        float draw = xbc[(size_t)m * XBCDT + CONV_CH + tid] + dtb[tid];
        float dt = draw > 20.f ? draw : log1pf(expf(draw));
        dtv[m * NH + tid] = dt;
    }
}

// ---------------- Pass A: segment-local scan, p-split (2 blocks per (b,h,seg)) ------
// thread: q = tid&7 owns 16 n-values, p = (tid>>3) + pb*32.
__global__ __launch_bounds__(256, 8)
void k_scan_seg(const float* __restrict__ xs, const float* __restrict__ Bm,
                const float* __restrict__ Cm, const float* __restrict__ dtv,
                const float* __restrict__ Alog, const float* __restrict__ Dvec,
                float* __restrict__ y, float* __restrict__ F,
                float* __restrict__ cumdA) {
    int blk = blockIdx.x;
    int pb  = blk & 1;
    int seg = (blk >> 1) & (SSEG - 1);
    int bh  = blk >> 3;
    int b = bh >> 3, hh = bh & 7;
    int tid = threadIdx.x;
    int q = tid & 7;
    int pl = tid >> 3;               // 0..31
    int p = pl + pb * 32;
    __shared__ __align__(16) float sBC[2 * CTS * 128];
    __shared__ __align__(16) float sX[CTS][32];
    __shared__ float sdt[CTS], sdA[CTS], srdA[CTS];
    float hst[16];
    #pragma unroll
    for (int i = 0; i < 16; i++) hst[i] = 0.f;
    float Dh = Dvec[hh];
    float Ahv = -expf(Alog[hh]);
    float c_run = 1.f;
    const size_t base = (size_t)b * LSEQ + (size_t)seg * TSEG;
    int col = tid & 127, half = tid >> 7;
    int sw = swz8(col);
    int xc = tid & 31, xh = tid >> 5;     // 8 steps x 32 p
    int q2 = q >> 1;

    for (int c0 = 0; c0 < TSEG; c0 += CTS) {
        #pragma unroll
        for (int u = 0; u < 4; u++) {
            int s = 2 * u + half;
            size_t m = base + c0 + s;
            sBC[s * 128 + sw] = Bm[m * D_STATE + col];
            sBC[(CTS + s) * 128 + sw] = Cm[m * D_STATE + col];
        }
        sX[xh][xc] = xs[(base + c0 + xh) * D_INNER + hh * HP + pb * 32 + xc];
        if (tid < CTS) {
            float dtl = dtv[(base + c0 + tid) * NH + hh];
            float e = fmaxf(dtl * Ahv, -37.f);
            sdt[tid] = dtl;
            sdA[tid] = expf(e);
            srdA[tid] = expf(-e);
        }
        __syncthreads();
        if (pb == 0 && tid == 0) {
            float cg = c_run;
            for (int s = 0; s < CTS; s++) {
                cg *= sdA[s];
                cumdA[(base + c0 + s) * NH + hh] = cg;
            }
            c_run = cg;
        } else if (tid == 0) {
            for (int s = 0; s < CTS; s++) c_run *= sdA[s];
        }
        float cc = 1.f, rc = 1.f;
        #pragma unroll
        for (int s = 0; s < CTS; s++) {
            float dAl = sdA[s], dtl = sdt[s];
            float ccn = cc * dAl;
            if (ccn < 1e-18f) {            // rare, wave-uniform rebase
                #pragma unroll
                for (int i = 0; i < 16; i++) hst[i] *= cc;
                rc = srdA[s];
                ccn = dAl;
            } else {
                rc *= srdA[s];
            }
            cc = ccn;
            float xv = sX[s][pl];
            float tmp = dtl * xv * rc;
            float yp = 0.f;
            #pragma unroll
            for (int i = 0; i < 4; i++) {
                int off = (q << 4) + (((i + q2) & 3) << 2);
                float4 bv = *(const float4*)&sBC[s * 128 + off];
                float4 cv = *(const float4*)&sBC[(CTS + s) * 128 + off];
                hst[4*i+0] = fmaf(tmp, bv.x, hst[4*i+0]); yp = fmaf(hst[4*i+0], cv.x, yp);
                hst[4*i+1] = fmaf(tmp, bv.y, hst[4*i+1]); yp = fmaf(hst[4*i+1], cv.y, yp);
                hst[4*i+2] = fmaf(tmp, bv.z, hst[4*i+2]); yp = fmaf(hst[4*i+2], cv.z, yp);
                hst[4*i+3] = fmaf(tmp, bv.w, hst[4*i+3]); yp = fmaf(hst[4*i+3], cv.w, yp);
            }
            yp += __shfl_xor(yp, 1);
            yp += __shfl_xor(yp, 2);
            yp += __shfl_xor(yp, 4);
            if (q == 0) y[(base + c0 + s) * D_INNER + hh * HP + p] = fmaf(Dh, xv, cc * yp);
            if (s == CTS - 1) {            // flush -> hst = true state
                #pragma unroll
                for (int i = 0; i < 16; i++) hst[i] *= cc;
            }
        }
        __syncthreads();
    }
    if (seg < SSEG - 1) {
        float* Fp = F + (((size_t)bh * (SSEG - 1) + seg) * HP + p) * D_STATE + (q << 4);
        #pragma unroll
        for (int i = 0; i < 4; i++)
            *(float4*)(Fp + 4 * i) = make_float4(hst[4*i], hst[4*i+1], hst[4*i+2], hst[4*i+3]);
    }
}

// ---------------- Pass C (fused combine), p-split: y_t += cumdA_t*(C_t.h_in) --------
__global__ __launch_bounds__(256, 8)
void k_seg_fix(const float* __restrict__ Cm, const float* __restrict__ cumdA,
               const float* __restrict__ F, float* __restrict__ y) {
    int blk = blockIdx.x;
    int pb = blk & 1;
    int t2 = blk >> 1;
    int bh = t2 / (SSEG - 1);
    int seg = t2 - bh * (SSEG - 1) + 1;
    int b = bh >> 3, hh = bh & 7;
    int tid = threadIdx.x;
    int q = tid & 7;
    int pl = tid >> 3;
    int p = pl + pb * 32;
    int q2 = q >> 1;
    float hin[16];
    #pragma unroll
    for (int i = 0; i < 16; i++) hin[i] = 0.f;
    for (int s = 0; s < seg; s++) {
        float P = cumdA[((size_t)b * LSEQ + (size_t)(s + 1) * TSEG - 1) * NH + hh];
        const float* Fp = F + (((size_t)bh * (SSEG - 1) + s) * HP + p) * D_STATE + (q << 4);
        #pragma unroll
        for (int i = 0; i < 4; i++) {
            float4 f = *(const float4*)(Fp + 4 * i);
            hin[4*i+0] = fmaf(hin[4*i+0], P, f.x);
            hin[4*i+1] = fmaf(hin[4*i+1], P, f.y);
            hin[4*i+2] = fmaf(hin[4*i+2], P, f.z);
            hin[4*i+3] = fmaf(hin[4*i+3], P, f.w);
        }
    }
    __shared__ __align__(16) float sC[CTS * 128];
    __shared__ float scd[CTS];
    const size_t base = (size_t)b * LSEQ + (size_t)seg * TSEG;
    int col = tid & 127, half = tid >> 7;
    int sw = swz8(col);
    for (int c0 = 0; c0 < TSEG; c0 += CTS) {
        #pragma unroll
        for (int u = 0; u < 4; u++) {
            int s = 2 * u + half;
            sC[s * 128 + sw] = Cm[(base + c0 + s) * D_STATE + col];
        }
        if (tid < CTS) scd[tid] = cumdA[(base + c0 + tid) * NH + hh];
        __syncthreads();
        #pragma unroll
        for (int s = 0; s < CTS; s++) {
            float yp = 0.f;
            #pragma unroll
            for (int i = 0; i < 4; i++) {
                int off = (q << 4) + (((i + q2) & 3) << 2);
                float4 cv = *(const float4*)&sC[s * 128 + off];
                yp = fmaf(hin[4*i+0], cv.x, yp);
                yp = fmaf(hin[4*i+1], cv.y, yp);
                yp = fmaf(hin[4*i+2], cv.z, yp);
                yp = fmaf(hin[4*i+3], cv.w, yp);
            }
            yp += __shfl_xor(yp, 1);
            yp += __shfl_xor(yp, 2);
            yp += __shfl_xor(yp, 4);
            if (q == 0) {
                size_t idx = (base + c0 + s) * D_INNER + hh * HP + p;
                y[idx] += scd[s] * yp;
            }
        }
        __syncthreads();
    }
}

// ---------------- gated RMSNorm (in-place on y) ----------------
__global__ __launch_bounds__(256)
void k_gate(float* __restrict__ y, const float* __restrict__ zbuf,
            const float* __restrict__ nw) {
    int m = blockIdx.x, tid = threadIdx.x;
    __shared__ float sred[8];
    float g[2];
    #pragma unroll
    for (int j = 0; j < 2; j++) {
        int d = tid + j * 256;
        float z = zbuf[(size_t)m * D_INNER + d];
        g[j] = y[(size_t)m * D_INNER + d] * silu_f(z);
    }
    float2 s = block_reduce2(g[0] * g[0] + g[1] * g[1], 0.f, sred);
    float r = rsqrtf(s.x * (1.f / D_INNER) + EPS);
    #pragma unroll
    for (int j = 0; j < 2; j++) {
        int d = tid + j * 256;
        y[(size_t)m * D_INNER + d] = g[j] * r * nw[d];
    }
}

// ---------------- h = LN(mo + h) ----------------
__global__ __launch_bounds__(256)
void k_addln(const float* __restrict__ mo, float* __restrict__ h,
             const float* __restrict__ w, const float* __restrict__ bias) {
    int m = blockIdx.x, o = threadIdx.x;
    __shared__ float sred[8];
    float v = mo[(size_t)m * D_MODEL + o] + h[(size_t)m * D_MODEL + o];
    float2 s = block_reduce2(v, v * v, sred);
    float mu = s.x * (1.f / D_MODEL);
    float var = s.y * (1.f / D_MODEL) - mu * mu;
    h[(size_t)m * D_MODEL + o] = (v - mu) * rsqrtf(var + EPS) * w[o] + bias[o];
}

// ---------------- pooled partial sums: 16 chunks of 64 tokens per batch ----------
__global__ __launch_bounds__(256)
void k_pool_part(const float* __restrict__ h, const int* __restrict__ len,
                 float* __restrict__ part) {
    int blk = blockIdx.x;
    int b = blk >> 4, ch = blk & 15;
    int d = threadIdx.x;
    int Lb = len[b];
    int l0 = ch * 64;
    int le = min(l0 + 64, Lb);
    float acc = 0.f;
    for (int l = l0; l < le; l++) acc += h[((size_t)b * LSEQ + l) * D_MODEL + d];
    part[(size_t)blk * D_MODEL + d] = acc;
}

// ---------------- final head: pooled mean + 14-way linear ----------------
__global__ __launch_bounds__(256)
void k_head(const float* __restrict__ part, const int* __restrict__ len,
            const float* __restrict__ hw, const float* __restrict__ hb,
            float* __restrict__ out) {
    int b = blockIdx.x, d = threadIdx.x;
    __shared__ float sp[D_MODEL];
    float a = 0.f;
    #pragma unroll
    for (int c = 0; c < 16; c++) a += part[(size_t)(b * 16 + c) * D_MODEL + d];
    sp[d] = a / (float)len[b];
    __syncthreads();
    if (d < N_CLS) {
        float o = hb[d];
        const float* wr = hw + (size_t)d * D_MODEL;
        #pragma unroll 8
        for (int k = 0; k < D_MODEL; k++) o = fmaf(sp[k], wr[k], o);
        out[b * N_CLS + d] = o;
    }
}

extern "C" void kernel_launch(void* const* d_in, const int* in_sizes, int n_in,
                              void* d_out, int out_size, void* d_ws, size_t ws_size,
                              hipStream_t stream) {
    const float* x      = (const float*)d_in[0];
    const float* in_w   = (const float*)d_in[1];
    const float* in_b   = (const float*)d_in[2];
    const float* lnin_w = (const float*)d_in[3];
    const float* lnin_b = (const float*)d_in[4];
    const float* inproj = (const float*)d_in[5];
    const float* conv_w = (const float*)d_in[6];
    const float* conv_b = (const float*)d_in[7];
    const float* dt_bias= (const float*)d_in[8];
    const float* A_log  = (const float*)d_in[9];
    const float* Dv     = (const float*)d_in[10];
    const float* norm_w = (const float*)d_in[11];
    const float* outp_w = (const float*)d_in[12];
    const float* ln_w   = (const float*)d_in[13];
    const float* ln_b   = (const float*)d_in[14];
    const float* head_w = (const float*)d_in[15];
    const float* head_b = (const float*)d_in[16];
    const int*   lengths= (const int*)d_in[17];
    float* out = (float*)d_out;

    float* ws    = (float*)d_ws;
    float* h     = ws;
    float* buf1  = h    + (size_t)NTOK * D_MODEL;
    float* xs    = buf1 + (size_t)NTOK * XBCDT;
    float* Bm    = xs   + (size_t)NTOK * D_INNER;
    float* Cm    = Bm   + (size_t)NTOK * D_STATE;
    float* dtv   = Cm   + (size_t)NTOK * D_STATE;
    float* cumdA = dtv  + (size_t)NTOK * NH;
    float* zbuf  = buf1;
    float* F     = buf1 + (size_t)NTOK * D_INNER;   // 3 segs * 256 bh * 8192
    float* mo    = Bm;
    float* xp    = buf1;
    float* pre   = buf1 + (size_t)NTOK * 64;
    float* poolp = buf1;                            // 32*16*256 floats (dead region)
    unsigned short* WP = (unsigned short*)(ws + WS_BASE);
    bool use_pk = (ws_size >= WS_NEED);

    dim3 gIO(D_MODEL / 128, NTOK / 128);
    dim3 g1a((XBCDT + 127) / 128, NTOK / 128);
    dim3 g1b(D_INNER / 128, NTOK / 128);
    int gScan = BSZ * NH * SSEG * 2;
    int gFix  = BSZ * NH * (SSEG - 1) * 2;

    if (use_pk) {
        k_pack_weights<<<TOTPK / 256, 256, 0, stream>>>(in_w, inproj, outp_w, WP);
        k_pack_x<<<NTOK * 64 / 256, 256, 0, stream>>>(x, xp);
        k_gemm_as<<<gIO, 256, 0, stream>>>(xp, WP + IN_HI, WP + IN_LO, pre,
                                           NTOK, D_MODEL, 64);
        k_lnio<<<NTOK, 256, 0, stream>>>(pre, in_b, lnin_w, lnin_b, h);
        for (int i = 0; i < NL; i++) {
            const unsigned short* iph = WP + IP_HI + (size_t)i * PROJ * D_MODEL;
            const unsigned short* ipl = WP + IP_LO + (size_t)i * PROJ * D_MODEL;
            k_gemm_as<<<g1a, 256, 0, stream>>>(h, iph + (size_t)D_INNER * D_MODEL,
                                               ipl + (size_t)D_INNER * D_MODEL,
                                               buf1, NTOK, XBCDT, D_MODEL);
            k_conv<<<NTOK, 256, 0, stream>>>(buf1, conv_w + i * DCONV * CONV_CH,
                                             conv_b + i * CONV_CH, dt_bias + i * NH,
                                             xs, Bm, Cm, dtv);
            k_gemm_as<<<g1b, 256, 0, stream>>>(h, iph, ipl, zbuf, NTOK, D_INNER, D_MODEL);
            k_scan_seg<<<gScan, 256, 0, stream>>>(xs, Bm, Cm, dtv,
                                                  A_log + i * NH, Dv + i * NH,
                                                  xs, F, cumdA);
            k_seg_fix<<<gFix, 256, 0, stream>>>(Cm, cumdA, F, xs);
            k_gate<<<NTOK, 256, 0, stream>>>(xs, zbuf, norm_w + i * D_INNER);
            k_gemm_as<<<gIO, 256, 0, stream>>>(xs, WP + OP_HI + (size_t)i * D_MODEL * D_INNER,
                                               WP + OP_LO + (size_t)i * D_MODEL * D_INNER,
                                               mo, NTOK, D_MODEL, D_INNER);
            k_addln<<<NTOK, 256, 0, stream>>>(mo, h, ln_w + i * D_MODEL, ln_b + i * D_MODEL);
        }
    } else {
        float* wp = Bm;
        k_pack_x<<<NTOK * 64 / 256, 256, 0, stream>>>(x, xp);
        k_pack_w<<<64, 256, 0, stream>>>(in_w, wp);
        k_gemm_mfma<<<gIO, 256, 0, stream>>>(xp, wp, pre, NTOK, D_MODEL, 64);
        k_lnio<<<NTOK, 256, 0, stream>>>(pre, in_b, lnin_w, lnin_b, h);
        for (int i = 0; i < NL; i++) {
            const float* W = inproj + (size_t)i * PROJ * D_MODEL;
            k_gemm_mfma<<<g1a, 256, 0, stream>>>(h, W + (size_t)D_INNER * D_MODEL,
                                                 buf1, NTOK, XBCDT, D_MODEL);
            k_conv<<<NTOK, 256, 0, stream>>>(buf1, conv_w + i * DCONV * CONV_CH,
                                             conv_b + i * CONV_CH, dt_bias + i * NH,
                                             xs, Bm, Cm, dtv);
            k_gemm_mfma<<<g1b, 256, 0, stream>>>(h, W, zbuf, NTOK, D_INNER, D_MODEL);
            k_scan_seg<<<gScan, 256, 0, stream>>>(xs, Bm, Cm, dtv,
                                                  A_log + i * NH, Dv + i * NH,
                                                  xs, F, cumdA);
            k_seg_fix<<<gFix, 256, 0, stream>>>(Cm, cumdA, F, xs);
            k_gate<<<NTOK, 256, 0, stream>>>(xs, zbuf, norm_w + i * D_INNER);
            k_gemm_mfma<<<gIO, 256, 0, stream>>>(xs, outp_w + (size_t)i * D_MODEL * D_INNER,
                                                 mo, NTOK, D_MODEL, D_INNER);
            k_addln<<<NTOK, 256, 0, stream>>>(mo, h, ln_w + i * D_MODEL, ln_b + i * D_MODEL);
        }
    }

    k_pool_part<<<BSZ * 16, 256, 0, stream>>>(h, lengths, poolp);
    k_head<<<BSZ, 256, 0, stream>>>(poolp, lengths, head_w, head_b, out);
}

// Round 7
// 2817.461 us; speedup vs baseline: 2.4773x; 1.0686x over previous
//
#include <hip/hip_runtime.h>
#include <math.h>

#define D_IN 63
#define D_MODEL 256
#define N_CLS 14
#define NL 4
#define D_INNER 512
#define D_STATE 128
#define NH 8
#define HP 64
#define DCONV 4
#define CONV_CH 768
#define PROJ 1288
#define XBCDT 776
#define EPS 1e-5f
#define BSZ 32
#define LSEQ 1024
#define NTOK (BSZ*LSEQ)

#define SSEG 4
#define TSEG (LSEQ/SSEG)
#define CT 16
#define RS 8

// weight-pack region (ushort offsets)
#define S_IN   16384
#define S_IP   1318912
#define S_OP   524288
#define IN_HI  0
#define IN_LO  16384
#define IP_HI  32768
#define IP_LO  (32768 + S_IP)
#define OP_HI  (32768 + 2*S_IP)
#define OP_LO  (OP_HI + S_OP)
#define TOTPK  (S_IN + S_IP + S_OP)
#define WS_BASE ((size_t)NTOK * 1816)
#define WS_NEED ((WS_BASE + (size_t)TOTPK) * 4)

typedef __attribute__((ext_vector_type(8))) short bf16x8;
typedef __attribute__((ext_vector_type(4))) float f32x4;

__device__ __forceinline__ float silu_f(float x) { return x / (1.f + expf(-x)); }

__device__ __forceinline__ unsigned short f2bf(float x) {
    union { float f; unsigned u; } v; v.f = x;
    unsigned r = v.u + 0x7FFFu + ((v.u >> 16) & 1u);
    return (unsigned short)(r >> 16);
}
__device__ __forceinline__ float bf2f(unsigned short h) {
    union { float f; unsigned u; } v; v.u = ((unsigned)h) << 16; return v.f;
}

// conflict-free swizzle (4 q-groups of 32): proven 0-conflict in rounds 3-5
__device__ __forceinline__ int swz128(int n) {
    int q = n >> 5, i = (n >> 2) & 7, j = n & 3;
    return (q << 5) + (((i + 2 * q) & 7) << 2) + j;
}

__device__ __forceinline__ float2 block_reduce2(float a, float b, float* sred) {
    #pragma unroll
    for (int off = 32; off >= 1; off >>= 1) {
        a += __shfl_xor(a, off);
        b += __shfl_xor(b, off);
    }
    int wid = threadIdx.x >> 6, lane = threadIdx.x & 63;
    if (lane == 0) { sred[wid * 2] = a; sred[wid * 2 + 1] = b; }
    __syncthreads();
    a = sred[0] + sred[2] + sred[4] + sred[6];
    b = sred[1] + sred[3] + sred[5] + sred[7];
    __syncthreads();
    return make_float2(a, b);
}

// ---------------- pack all weights to bf16 hi/lo planes ----------------
__global__ __launch_bounds__(256)
void k_pack_weights(const float* __restrict__ in_w, const float* __restrict__ inproj,
                    const float* __restrict__ outp, unsigned short* __restrict__ WP) {
    int idx = blockIdx.x * 256 + threadIdx.x;
    float v; int hi_off, lo_off;
    if (idx < S_IN) {
        int n = idx >> 6, k = idx & 63;
        v = (k < D_IN) ? in_w[n * D_IN + k] : 0.f;
        hi_off = IN_HI + idx; lo_off = IN_LO + idx;
    } else if (idx < S_IN + S_IP) {
        int j = idx - S_IN;
        v = inproj[j];
        hi_off = IP_HI + j; lo_off = IP_LO + j;
    } else {
        int j = idx - S_IN - S_IP;
        v = outp[j];
        hi_off = OP_HI + j; lo_off = OP_LO + j;
    }
    unsigned short h = f2bf(v);
    unsigned short l = f2bf(v - bf2f(h));
    WP[hi_off] = h; WP[lo_off] = l;
}

// ---------------- MFMA GEMM, A fp32 (in-kernel trunc split), B pre-packed ----------
#define LDKP 40
__global__ __launch_bounds__(256, 2)
void k_gemm_as(const float* __restrict__ A, const unsigned short* __restrict__ Bhg,
               const unsigned short* __restrict__ Blg, float* __restrict__ C,
               int M, int N, int K) {
    __shared__ unsigned short Ah[128][LDKP], Al[128][LDKP];
    __shared__ unsigned short Bh[128][LDKP], Bl[128][LDKP];
    int n0 = blockIdx.x * 128, m0 = blockIdx.y * 128;
    int tid = threadIdx.x;
    int srow = tid >> 1, sk = (tid & 1) * 16;
    int lane = tid & 63, wave = tid >> 6;
    int wm = (wave >> 1) * 64, wn = (wave & 1) * 64;
    int ln = lane & 15, quad = lane >> 4;
    f32x4 acc[4][4];
    #pragma unroll
    for (int i = 0; i < 4; i++)
        #pragma unroll
        for (int j = 0; j < 4; j++) acc[i][j] = (f32x4){0.f, 0.f, 0.f, 0.f};
    const float* Ap = A + (size_t)(m0 + srow) * K + sk;
    const unsigned short* Bhp = Bhg + (size_t)(n0 + srow) * K + sk;
    const unsigned short* Blp = Blg + (size_t)(n0 + srow) * K + sk;
    bool bval = (n0 + srow) < N;
    uint4 z4 = make_uint4(0u, 0u, 0u, 0u);
    for (int k0 = 0; k0 < K; k0 += 32) {
        float av[16];
        #pragma unroll
        for (int i = 0; i < 4; i++)
            *(float4*)&av[4 * i] = *(const float4*)(Ap + k0 + 4 * i);
        uint4 bh0 = bval ? *(const uint4*)(Bhp + k0) : z4;
        uint4 bh1 = bval ? *(const uint4*)(Bhp + k0 + 8) : z4;
        uint4 bl0 = bval ? *(const uint4*)(Blp + k0) : z4;
        uint4 bl1 = bval ? *(const uint4*)(Blp + k0 + 8) : z4;
        unsigned hp[8], lp[8];
        #pragma unroll
        for (int j = 0; j < 8; j++) {
            float a0 = av[2 * j], a1 = av[2 * j + 1];
            unsigned u0 = __float_as_uint(a0), u1 = __float_as_uint(a1);
            unsigned h0 = u0 & 0xFFFF0000u, h1 = u1 & 0xFFFF0000u;
            float r0 = a0 - __uint_as_float(h0);
            float r1 = a1 - __uint_as_float(h1);
            hp[j] = (u0 >> 16) | h1;
            lp[j] = (__float_as_uint(r0) >> 16) | (__float_as_uint(r1) & 0xFFFF0000u);
        }
        __syncthreads();
        *(uint4*)&Ah[srow][sk]     = *(uint4*)&hp[0];
        *(uint4*)&Ah[srow][sk + 8] = *(uint4*)&hp[4];
        *(uint4*)&Al[srow][sk]     = *(uint4*)&lp[0];
        *(uint4*)&Al[srow][sk + 8] = *(uint4*)&lp[4];
        *(uint4*)&Bh[srow][sk]     = bh0;
        *(uint4*)&Bh[srow][sk + 8] = bh1;
        *(uint4*)&Bl[srow][sk]     = bl0;
        *(uint4*)&Bl[srow][sk + 8] = bl1;
        __syncthreads();
        bf16x8 fah[4], fal[4], fbh[4], fbl[4];
        #pragma unroll
        for (int t = 0; t < 4; t++) {
            fah[t] = *(const bf16x8*)&Ah[wm + t * 16 + ln][quad * 8];
            fal[t] = *(const bf16x8*)&Al[wm + t * 16 + ln][quad * 8];
            fbh[t] = *(const bf16x8*)&Bh[wn + t * 16 + ln][quad * 8];
            fbl[t] = *(const bf16x8*)&Bl[wn + t * 16 + ln][quad * 8];
        }
        #pragma unroll
        for (int mt = 0; mt < 4; mt++)
            #pragma unroll
            for (int nt = 0; nt < 4; nt++) {
                acc[mt][nt] = __builtin_amdgcn_mfma_f32_16x16x32_bf16(fal[mt], fbh[nt], acc[mt][nt], 0, 0, 0);
                acc[mt][nt] = __builtin_amdgcn_mfma_f32_16x16x32_bf16(fah[mt], fbl[nt], acc[mt][nt], 0, 0, 0);
                acc[mt][nt] = __builtin_amdgcn_mfma_f32_16x16x32_bf16(fah[mt], fbh[nt], acc[mt][nt], 0, 0, 0);
            }
    }
    #pragma unroll
    for (int mt = 0; mt < 4; mt++)
        #pragma unroll
        for (int nt = 0; nt < 4; nt++) {
            int cn = n0 + wn + nt * 16 + ln;
            if (cn < N) {
                #pragma unroll
                for (int r = 0; r < 4; r++) {
                    int cm = m0 + wm + mt * 16 + quad * 4 + r;
                    C[(size_t)cm * N + cn] = acc[mt][nt][r];
                }
            }
        }
}

// ---------------- fallback GEMM: fp32 A and B, in-kernel split ----------------
__global__ __launch_bounds__(256, 2)
void k_gemm_mfma(const float* __restrict__ A, const float* __restrict__ B,
                 float* __restrict__ C, int M, int N, int K) {
    __shared__ unsigned short Ah[128][LDKP], Al[128][LDKP];
    __shared__ unsigned short Bh[128][LDKP], Bl[128][LDKP];
    int n0 = blockIdx.x * 128, m0 = blockIdx.y * 128;
    int tid = threadIdx.x;
    int srow = tid >> 1, sk = (tid & 1) * 16;
    int lane = tid & 63, wave = tid >> 6;
    int wm = (wave >> 1) * 64, wn = (wave & 1) * 64;
    int ln = lane & 15, quad = lane >> 4;
    f32x4 acc[4][4];
    #pragma unroll
    for (int i = 0; i < 4; i++)
        #pragma unroll
        for (int j = 0; j < 4; j++) acc[i][j] = (f32x4){0.f, 0.f, 0.f, 0.f};
    const float* Ap = A + (size_t)(m0 + srow) * K + sk;
    const float* Bp = B + (size_t)(n0 + srow) * K + sk;
    bool bval = (n0 + srow) < N;
    for (int k0 = 0; k0 < K; k0 += 32) {
        float av[16], bv[16];
        #pragma unroll
        for (int i = 0; i < 4; i++) {
            *(float4*)&av[4 * i] = *(const float4*)(Ap + k0 + 4 * i);
            *(float4*)&bv[4 * i] = bval ? *(const float4*)(Bp + k0 + 4 * i)
                                        : make_float4(0.f, 0.f, 0.f, 0.f);
        }
        __syncthreads();
        #pragma unroll
        for (int g = 0; g < 2; g++) {
            unsigned hiA[4], loA[4], hiB[4], loB[4];
            #pragma unroll
            for (int j = 0; j < 4; j++) {
                float a0 = av[8 * g + 2 * j], a1 = av[8 * g + 2 * j + 1];
                unsigned short h0 = f2bf(a0), h1 = f2bf(a1);
                unsigned short l0 = f2bf(a0 - bf2f(h0)), l1 = f2bf(a1 - bf2f(h1));
                hiA[j] = (unsigned)h0 | ((unsigned)h1 << 16);
                loA[j] = (unsigned)l0 | ((unsigned)l1 << 16);
                float b0 = bv[8 * g + 2 * j], b1 = bv[8 * g + 2 * j + 1];
                unsigned short g0 = f2bf(b0), g1 = f2bf(b1);
                unsigned short m0s = f2bf(b0 - bf2f(g0)), m1s = f2bf(b1 - bf2f(g1));
                hiB[j] = (unsigned)g0 | ((unsigned)g1 << 16);
                loB[j] = (unsigned)m0s | ((unsigned)m1s << 16);
            }
            *(uint4*)&Ah[srow][sk + 8 * g] = *(uint4*)hiA;
            *(uint4*)&Al[srow][sk + 8 * g] = *(uint4*)loA;
            *(uint4*)&Bh[srow][sk + 8 * g] = *(uint4*)hiB;
            *(uint4*)&Bl[srow][sk + 8 * g] = *(uint4*)loB;
        }
        __syncthreads();
        bf16x8 fah[4], fal[4], fbh[4], fbl[4];
        #pragma unroll
        for (int t = 0; t < 4; t++) {
            fah[t] = *(const bf16x8*)&Ah[wm + t * 16 + ln][quad * 8];
            fal[t] = *(const bf16x8*)&Al[wm + t * 16 + ln][quad * 8];
            fbh[t] = *(const bf16x8*)&Bh[wn + t * 16 + ln][quad * 8];
            fbl[t] = *(const bf16x8*)&Bl[wn + t * 16 + ln][quad * 8];
        }
        #pragma unroll
        for (int mt = 0; mt < 4; mt++)
            #pragma unroll
            for (int nt = 0; nt < 4; nt++) {
                acc[mt][nt] = __builtin_amdgcn_mfma_f32_16x16x32_bf16(fal[mt], fbh[nt], acc[mt][nt], 0, 0, 0);
                acc[mt][nt] = __builtin_amdgcn_mfma_f32_16x16x32_bf16(fah[mt], fbl[nt], acc[mt][nt], 0, 0, 0);
                acc[mt][nt] = __builtin_amdgcn_mfma_f32_16x16x32_bf16(fah[mt], fbh[nt], acc[mt][nt], 0, 0, 0);
            }
    }
    #pragma unroll
    for (int mt = 0; mt < 4; mt++)
        #pragma unroll
        for (int nt = 0; nt < 4; nt++) {
            int cn = n0 + wn + nt * 16 + ln;
            if (cn < N) {
                #pragma unroll
                for (int r = 0; r < 4; r++) {
                    int cm = m0 + wm + mt * 16 + quad * 4 + r;
                    C[(size_t)cm * N + cn] = acc[mt][nt][r];
                }
            }
        }
}

// ---------------- pack x / pack w ----------------
__global__ __launch_bounds__(256)
void k_pack_x(const float* __restrict__ x, float* __restrict__ xp) {
    size_t idx = (size_t)blockIdx.x * 256 + threadIdx.x;
    int k = (int)(idx & 63);
    size_t m = idx >> 6;
    xp[idx] = (k < D_IN) ? x[m * D_IN + k] : 0.f;
}
__global__ __launch_bounds__(256)
void k_pack_w(const float* __restrict__ w, float* __restrict__ wp) {
    int idx = blockIdx.x * 256 + threadIdx.x;
    int k = idx & 63, n = idx >> 6;
    wp[idx] = (k < D_IN) ? w[n * D_IN + k] : 0.f;
}

// ---------------- h = LN(pre + in_b) ----------------
__global__ __launch_bounds__(256)
void k_lnio(const float* __restrict__ pre, const float* __restrict__ bias,
            const float* __restrict__ gw, const float* __restrict__ gb,
            float* __restrict__ h) {
    int m = blockIdx.x, o = threadIdx.x;
    __shared__ float sred[8];
    float v = pre[(size_t)m * D_MODEL + o] + bias[o];
    float2 s = block_reduce2(v, v * v, sred);
    float mu = s.x * (1.f / D_MODEL);
    float var = s.y * (1.f / D_MODEL) - mu * mu;
    h[(size_t)m * D_MODEL + o] = (v - mu) * rsqrtf(var + EPS) * gw[o] + gb[o];
}

// ---------------- conv (causal depthwise k=4) + silu + dt ----------------
__global__ __launch_bounds__(256)
void k_conv(const float* __restrict__ xbc, const float* __restrict__ cw,
            const float* __restrict__ cb, const float* __restrict__ dtb,
            float* __restrict__ xs, float* __restrict__ Bm, float* __restrict__ Cm,
            float* __restrict__ dtv) {
    int m = blockIdx.x;
    int l = m & (LSEQ - 1);
    int tid = threadIdx.x;
    #pragma unroll
    for (int it = 0; it < 3; it++) {
        int c = tid + it * 256;
        float acc = cb[c];
        #pragma unroll
        for (int k = 0; k < DCONV; k++) {
            int lp = l - (DCONV - 1) + k;
            if (lp >= 0)
                acc = fmaf(cw[k * CONV_CH + c],
                           xbc[(size_t)(m - (DCONV - 1) + k) * XBCDT + c], acc);
        }
        float v = silu_f(acc);
        if (c < D_INNER) xs[(size_t)m * D_INNER + c] = v;
        else if (c < D_INNER + D_STATE) Bm[(size_t)m * D_STATE + (c - D_INNER)] = v;
        else Cm[(size_t)m * D_STATE + (c - D_INNER - D_STATE)] = v;
    }
    if (tid < NH) {
        float draw = xbc[(size_t)m * XBCDT + CONV_CH + tid] + dtb[tid];
        float dt = draw > 20.f ? draw : log1pf(expf(draw));
        dtv[m * NH + tid] = dt;
    }
}

// ---------------- Pass A: segment-local scan (round-4 structure, 4-way yp) ---------
__global__ __launch_bounds__(256, 4)
void k_scan_seg(const float* __restrict__ xs, const float* __restrict__ Bm,
                const float* __restrict__ Cm, const float* __restrict__ dtv,
                const float* __restrict__ Alog, const float* __restrict__ Dvec,
                float* __restrict__ y, float* __restrict__ F,
                float* __restrict__ cumdA) {
    int blk = blockIdx.x;
    int bh = blk >> 2;
    int seg = blk & (SSEG - 1);
    int b = bh >> 3, hh = bh & 7;
    int tid = threadIdx.x;
    int p = tid >> 2, q = tid & 3;
    int q2 = q << 1;
    __shared__ __align__(16) float sBC[2 * CT * 128];
    __shared__ __align__(16) float sX[CT][HP];
    __shared__ float sdt[CT], sdA[CT], srdA[CT];
    float hst[32];
    #pragma unroll
    for (int i = 0; i < 32; i++) hst[i] = 0.f;
    float Dh = Dvec[hh];
    float Ahv = -expf(Alog[hh]);
    float c_run = 1.f;
    const size_t base = (size_t)b * LSEQ + (size_t)seg * TSEG;
    int col = tid & 127, half = tid >> 7;
    int sw = swz128(col);
    int xc = tid & 63, xh = tid >> 6;

    for (int c0 = 0; c0 < TSEG; c0 += CT) {
        #pragma unroll
        for (int u = 0; u < 8; u++) {
            int s = 2 * u + half;
            size_t m = base + c0 + s;
            sBC[s * 128 + sw] = Bm[m * D_STATE + col];
            sBC[(CT + s) * 128 + sw] = Cm[m * D_STATE + col];
        }
        #pragma unroll
        for (int u = 0; u < 4; u++) {
            int s = 4 * u + xh;
            sX[s][xc] = xs[(base + c0 + s) * D_INNER + hh * HP + xc];
        }
        if (tid < CT) {
            float dtl = dtv[(base + c0 + tid) * NH + hh];
            float e = fmaxf(dtl * Ahv, -37.f);
            sdt[tid] = dtl;
            sdA[tid] = expf(e);
            srdA[tid] = expf(-e);
        }
        __syncthreads();
        if (tid == 0) {
            float cg = c_run;
            for (int s = 0; s < CT; s++) {
                cg *= sdA[s];
                cumdA[(base + c0 + s) * NH + hh] = cg;
            }
            c_run = cg;
        }
        float cc = 1.f, rc = 1.f;
        #pragma unroll
        for (int s = 0; s < CT; s++) {
            float dAl = sdA[s], dtl = sdt[s];
            float ccn = cc * dAl;
            if (ccn < 1e-18f) {          // rare, wave-uniform rebase
                #pragma unroll
                for (int i = 0; i < 32; i++) hst[i] *= cc;
                rc = srdA[s];
                ccn = dAl;
            } else {
                rc *= srdA[s];
            }
            cc = ccn;
            float xv = sX[s][p];
            float tmp = dtl * xv * rc;
            float yp0 = 0.f, yp1 = 0.f, yp2 = 0.f, yp3 = 0.f;
            #pragma unroll
            for (int i = 0; i < 8; i++) {
                int off = (q << 5) + (((i + q2) & 7) << 2);
                float4 bv = *(const float4*)&sBC[s * 128 + off];
                float4 cv = *(const float4*)&sBC[(CT + s) * 128 + off];
                hst[4*i+0] = fmaf(tmp, bv.x, hst[4*i+0]); yp0 = fmaf(hst[4*i+0], cv.x, yp0);
                hst[4*i+1] = fmaf(tmp, bv.y, hst[4*i+1]); yp1 = fmaf(hst[4*i+1], cv.y, yp1);
                hst[4*i+2] = fmaf(tmp, bv.z, hst[4*i+2]); yp2 = fmaf(hst[4*i+2], cv.z, yp2);
                hst[4*i+3] = fmaf(tmp, bv.w, hst[4*i+3]); yp3 = fmaf(hst[4*i+3], cv.w, yp3);
            }
            float yp = (yp0 + yp1) + (yp2 + yp3);
            yp += __shfl_xor(yp, 1);
            yp += __shfl_xor(yp, 2);
            if (q == 0) y[(base + c0 + s) * D_INNER + hh * HP + p] = fmaf(Dh, xv, cc * yp);
            if ((s & (RS - 1)) == RS - 1) {   // sub-chunk flush -> hst = true state
                #pragma unroll
                for (int i = 0; i < 32; i++) hst[i] *= cc;
                cc = 1.f; rc = 1.f;
            }
        }
        __syncthreads();
    }
    if (seg < SSEG - 1) {
        float* Fp = F + (((size_t)bh * (SSEG - 1) + seg) * HP + p) * D_STATE + (q << 5);
        #pragma unroll
        for (int i = 0; i < 8; i++)
            *(float4*)(Fp + 4 * i) = make_float4(hst[4*i], hst[4*i+1], hst[4*i+2], hst[4*i+3]);
    }
}

// ---------------- Pass C (fused combine): y_t += cumdA_t * (C_t . h_in[seg]) --------
__global__ __launch_bounds__(256, 4)
void k_seg_fix(const float* __restrict__ Cm, const float* __restrict__ cumdA,
               const float* __restrict__ F, float* __restrict__ y) {
    int blk = blockIdx.x;
    int bh = blk / (SSEG - 1);
    int seg = blk - bh * (SSEG - 1) + 1;
    int b = bh >> 3, hh = bh & 7;
    int tid = threadIdx.x, p = tid >> 2, q = tid & 3;
    int q2 = q << 1;
    float hin[32];
    #pragma unroll
    for (int i = 0; i < 32; i++) hin[i] = 0.f;
    for (int s = 0; s < seg; s++) {
        float P = cumdA[((size_t)b * LSEQ + (size_t)(s + 1) * TSEG - 1) * NH + hh];
        const float* Fp = F + (((size_t)bh * (SSEG - 1) + s) * HP + p) * D_STATE + (q << 5);
        #pragma unroll
        for (int i = 0; i < 8; i++) {
            float4 f = *(const float4*)(Fp + 4 * i);
            hin[4*i+0] = fmaf(hin[4*i+0], P, f.x);
            hin[4*i+1] = fmaf(hin[4*i+1], P, f.y);
            hin[4*i+2] = fmaf(hin[4*i+2], P, f.z);
            hin[4*i+3] = fmaf(hin[4*i+3], P, f.w);
        }
    }
    __shared__ __align__(16) float sC[CT][D_STATE];
    __shared__ float scd[CT];
    const size_t base = (size_t)b * LSEQ + (size_t)seg * TSEG;
    int col = tid & 127, half = tid >> 7;
    int sw = swz128(col);
    for (int c0 = 0; c0 < TSEG; c0 += CT) {
        #pragma unroll
        for (int u = 0; u < 8; u++) {
            int s = 2 * u + half;
            sC[s][sw] = Cm[(base + c0 + s) * D_STATE + col];
        }
        if (tid < CT) scd[tid] = cumdA[(base + c0 + tid) * NH + hh];
        __syncthreads();
        #pragma unroll 1
        for (int s = 0; s < CT; s++) {
            float yp0 = 0.f, yp1 = 0.f, yp2 = 0.f, yp3 = 0.f;
            #pragma unroll
            for (int i = 0; i < 8; i++) {
                int off = (q << 5) + (((i + q2) & 7) << 2);
                float4 cv = *(const float4*)&sC[s][off];
                yp0 = fmaf(hin[4*i+0], cv.x, yp0);
                yp1 = fmaf(hin[4*i+1], cv.y, yp1);
                yp2 = fmaf(hin[4*i+2], cv.z, yp2);
                yp3 = fmaf(hin[4*i+3], cv.w, yp3);
            }
            float yp = (yp0 + yp1) + (yp2 + yp3);
            yp += __shfl_xor(yp, 1);
            yp += __shfl_xor(yp, 2);
            if (q == 0) {
                size_t idx = (base + c0 + s) * D_INNER + hh * HP + p;
                y[idx] += scd[s] * yp;
            }
        }
        __syncthreads();
    }
}

// ---------------- gated RMSNorm (in-place on y) ----------------
__global__ __launch_bounds__(256)
void k_gate(float* __restrict__ y, const float* __restrict__ zbuf,
            const float* __restrict__ nw) {
    int m = blockIdx.x, tid = threadIdx.x;
    __shared__ float sred[8];
    float g[2];
    #pragma unroll
    for (int j = 0; j < 2; j++) {
        int d = tid + j * 256;
        float z = zbuf[(size_t)m * D_INNER + d];
        g[j] = y[(size_t)m * D_INNER + d] * silu_f(z);
    }
    float2 s = block_reduce2(g[0] * g[0] + g[1] * g[1], 0.f, sred);
    float r = rsqrtf(s.x * (1.f / D_INNER) + EPS);
    #pragma unroll
    for (int j = 0; j < 2; j++) {
        int d = tid + j * 256;
        y[(size_t)m * D_INNER + d] = g[j] * r * nw[d];
    }
}

// ---------------- h = LN(mo + h) ----------------
__global__ __launch_bounds__(256)
void k_addln(const float* __restrict__ mo, float* __restrict__ h,
             const float* __restrict__ w, const float* __restrict__ bias) {
    int m = blockIdx.x, o = threadIdx.x;
    __shared__ float sred[8];
    float v = mo[(size_t)m * D_MODEL + o] + h[(size_t)m * D_MODEL + o];
    float2 s = block_reduce2(v, v * v, sred);
    float mu = s.x * (1.f / D_MODEL);
    float var = s.y * (1.f / D_MODEL) - mu * mu;
    h[(size_t)m * D_MODEL + o] = (v - mu) * rsqrtf(var + EPS) * w[o] + bias[o];
}

// ---------------- pooled partial sums: 16 chunks of 64 tokens per batch ----------
__global__ __launch_bounds__(256)
void k_pool_part(const float* __restrict__ h, const int* __restrict__ len,
                 float* __restrict__ part) {
    int blk = blockIdx.x;
    int b = blk >> 4, ch = blk & 15;
    int d = threadIdx.x;
    int Lb = len[b];
    int l0 = ch * 64;
    int le = min(l0 + 64, Lb);
    float acc = 0.f;
    for (int l = l0; l < le; l++) acc += h[((size_t)b * LSEQ + l) * D_MODEL + d];
    part[(size_t)blk * D_MODEL + d] = acc;
}

// ---------------- final head: pooled mean + 14-way linear ----------------
__global__ __launch_bounds__(256)
void k_head(const float* __restrict__ part, const int* __restrict__ len,
            const float* __restrict__ hw, const float* __restrict__ hb,
            float* __restrict__ out) {
    int b = blockIdx.x, d = threadIdx.x;
    __shared__ float sp[D_MODEL];
    float a = 0.f;
    #pragma unroll
    for (int c = 0; c < 16; c++) a += part[(size_t)(b * 16 + c) * D_MODEL + d];
    sp[d] = a / (float)len[b];
    __syncthreads();
    if (d < N_CLS) {
        float o = hb[d];
        const float* wr = hw + (size_t)d * D_MODEL;
        #pragma unroll 8
        for (int k = 0; k < D_MODEL; k++) o = fmaf(sp[k], wr[k], o);
        out[b * N_CLS + d] = o;
    }
}

extern "C" void kernel_launch(void* const* d_in, const int* in_sizes, int n_in,
                              void* d_out, int out_size, void* d_ws, size_t ws_size,
                              hipStream_t stream) {
    const float* x      = (const float*)d_in[0];
    const float* in_w   = (const float*)d_in[1];
    const float* in_b   = (const float*)d_in[2];
    const float* lnin_w = (const float*)d_in[3];
    const float* lnin_b = (const float*)d_in[4];
    const float* inproj = (const float*)d_in[5];
    const float* conv_w = (const float*)d_in[6];
    const float* conv_b = (const float*)d_in[7];
    const float* dt_bias= (const float*)d_in[8];
    const float* A_log  = (const float*)d_in[9];
    const float* Dv     = (const float*)d_in[10];
    const float* norm_w = (const float*)d_in[11];
    const float* outp_w = (const float*)d_in[12];
    const float* ln_w   = (const float*)d_in[13];
    const float* ln_b   = (const float*)d_in[14];
    const float* head_w = (const float*)d_in[15];
    const float* head_b = (const float*)d_in[16];
    const int*   lengths= (const int*)d_in[17];
    float* out = (float*)d_out;

    float* ws    = (float*)d_ws;
    float* h     = ws;
    float* buf1  = h    + (size_t)NTOK * D_MODEL;
    float* xs    = buf1 + (size_t)NTOK * XBCDT;
    float* Bm    = xs   + (size_t)NTOK * D_INNER;
    float* Cm    = Bm   + (size_t)NTOK * D_STATE;
    float* dtv   = Cm   + (size_t)NTOK * D_STATE;
    float* cumdA = dtv  + (size_t)NTOK * NH;
    float* zbuf  = buf1;
    float* F     = buf1 + (size_t)NTOK * D_INNER;   // 3 segs * 256 bh * 8192 floats
    float* mo    = Bm;
    float* xp    = buf1;
    float* pre   = buf1 + (size_t)NTOK * 64;
    float* poolp = buf1;                            // 32*16*256 floats (dead region)
    unsigned short* WP = (unsigned short*)(ws + WS_BASE);
    bool use_pk = (ws_size >= WS_NEED);

    dim3 gIO(D_MODEL / 128, NTOK / 128);
    dim3 g1a((XBCDT + 127) / 128, NTOK / 128);
    dim3 g1b(D_INNER / 128, NTOK / 128);
    int gScan = BSZ * NH * SSEG;
    int gFix  = BSZ * NH * (SSEG - 1);

    if (use_pk) {
        k_pack_weights<<<TOTPK / 256, 256, 0, stream>>>(in_w, inproj, outp_w, WP);
        k_pack_x<<<NTOK * 64 / 256, 256, 0, stream>>>(x, xp);
        k_gemm_as<<<gIO, 256, 0, stream>>>(xp, WP + IN_HI, WP + IN_LO, pre,
                                           NTOK, D_MODEL, 64);
        k_lnio<<<NTOK, 256, 0, stream>>>(pre, in_b, lnin_w, lnin_b, h);
        for (int i = 0; i < NL; i++) {
            const unsigned short* iph = WP + IP_HI + (size_t)i * PROJ * D_MODEL;
            const unsigned short* ipl = WP + IP_LO + (size_t)i * PROJ * D_MODEL;
            k_gemm_as<<<g1a, 256, 0, stream>>>(h, iph + (size_t)D_INNER * D_MODEL,
                                               ipl + (size_t)D_INNER * D_MODEL,
                                               buf1, NTOK, XBCDT, D_MODEL);
            k_conv<<<NTOK, 256, 0, stream>>>(buf1, conv_w + i * DCONV * CONV_CH,
                                             conv_b + i * CONV_CH, dt_bias + i * NH,
                                             xs, Bm, Cm, dtv);
            k_gemm_as<<<g1b, 256, 0, stream>>>(h, iph, ipl, zbuf, NTOK, D_INNER, D_MODEL);
            k_scan_seg<<<gScan, 256, 0, stream>>>(xs, Bm, Cm, dtv,
                                                  A_log + i * NH, Dv + i * NH,
                                                  xs, F, cumdA);
            k_seg_fix<<<gFix, 256, 0, stream>>>(Cm, cumdA, F, xs);
            k_gate<<<NTOK, 256, 0, stream>>>(xs, zbuf, norm_w + i * D_INNER);
            k_gemm_as<<<gIO, 256, 0, stream>>>(xs, WP + OP_HI + (size_t)i * D_MODEL * D_INNER,
                                               WP + OP_LO + (size_t)i * D_MODEL * D_INNER,
                                               mo, NTOK, D_MODEL, D_INNER);
            k_addln<<<NTOK, 256, 0, stream>>>(mo, h, ln_w + i * D_MODEL, ln_b + i * D_MODEL);
        }
    } else {
        float* wp = Bm;
        k_pack_x<<<NTOK * 64 / 256, 256, 0, stream>>>(x, xp);
        k_pack_w<<<64, 256, 0, stream>>>(in_w, wp);
        k_gemm_mfma<<<gIO, 256, 0, stream>>>(xp, wp, pre, NTOK, D_MODEL, 64);
        k_lnio<<<NTOK, 256, 0, stream>>>(pre, in_b, lnin_w, lnin_b, h);
        for (int i = 0; i < NL; i++) {
            const float* W = inproj + (size_t)i * PROJ * D_MODEL;
            k_gemm_mfma<<<g1a, 256, 0, stream>>>(h, W + (size_t)D_INNER * D_MODEL,
                                                 buf1, NTOK, XBCDT, D_MODEL);
            k_conv<<<NTOK, 256, 0, stream>>>(buf1, conv_w + i * DCONV * CONV_CH,
                                             conv_b + i * CONV_CH, dt_bias + i * NH,
                                             xs, Bm, Cm, dtv);
            k_gemm_mfma<<<g1b, 256, 0, stream>>>(h, W, zbuf, NTOK, D_INNER, D_MODEL);
            k_scan_seg<<<gScan, 256, 0, stream>>>(xs, Bm, Cm, dtv,
                                                  A_log + i * NH, Dv + i * NH,
                                                  xs, F, cumdA);
            k_seg_fix<<<gFix, 256, 0, stream>>>(Cm, cumdA, F, xs);
            k_gate<<<NTOK, 256, 0, stream>>>(xs, zbuf, norm_w + i * D_INNER);
            k_gemm_mfma<<<gIO, 256, 0, stream>>>(xs, outp_w + (size_t)i * D_MODEL * D_INNER,
                                                 mo, NTOK, D_MODEL, D_INNER);
            k_addln<<<NTOK, 256, 0, stream>>>(mo, h, ln_w + i * D_MODEL, ln_b + i * D_MODEL);
        }
    }

    k_pool_part<<<BSZ * 16, 256, 0, stream>>>(h, lengths, poolp);
    k_head<<<BSZ, 256, 0, stream>>>(poolp, lengths, head_w, head_b, out);
}

// Round 8
// 2670.484 us; speedup vs baseline: 2.6136x; 1.0550x over previous
//
#include <hip/hip_runtime.h>
#include <math.h>

#define D_IN 63
#define D_MODEL 256
#define N_CLS 14
#define NL 4
#define D_INNER 512
#define D_STATE 128
#define NH 8
#define HP 64
#define DCONV 4
#define CONV_CH 768
#define PROJ 1288
#define XBCDT 776
#define EPS 1e-5f
#define BSZ 32
#define LSEQ 1024
#define NTOK (BSZ*LSEQ)

#define SSEG 4
#define TSEG (LSEQ/SSEG)
#define CT 16
#define RS 8

// weight-pack region (ushort offsets)
#define S_IN   16384
#define S_IP   1318912
#define S_OP   524288
#define IN_HI  0
#define IN_LO  16384
#define IP_HI  32768
#define IP_LO  (32768 + S_IP)
#define OP_HI  (32768 + 2*S_IP)
#define OP_LO  (OP_HI + S_OP)
#define TOTPK  (S_IN + S_IP + S_OP)
#define WS_BASE ((size_t)NTOK * 1816)
#define WS_NEED ((WS_BASE + (size_t)TOTPK) * 4)

typedef __attribute__((ext_vector_type(8))) short bf16x8;
typedef __attribute__((ext_vector_type(4))) float f32x4;

__device__ __forceinline__ float silu_f(float x) { return x / (1.f + expf(-x)); }

__device__ __forceinline__ unsigned short f2bf(float x) {
    union { float f; unsigned u; } v; v.f = x;
    unsigned r = v.u + 0x7FFFu + ((v.u >> 16) & 1u);
    return (unsigned short)(r >> 16);
}
__device__ __forceinline__ float bf2f(unsigned short h) {
    union { float f; unsigned u; } v; v.u = ((unsigned)h) << 16; return v.f;
}

// swizzle for 8 groups of 16 values (proven 0-conflict, round 6): at inner
// iter i the 8 q-groups' float4 reads land on 8 disjoint bank quads.
__device__ __forceinline__ int swz8(int n) {
    int g = n >> 4, j = (n >> 2) & 3, e = n & 3;
    return (g << 4) + (((j + (g >> 1)) & 3) << 2) + e;
}

__device__ __forceinline__ float2 block_reduce2(float a, float b, float* sred) {
    #pragma unroll
    for (int off = 32; off >= 1; off >>= 1) {
        a += __shfl_xor(a, off);
        b += __shfl_xor(b, off);
    }
    int wid = threadIdx.x >> 6, lane = threadIdx.x & 63;
    if (lane == 0) { sred[wid * 2] = a; sred[wid * 2 + 1] = b; }
    __syncthreads();
    a = sred[0] + sred[2] + sred[4] + sred[6];
    b = sred[1] + sred[3] + sred[5] + sred[7];
    __syncthreads();
    return make_float2(a, b);
}

// ---------------- pack all weights to bf16 hi/lo planes ----------------
__global__ __launch_bounds__(256)
void k_pack_weights(const float* __restrict__ in_w, const float* __restrict__ inproj,
                    const float* __restrict__ outp, unsigned short* __restrict__ WP) {
    int idx = blockIdx.x * 256 + threadIdx.x;
    float v; int hi_off, lo_off;
    if (idx < S_IN) {
        int n = idx >> 6, k = idx & 63;
        v = (k < D_IN) ? in_w[n * D_IN + k] : 0.f;
        hi_off = IN_HI + idx; lo_off = IN_LO + idx;
    } else if (idx < S_IN + S_IP) {
        int j = idx - S_IN;
        v = inproj[j];
        hi_off = IP_HI + j; lo_off = IP_LO + j;
    } else {
        int j = idx - S_IN - S_IP;
        v = outp[j];
        hi_off = OP_HI + j; lo_off = OP_LO + j;
    }
    unsigned short h = f2bf(v);
    unsigned short l = f2bf(v - bf2f(h));
    WP[hi_off] = h; WP[lo_off] = l;
}

// ---------------- MFMA GEMM, A fp32 (in-kernel trunc split), B pre-packed ----------
#define LDKP 40
__global__ __launch_bounds__(256, 2)
void k_gemm_as(const float* __restrict__ A, const unsigned short* __restrict__ Bhg,
               const unsigned short* __restrict__ Blg, float* __restrict__ C,
               int M, int N, int K) {
    __shared__ unsigned short Ah[128][LDKP], Al[128][LDKP];
    __shared__ unsigned short Bh[128][LDKP], Bl[128][LDKP];
    int n0 = blockIdx.x * 128, m0 = blockIdx.y * 128;
    int tid = threadIdx.x;
    int srow = tid >> 1, sk = (tid & 1) * 16;
    int lane = tid & 63, wave = tid >> 6;
    int wm = (wave >> 1) * 64, wn = (wave & 1) * 64;
    int ln = lane & 15, quad = lane >> 4;
    f32x4 acc[4][4];
    #pragma unroll
    for (int i = 0; i < 4; i++)
        #pragma unroll
        for (int j = 0; j < 4; j++) acc[i][j] = (f32x4){0.f, 0.f, 0.f, 0.f};
    const float* Ap = A + (size_t)(m0 + srow) * K + sk;
    const unsigned short* Bhp = Bhg + (size_t)(n0 + srow) * K + sk;
    const unsigned short* Blp = Blg + (size_t)(n0 + srow) * K + sk;
    bool bval = (n0 + srow) < N;
    uint4 z4 = make_uint4(0u, 0u, 0u, 0u);
    for (int k0 = 0; k0 < K; k0 += 32) {
        float av[16];
        #pragma unroll
        for (int i = 0; i < 4; i++)
            *(float4*)&av[4 * i] = *(const float4*)(Ap + k0 + 4 * i);
        uint4 bh0 = bval ? *(const uint4*)(Bhp + k0) : z4;
        uint4 bh1 = bval ? *(const uint4*)(Bhp + k0 + 8) : z4;
        uint4 bl0 = bval ? *(const uint4*)(Blp + k0) : z4;
        uint4 bl1 = bval ? *(const uint4*)(Blp + k0 + 8) : z4;
        unsigned hp[8], lp[8];
        #pragma unroll
        for (int j = 0; j < 8; j++) {
            float a0 = av[2 * j], a1 = av[2 * j + 1];
            unsigned u0 = __float_as_uint(a0), u1 = __float_as_uint(a1);
            unsigned h0 = u0 & 0xFFFF0000u, h1 = u1 & 0xFFFF0000u;
            float r0 = a0 - __uint_as_float(h0);
            float r1 = a1 - __uint_as_float(h1);
            hp[j] = (u0 >> 16) | h1;
            lp[j] = (__float_as_uint(r0) >> 16) | (__float_as_uint(r1) & 0xFFFF0000u);
        }
        __syncthreads();
        *(uint4*)&Ah[srow][sk]     = *(uint4*)&hp[0];
        *(uint4*)&Ah[srow][sk + 8] = *(uint4*)&hp[4];
        *(uint4*)&Al[srow][sk]     = *(uint4*)&lp[0];
        *(uint4*)&Al[srow][sk + 8] = *(uint4*)&lp[4];
        *(uint4*)&Bh[srow][sk]     = bh0;
        *(uint4*)&Bh[srow][sk + 8] = bh1;
        *(uint4*)&Bl[srow][sk]     = bl0;
        *(uint4*)&Bl[srow][sk + 8] = bl1;
        __syncthreads();
        bf16x8 fah[4], fal[4], fbh[4], fbl[4];
        #pragma unroll
        for (int t = 0; t < 4; t++) {
            fah[t] = *(const bf16x8*)&Ah[wm + t * 16 + ln][quad * 8];
            fal[t] = *(const bf16x8*)&Al[wm + t * 16 + ln][quad * 8];
            fbh[t] = *(const bf16x8*)&Bh[wn + t * 16 + ln][quad * 8];
            fbl[t] = *(const bf16x8*)&Bl[wn + t * 16 + ln][quad * 8];
        }
        #pragma unroll
        for (int mt = 0; mt < 4; mt++)
            #pragma unroll
            for (int nt = 0; nt < 4; nt++) {
                acc[mt][nt] = __builtin_amdgcn_mfma_f32_16x16x32_bf16(fal[mt], fbh[nt], acc[mt][nt], 0, 0, 0);
                acc[mt][nt] = __builtin_amdgcn_mfma_f32_16x16x32_bf16(fah[mt], fbl[nt], acc[mt][nt], 0, 0, 0);
                acc[mt][nt] = __builtin_amdgcn_mfma_f32_16x16x32_bf16(fah[mt], fbh[nt], acc[mt][nt], 0, 0, 0);
            }
    }
    #pragma unroll
    for (int mt = 0; mt < 4; mt++)
        #pragma unroll
        for (int nt = 0; nt < 4; nt++) {
            int cn = n0 + wn + nt * 16 + ln;
            if (cn < N) {
                #pragma unroll
                for (int r = 0; r < 4; r++) {
                    int cm = m0 + wm + mt * 16 + quad * 4 + r;
                    C[(size_t)cm * N + cn] = acc[mt][nt][r];
                }
            }
        }
}

// ---------------- fallback GEMM: fp32 A and B, in-kernel split ----------------
__global__ __launch_bounds__(256, 2)
void k_gemm_mfma(const float* __restrict__ A, const float* __restrict__ B,
                 float* __restrict__ C, int M, int N, int K) {
    __shared__ unsigned short Ah[128][LDKP], Al[128][LDKP];
    __shared__ unsigned short Bh[128][LDKP], Bl[128][LDKP];
    int n0 = blockIdx.x * 128, m0 = blockIdx.y * 128;
    int tid = threadIdx.x;
    int srow = tid >> 1, sk = (tid & 1) * 16;
    int lane = tid & 63, wave = tid >> 6;
    int wm = (wave >> 1) * 64, wn = (wave & 1) * 64;
    int ln = lane & 15, quad = lane >> 4;
    f32x4 acc[4][4];
    #pragma unroll
    for (int i = 0; i < 4; i++)
        #pragma unroll
        for (int j = 0; j < 4; j++) acc[i][j] = (f32x4){0.f, 0.f, 0.f, 0.f};
    const float* Ap = A + (size_t)(m0 + srow) * K + sk;
    const float* Bp = B + (size_t)(n0 + srow) * K + sk;
    bool bval = (n0 + srow) < N;
    for (int k0 = 0; k0 < K; k0 += 32) {
        float av[16], bv[16];
        #pragma unroll
        for (int i = 0; i < 4; i++) {
            *(float4*)&av[4 * i] = *(const float4*)(Ap + k0 + 4 * i);
            *(float4*)&bv[4 * i] = bval ? *(const float4*)(Bp + k0 + 4 * i)
                                        : make_float4(0.f, 0.f, 0.f, 0.f);
        }
        __syncthreads();
        #pragma unroll
        for (int g = 0; g < 2; g++) {
            unsigned hiA[4], loA[4], hiB[4], loB[4];
            #pragma unroll
            for (int j = 0; j < 4; j++) {
                float a0 = av[8 * g + 2 * j], a1 = av[8 * g + 2 * j + 1];
                unsigned short h0 = f2bf(a0), h1 = f2bf(a1);
                unsigned short l0 = f2bf(a0 - bf2f(h0)), l1 = f2bf(a1 - bf2f(h1));
                hiA[j] = (unsigned)h0 | ((unsigned)h1 << 16);
                loA[j] = (unsigned)l0 | ((unsigned)l1 << 16);
                float b0 = bv[8 * g + 2 * j], b1 = bv[8 * g + 2 * j + 1];
                unsigned short g0 = f2bf(b0), g1 = f2bf(b1);
                unsigned short m0s = f2bf(b0 - bf2f(g0)), m1s = f2bf(b1 - bf2f(g1));
                hiB[j] = (unsigned)g0 | ((unsigned)g1 << 16);
                loB[j] = (unsigned)m0s | ((unsigned)m1s << 16);
            }
            *(uint4*)&Ah[srow][sk + 8 * g] = *(uint4*)hiA;
            *(uint4*)&Al[srow][sk + 8 * g] = *(uint4*)loA;
            *(uint4*)&Bh[srow][sk + 8 * g] = *(uint4*)hiB;
            *(uint4*)&Bl[srow][sk + 8 * g] = *(uint4*)loB;
        }
        __syncthreads();
        bf16x8 fah[4], fal[4], fbh[4], fbl[4];
        #pragma unroll
        for (int t = 0; t < 4; t++) {
            fah[t] = *(const bf16x8*)&Ah[wm + t * 16 + ln][quad * 8];
            fal[t] = *(const bf16x8*)&Al[wm + t * 16 + ln][quad * 8];
            fbh[t] = *(const bf16x8*)&Bh[wn + t * 16 + ln][quad * 8];
            fbl[t] = *(const bf16x8*)&Bl[wn + t * 16 + ln][quad * 8];
        }
        #pragma unroll
        for (int mt = 0; mt < 4; mt++)
            #pragma unroll
            for (int nt = 0; nt < 4; nt++) {
                acc[mt][nt] = __builtin_amdgcn_mfma_f32_16x16x32_bf16(fal[mt], fbh[nt], acc[mt][nt], 0, 0, 0);
                acc[mt][nt] = __builtin_amdgcn_mfma_f32_16x16x32_bf16(fah[mt], fbl[nt], acc[mt][nt], 0, 0, 0);
                acc[mt][nt] = __builtin_amdgcn_mfma_f32_16x16x32_bf16(fah[mt], fbh[nt], acc[mt][nt], 0, 0, 0);
            }
    }
    #pragma unroll
    for (int mt = 0; mt < 4; mt++)
        #pragma unroll
        for (int nt = 0; nt < 4; nt++) {
            int cn = n0 + wn + nt * 16 + ln;
            if (cn < N) {
                #pragma unroll
                for (int r = 0; r < 4; r++) {
                    int cm = m0 + wm + mt * 16 + quad * 4 + r;
                    C[(size_t)cm * N + cn] = acc[mt][nt][r];
                }
            }
        }
}

// ---------------- pack x / pack w ----------------
__global__ __launch_bounds__(256)
void k_pack_x(const float* __restrict__ x, float* __restrict__ xp) {
    size_t idx = (size_t)blockIdx.x * 256 + threadIdx.x;
    int k = (int)(idx & 63);
    size_t m = idx >> 6;
    xp[idx] = (k < D_IN) ? x[m * D_IN + k] : 0.f;
}
__global__ __launch_bounds__(256)
void k_pack_w(const float* __restrict__ w, float* __restrict__ wp) {
    int idx = blockIdx.x * 256 + threadIdx.x;
    int k = idx & 63, n = idx >> 6;
    wp[idx] = (k < D_IN) ? w[n * D_IN + k] : 0.f;
}

// ---------------- h = LN(pre + in_b) ----------------
__global__ __launch_bounds__(256)
void k_lnio(const float* __restrict__ pre, const float* __restrict__ bias,
            const float* __restrict__ gw, const float* __restrict__ gb,
            float* __restrict__ h) {
    int m = blockIdx.x, o = threadIdx.x;
    __shared__ float sred[8];
    float v = pre[(size_t)m * D_MODEL + o] + bias[o];
    float2 s = block_reduce2(v, v * v, sred);
    float mu = s.x * (1.f / D_MODEL);
    float var = s.y * (1.f / D_MODEL) - mu * mu;
    h[(size_t)m * D_MODEL + o] = (v - mu) * rsqrtf(var + EPS) * gw[o] + gb[o];
}

// ---------------- conv (causal depthwise k=4) + silu + dt ----------------
__global__ __launch_bounds__(256)
void k_conv(const float* __restrict__ xbc, const float* __restrict__ cw,
            const float* __restrict__ cb, const float* __restrict__ dtb,
            float* __restrict__ xs, float* __restrict__ Bm, float* __restrict__ Cm,
            float* __restrict__ dtv) {
    int m = blockIdx.x;
    int l = m & (LSEQ - 1);
    int tid = threadIdx.x;
    #pragma unroll
    for (int it = 0; it < 3; it++) {
        int c = tid + it * 256;
        float acc = cb[c];
        #pragma unroll
        for (int k = 0; k < DCONV; k++) {
            int lp = l - (DCONV - 1) + k;
            if (lp >= 0)
                acc = fmaf(cw[k * CONV_CH + c],
                           xbc[(size_t)(m - (DCONV - 1) + k) * XBCDT + c], acc);
        }
        float v = silu_f(acc);
        if (c < D_INNER) xs[(size_t)m * D_INNER + c] = v;
        else if (c < D_INNER + D_STATE) Bm[(size_t)m * D_STATE + (c - D_INNER)] = v;
        else Cm[(size_t)m * D_STATE + (c - D_INNER - D_STATE)] = v;
    }
    if (tid < NH) {
        float draw = xbc[(size_t)m * XBCDT + CONV_CH + tid] + dtb[tid];
        float dt = draw > 20.f ? draw : log1pf(expf(draw));
        dtv[m * NH + tid] = dt;
    }
}

// ---------------- Pass A: segment-local scan, 2p x 16n per thread ----------------
// q = tid&7 owns 16 n-values; pl = tid>>3 owns p = pl and p+32.
// Halves LDS read bytes vs 1p x 32n (the measured LDS-BW roofline).
__global__ __launch_bounds__(256, 4)
void k_scan_seg(const float* __restrict__ xs, const float* __restrict__ Bm,
                const float* __restrict__ Cm, const float* __restrict__ dtv,
                const float* __restrict__ Alog, const float* __restrict__ Dvec,
                float* __restrict__ y, float* __restrict__ F,
                float* __restrict__ cumdA) {
    int blk = blockIdx.x;
    int bh = blk >> 2;
    int seg = blk & (SSEG - 1);
    int b = bh >> 3, hh = bh & 7;
    int tid = threadIdx.x;
    int q = tid & 7;
    int pl = tid >> 3;              // 0..31
    int q2 = q >> 1;
    __shared__ __align__(16) float sBC[2 * CT * 128];
    __shared__ __align__(16) float sX[CT][HP];
    __shared__ float sdt[CT], sdA[CT], srdA[CT];
    float h0[16], h1[16];
    #pragma unroll
    for (int i = 0; i < 16; i++) { h0[i] = 0.f; h1[i] = 0.f; }
    float Dh = Dvec[hh];
    float Ahv = -expf(Alog[hh]);
    float c_run = 1.f;
    const size_t base = (size_t)b * LSEQ + (size_t)seg * TSEG;
    int col = tid & 127, half = tid >> 7;
    int sw = swz8(col);
    int xc = tid & 63, xh = tid >> 6;

    for (int c0 = 0; c0 < TSEG; c0 += CT) {
        #pragma unroll
        for (int u = 0; u < 8; u++) {
            int s = 2 * u + half;
            size_t m = base + c0 + s;
            sBC[s * 128 + sw] = Bm[m * D_STATE + col];
            sBC[(CT + s) * 128 + sw] = Cm[m * D_STATE + col];
        }
        #pragma unroll
        for (int u = 0; u < 4; u++) {
            int s = 4 * u + xh;
            sX[s][xc] = xs[(base + c0 + s) * D_INNER + hh * HP + xc];
        }
        if (tid < CT) {
            float dtl = dtv[(base + c0 + tid) * NH + hh];
            float e = fmaxf(dtl * Ahv, -37.f);
            sdt[tid] = dtl;
            sdA[tid] = expf(e);
            srdA[tid] = expf(-e);
        }
        __syncthreads();
        if (tid == 0) {
            float cg = c_run;
            for (int s = 0; s < CT; s++) {
                cg *= sdA[s];
                cumdA[(base + c0 + s) * NH + hh] = cg;
            }
            c_run = cg;
        }
        float cc = 1.f, rc = 1.f;
        #pragma unroll
        for (int s = 0; s < CT; s++) {
            float dAl = sdA[s], dtl = sdt[s];
            float ccn = cc * dAl;
            if (ccn < 1e-18f) {          // rare, wave-uniform rebase
                #pragma unroll
                for (int i = 0; i < 16; i++) { h0[i] *= cc; h1[i] *= cc; }
                rc = srdA[s];
                ccn = dAl;
            } else {
                rc *= srdA[s];
            }
            cc = ccn;
            float xv0 = sX[s][pl];
            float xv1 = sX[s][pl + 32];
            float dr = dtl * rc;
            float t0 = dr * xv0, t1 = dr * xv1;
            float ya0 = 0.f, yb0 = 0.f, ya1 = 0.f, yb1 = 0.f;
            #pragma unroll
            for (int i = 0; i < 4; i++) {
                int off = (q << 4) + (((i + q2) & 3) << 2);
                float4 bv = *(const float4*)&sBC[s * 128 + off];
                float4 cv = *(const float4*)&sBC[(CT + s) * 128 + off];
                h0[4*i+0] = fmaf(t0, bv.x, h0[4*i+0]); ya0 = fmaf(h0[4*i+0], cv.x, ya0);
                h0[4*i+1] = fmaf(t0, bv.y, h0[4*i+1]); yb0 = fmaf(h0[4*i+1], cv.y, yb0);
                h0[4*i+2] = fmaf(t0, bv.z, h0[4*i+2]); ya0 = fmaf(h0[4*i+2], cv.z, ya0);
                h0[4*i+3] = fmaf(t0, bv.w, h0[4*i+3]); yb0 = fmaf(h0[4*i+3], cv.w, yb0);
                h1[4*i+0] = fmaf(t1, bv.x, h1[4*i+0]); ya1 = fmaf(h1[4*i+0], cv.x, ya1);
                h1[4*i+1] = fmaf(t1, bv.y, h1[4*i+1]); yb1 = fmaf(h1[4*i+1], cv.y, yb1);
                h1[4*i+2] = fmaf(t1, bv.z, h1[4*i+2]); ya1 = fmaf(h1[4*i+2], cv.z, ya1);
                h1[4*i+3] = fmaf(t1, bv.w, h1[4*i+3]); yb1 = fmaf(h1[4*i+3], cv.w, yb1);
            }
            float yp0 = ya0 + yb0;
            float yp1 = ya1 + yb1;
            yp0 += __shfl_xor(yp0, 1);  yp1 += __shfl_xor(yp1, 1);
            yp0 += __shfl_xor(yp0, 2);  yp1 += __shfl_xor(yp1, 2);
            yp0 += __shfl_xor(yp0, 4);  yp1 += __shfl_xor(yp1, 4);
            if (q == 0) {
                size_t row = (base + c0 + s) * D_INNER + hh * HP;
                y[row + pl]      = fmaf(Dh, xv0, cc * yp0);
                y[row + pl + 32] = fmaf(Dh, xv1, cc * yp1);
            }
            if ((s & (RS - 1)) == RS - 1) {   // sub-chunk flush -> true state
                #pragma unroll
                for (int i = 0; i < 16; i++) { h0[i] *= cc; h1[i] *= cc; }
                cc = 1.f; rc = 1.f;
            }
        }
        __syncthreads();
    }
    if (seg < SSEG - 1) {
        float* F0 = F + (((size_t)bh * (SSEG - 1) + seg) * HP + pl) * D_STATE + (q << 4);
        float* F1 = F + (((size_t)bh * (SSEG - 1) + seg) * HP + pl + 32) * D_STATE + (q << 4);
        #pragma unroll
        for (int i = 0; i < 4; i++) {
            *(float4*)(F0 + 4 * i) = make_float4(h0[4*i], h0[4*i+1], h0[4*i+2], h0[4*i+3]);
            *(float4*)(F1 + 4 * i) = make_float4(h1[4*i], h1[4*i+1], h1[4*i+2], h1[4*i+3]);
        }
    }
}

// ---------------- Pass C (fused combine), 2p x 16n ----------------
__global__ __launch_bounds__(256, 4)
void k_seg_fix(const float* __restrict__ Cm, const float* __restrict__ cumdA,
               const float* __restrict__ F, float* __restrict__ y) {
    int blk = blockIdx.x;
    int bh = blk / (SSEG - 1);
    int seg = blk - bh * (SSEG - 1) + 1;
    int b = bh >> 3, hh = bh & 7;
    int tid = threadIdx.x;
    int q = tid & 7;
    int pl = tid >> 3;
    int q2 = q >> 1;
    float g0[16], g1[16];
    #pragma unroll
    for (int i = 0; i < 16; i++) { g0[i] = 0.f; g1[i] = 0.f; }
    for (int s = 0; s < seg; s++) {
        float P = cumdA[((size_t)b * LSEQ + (size_t)(s + 1) * TSEG - 1) * NH + hh];
        const float* F0 = F + (((size_t)bh * (SSEG - 1) + s) * HP + pl) * D_STATE + (q << 4);
        const float* F1 = F + (((size_t)bh * (SSEG - 1) + s) * HP + pl + 32) * D_STATE + (q << 4);
        #pragma unroll
        for (int i = 0; i < 4; i++) {
            float4 f0 = *(const float4*)(F0 + 4 * i);
            float4 f1 = *(const float4*)(F1 + 4 * i);
            g0[4*i+0] = fmaf(g0[4*i+0], P, f0.x);
            g0[4*i+1] = fmaf(g0[4*i+1], P, f0.y);
            g0[4*i+2] = fmaf(g0[4*i+2], P, f0.z);
            g0[4*i+3] = fmaf(g0[4*i+3], P, f0.w);
            g1[4*i+0] = fmaf(g1[4*i+0], P, f1.x);
            g1[4*i+1] = fmaf(g1[4*i+1], P, f1.y);
            g1[4*i+2] = fmaf(g1[4*i+2], P, f1.z);
            g1[4*i+3] = fmaf(g1[4*i+3], P, f1.w);
        }
    }
    __shared__ __align__(16) float sC[CT * 128];
    __shared__ float scd[CT];
    const size_t base = (size_t)b * LSEQ + (size_t)seg * TSEG;
    int col = tid & 127, half = tid >> 7;
    int sw = swz8(col);
    for (int c0 = 0; c0 < TSEG; c0 += CT) {
        #pragma unroll
        for (int u = 0; u < 8; u++) {
            int s = 2 * u + half;
            sC[s * 128 + sw] = Cm[(base + c0 + s) * D_STATE + col];
        }
        if (tid < CT) scd[tid] = cumdA[(base + c0 + tid) * NH + hh];
        __syncthreads();
        #pragma unroll 1
        for (int s = 0; s < CT; s++) {
            float ya0 = 0.f, yb0 = 0.f, ya1 = 0.f, yb1 = 0.f;
            #pragma unroll
            for (int i = 0; i < 4; i++) {
                int off = (q << 4) + (((i + q2) & 3) << 2);
                float4 cv = *(const float4*)&sC[s * 128 + off];
                ya0 = fmaf(g0[4*i+0], cv.x, ya0);
                yb0 = fmaf(g0[4*i+1], cv.y, yb0);
                ya0 = fmaf(g0[4*i+2], cv.z, ya0);
                yb0 = fmaf(g0[4*i+3], cv.w, yb0);
                ya1 = fmaf(g1[4*i+0], cv.x, ya1);
                yb1 = fmaf(g1[4*i+1], cv.y, yb1);
                ya1 = fmaf(g1[4*i+2], cv.z, ya1);
                yb1 = fmaf(g1[4*i+3], cv.w, yb1);
            }
            float yp0 = ya0 + yb0;
            float yp1 = ya1 + yb1;
            yp0 += __shfl_xor(yp0, 1);  yp1 += __shfl_xor(yp1, 1);
            yp0 += __shfl_xor(yp0, 2);  yp1 += __shfl_xor(yp1, 2);
            yp0 += __shfl_xor(yp0, 4);  yp1 += __shfl_xor(yp1, 4);
            if (q == 0) {
                size_t row = (base + c0 + s) * D_INNER + hh * HP;
                y[row + pl]      += scd[s] * yp0;
                y[row + pl + 32] += scd[s] * yp1;
            }
        }
        __syncthreads();
    }
}

// ---------------- gated RMSNorm (in-place on y) ----------------
__global__ __launch_bounds__(256)
void k_gate(float* __restrict__ y, const float* __restrict__ zbuf,
            const float* __restrict__ nw) {
    int m = blockIdx.x, tid = threadIdx.x;
    __shared__ float sred[8];
    float g[2];
    #pragma unroll
    for (int j = 0; j < 2; j++) {
        int d = tid + j * 256;
        float z = zbuf[(size_t)m * D_INNER + d];
        g[j] = y[(size_t)m * D_INNER + d] * silu_f(z);
    }
    float2 s = block_reduce2(g[0] * g[0] + g[1] * g[1], 0.f, sred);
    float r = rsqrtf(s.x * (1.f / D_INNER) + EPS);
    #pragma unroll
    for (int j = 0; j < 2; j++) {
        int d = tid + j * 256;
        y[(size_t)m * D_INNER + d] = g[j] * r * nw[d];
    }
}

// ---------------- h = LN(mo + h) ----------------
__global__ __launch_bounds__(256)
void k_addln(const float* __restrict__ mo, float* __restrict__ h,
             const float* __restrict__ w, const float* __restrict__ bias) {
    int m = blockIdx.x, o = threadIdx.x;
    __shared__ float sred[8];
    float v = mo[(size_t)m * D_MODEL + o] + h[(size_t)m * D_MODEL + o];
    float2 s = block_reduce2(v, v * v, sred);
    float mu = s.x * (1.f / D_MODEL);
    float var = s.y * (1.f / D_MODEL) - mu * mu;
    h[(size_t)m * D_MODEL + o] = (v - mu) * rsqrtf(var + EPS) * w[o] + bias[o];
}

// ---------------- pooled partial sums: 16 chunks of 64 tokens per batch ----------
__global__ __launch_bounds__(256)
void k_pool_part(const float* __restrict__ h, const int* __restrict__ len,
                 float* __restrict__ part) {
    int blk = blockIdx.x;
    int b = blk >> 4, ch = blk & 15;
    int d = threadIdx.x;
    int Lb = len[b];
    int l0 = ch * 64;
    int le = min(l0 + 64, Lb);
    float acc = 0.f;
    for (int l = l0; l < le; l++) acc += h[((size_t)b * LSEQ + l) * D_MODEL + d];
    part[(size_t)blk * D_MODEL + d] = acc;
}

// ---------------- final head: pooled mean + 14-way linear ----------------
__global__ __launch_bounds__(256)
void k_head(const float* __restrict__ part, const int* __restrict__ len,
            const float* __restrict__ hw, const float* __restrict__ hb,
            float* __restrict__ out) {
    int b = blockIdx.x, d = threadIdx.x;
    __shared__ float sp[D_MODEL];
    float a = 0.f;
    #pragma unroll
    for (int c = 0; c < 16; c++) a += part[(size_t)(b * 16 + c) * D_MODEL + d];
    sp[d] = a / (float)len[b];
    __syncthreads();
    if (d < N_CLS) {
        float o = hb[d];
        const float* wr = hw + (size_t)d * D_MODEL;
        #pragma unroll 8
        for (int k = 0; k < D_MODEL; k++) o = fmaf(sp[k], wr[k], o);
        out[b * N_CLS + d] = o;
    }
}

extern "C" void kernel_launch(void* const* d_in, const int* in_sizes, int n_in,
                              void* d_out, int out_size, void* d_ws, size_t ws_size,
                              hipStream_t stream) {
    const float* x      = (const float*)d_in[0];
    const float* in_w   = (const float*)d_in[1];
    const float* in_b   = (const float*)d_in[2];
    const float* lnin_w = (const float*)d_in[3];
    const float* lnin_b = (const float*)d_in[4];
    const float* inproj = (const float*)d_in[5];
    const float* conv_w = (const float*)d_in[6];
    const float* conv_b = (const float*)d_in[7];
    const float* dt_bias= (const float*)d_in[8];
    const float* A_log  = (const float*)d_in[9];
    const float* Dv     = (const float*)d_in[10];
    const float* norm_w = (const float*)d_in[11];
    const float* outp_w = (const float*)d_in[12];
    const float* ln_w   = (const float*)d_in[13];
    const float* ln_b   = (const float*)d_in[14];
    const float* head_w = (const float*)d_in[15];
    const float* head_b = (const float*)d_in[16];
    const int*   lengths= (const int*)d_in[17];
    float* out = (float*)d_out;

    float* ws    = (float*)d_ws;
    float* h     = ws;
    float* buf1  = h    + (size_t)NTOK * D_MODEL;
    float* xs    = buf1 + (size_t)NTOK * XBCDT;
    float* Bm    = xs   + (size_t)NTOK * D_INNER;
    float* Cm    = Bm   + (size_t)NTOK * D_STATE;
    float* dtv   = Cm   + (size_t)NTOK * D_STATE;
    float* cumdA = dtv  + (size_t)NTOK * NH;
    float* zbuf  = buf1;
    float* F     = buf1 + (size_t)NTOK * D_INNER;   // 3 segs * 256 bh * 8192 floats
    float* mo    = Bm;
    float* xp    = buf1;
    float* pre   = buf1 + (size_t)NTOK * 64;
    float* poolp = buf1;
    unsigned short* WP = (unsigned short*)(ws + WS_BASE);
    bool use_pk = (ws_size >= WS_NEED);

    dim3 gIO(D_MODEL / 128, NTOK / 128);
    dim3 g1a((XBCDT + 127) / 128, NTOK / 128);
    dim3 g1b(D_INNER / 128, NTOK / 128);
    int gScan = BSZ * NH * SSEG;
    int gFix  = BSZ * NH * (SSEG - 1);

    if (use_pk) {
        k_pack_weights<<<TOTPK / 256, 256, 0, stream>>>(in_w, inproj, outp_w, WP);
        k_pack_x<<<NTOK * 64 / 256, 256, 0, stream>>>(x, xp);
        k_gemm_as<<<gIO, 256, 0, stream>>>(xp, WP + IN_HI, WP + IN_LO, pre,
                                           NTOK, D_MODEL, 64);
        k_lnio<<<NTOK, 256, 0, stream>>>(pre, in_b, lnin_w, lnin_b, h);
        for (int i = 0; i < NL; i++) {
            const unsigned short* iph = WP + IP_HI + (size_t)i * PROJ * D_MODEL;
            const unsigned short* ipl = WP + IP_LO + (size_t)i * PROJ * D_MODEL;
            k_gemm_as<<<g1a, 256, 0, stream>>>(h, iph + (size_t)D_INNER * D_MODEL,
                                               ipl + (size_t)D_INNER * D_MODEL,
                                               buf1, NTOK, XBCDT, D_MODEL);
            k_conv<<<NTOK, 256, 0, stream>>>(buf1, conv_w + i * DCONV * CONV_CH,
                                             conv_b + i * CONV_CH, dt_bias + i * NH,
                                             xs, Bm, Cm, dtv);
            k_gemm_as<<<g1b, 256, 0, stream>>>(h, iph, ipl, zbuf, NTOK, D_INNER, D_MODEL);
            k_scan_seg<<<gScan, 256, 0, stream>>>(xs, Bm, Cm, dtv,
                                                  A_log + i * NH, Dv + i * NH,
                                                  xs, F, cumdA);
            k_seg_fix<<<gFix, 256, 0, stream>>>(Cm, cumdA, F, xs);
            k_gate<<<NTOK, 256, 0, stream>>>(xs, zbuf, norm_w + i * D_INNER);
            k_gemm_as<<<gIO, 256, 0, stream>>>(xs, WP + OP_HI + (size_t)i * D_MODEL * D_INNER,
                                               WP + OP_LO + (size_t)i * D_MODEL * D_INNER,
                                               mo, NTOK, D_MODEL, D_INNER);
            k_addln<<<NTOK, 256, 0, stream>>>(mo, h, ln_w + i * D_MODEL, ln_b + i * D_MODEL);
        }
    } else {
        float* wp = Bm;
        k_pack_x<<<NTOK * 64 / 256, 256, 0, stream>>>(x, xp);
        k_pack_w<<<64, 256, 0, stream>>>(in_w, wp);
        k_gemm_mfma<<<gIO, 256, 0, stream>>>(xp, wp, pre, NTOK, D_MODEL, 64);
        k_lnio<<<NTOK, 256, 0, stream>>>(pre, in_b, lnin_w, lnin_b, h);
        for (int i = 0; i < NL; i++) {
            const float* W = inproj + (size_t)i * PROJ * D_MODEL;
            k_gemm_mfma<<<g1a, 256, 0, stream>>>(h, W + (size_t)D_INNER * D_MODEL,
                                                 buf1, NTOK, XBCDT, D_MODEL);
            k_conv<<<NTOK, 256, 0, stream>>>(buf1, conv_w + i * DCONV * CONV_CH,
                                             conv_b + i * CONV_CH, dt_bias + i * NH,
                                             xs, Bm, Cm, dtv);
            k_gemm_mfma<<<g1b, 256, 0, stream>>>(h, W, zbuf, NTOK, D_INNER, D_MODEL);
            k_scan_seg<<<gScan, 256, 0, stream>>>(xs, Bm, Cm, dtv,
                                                  A_log + i * NH, Dv + i * NH,
                                                  xs, F, cumdA);
            k_seg_fix<<<gFix, 256, 0, stream>>>(Cm, cumdA, F, xs);
            k_gate<<<NTOK, 256, 0, stream>>>(xs, zbuf, norm_w + i * D_INNER);
            k_gemm_mfma<<<gIO, 256, 0, stream>>>(xs, outp_w + (size_t)i * D_MODEL * D_INNER,
                                                 mo, NTOK, D_MODEL, D_INNER);
            k_addln<<<NTOK, 256, 0, stream>>>(mo, h, ln_w + i * D_MODEL, ln_b + i * D_MODEL);
        }
    }

    k_pool_part<<<BSZ * 16, 256, 0, stream>>>(h, lengths, poolp);
    k_head<<<BSZ, 256, 0, stream>>>(poolp, lengths, head_w, head_b, out);
}

// Round 9
// 2608.166 us; speedup vs baseline: 2.6761x; 1.0239x over previous
//
#include <hip/hip_runtime.h>
#include <math.h>

#define D_IN 63
#define D_MODEL 256
#define N_CLS 14
#define NL 4
#define D_INNER 512
#define D_STATE 128
#define NH 8
#define HP 64
#define DCONV 4
#define CONV_CH 768
#define PROJ 1288
#define XBCDT 776
#define EPS 1e-5f
#define BSZ 32
#define LSEQ 1024
#define NTOK (BSZ*LSEQ)

#define SSEG 4
#define TSEG (LSEQ/SSEG)
#define CT 16
#define RS 8

// weight-pack region (ushort offsets)
#define S_IN   16384
#define S_IP   1318912
#define S_OP   524288
#define IN_HI  0
#define IN_LO  16384
#define IP_HI  32768
#define IP_LO  (32768 + S_IP)
#define OP_HI  (32768 + 2*S_IP)
#define OP_LO  (OP_HI + S_OP)
#define TOTPK  (S_IN + S_IP + S_OP)
#define WS_BASE ((size_t)NTOK * 1816)
#define WS_NEED ((WS_BASE + (size_t)TOTPK) * 4)

typedef __attribute__((ext_vector_type(8))) short bf16x8;
typedef __attribute__((ext_vector_type(4))) float f32x4;

__device__ __forceinline__ float silu_f(float x) { return x / (1.f + expf(-x)); }

__device__ __forceinline__ unsigned short f2bf(float x) {
    union { float f; unsigned u; } v; v.f = x;
    unsigned r = v.u + 0x7FFFu + ((v.u >> 16) & 1u);
    return (unsigned short)(r >> 16);
}
__device__ __forceinline__ float bf2f(unsigned short h) {
    union { float f; unsigned u; } v; v.u = ((unsigned)h) << 16; return v.f;
}

// swizzle for 8 groups of 16 values (proven 0-conflict): at inner iter i the
// 8 q-groups' float4 reads land on 8 disjoint bank quads.
__device__ __forceinline__ int swz8(int n) {
    int g = n >> 4, j = (n >> 2) & 3, e = n & 3;
    return (g << 4) + (((j + (g >> 1)) & 3) << 2) + e;
}

__device__ __forceinline__ float2 block_reduce2(float a, float b, float* sred) {
    #pragma unroll
    for (int off = 32; off >= 1; off >>= 1) {
        a += __shfl_xor(a, off);
        b += __shfl_xor(b, off);
    }
    int wid = threadIdx.x >> 6, lane = threadIdx.x & 63;
    if (lane == 0) { sred[wid * 2] = a; sred[wid * 2 + 1] = b; }
    __syncthreads();
    a = sred[0] + sred[2] + sred[4] + sred[6];
    b = sred[1] + sred[3] + sred[5] + sred[7];
    __syncthreads();
    return make_float2(a, b);
}

// ---------------- pack all weights to bf16 hi/lo planes ----------------
__global__ __launch_bounds__(256)
void k_pack_weights(const float* __restrict__ in_w, const float* __restrict__ inproj,
                    const float* __restrict__ outp, unsigned short* __restrict__ WP) {
    int idx = blockIdx.x * 256 + threadIdx.x;
    float v; int hi_off, lo_off;
    if (idx < S_IN) {
        int n = idx >> 6, k = idx & 63;
        v = (k < D_IN) ? in_w[n * D_IN + k] : 0.f;
        hi_off = IN_HI + idx; lo_off = IN_LO + idx;
    } else if (idx < S_IN + S_IP) {
        int j = idx - S_IN;
        v = inproj[j];
        hi_off = IP_HI + j; lo_off = IP_LO + j;
    } else {
        int j = idx - S_IN - S_IP;
        v = outp[j];
        hi_off = OP_HI + j; lo_off = OP_LO + j;
    }
    unsigned short h = f2bf(v);
    unsigned short l = f2bf(v - bf2f(h));
    WP[hi_off] = h; WP[lo_off] = l;
}

// ---------------- MFMA GEMM, A fp32 (in-kernel trunc split), B pre-packed ----------
#define LDKP 40
__global__ __launch_bounds__(256, 2)
void k_gemm_as(const float* __restrict__ A, const unsigned short* __restrict__ Bhg,
               const unsigned short* __restrict__ Blg, float* __restrict__ C,
               int M, int N, int K) {
    __shared__ unsigned short Ah[128][LDKP], Al[128][LDKP];
    __shared__ unsigned short Bh[128][LDKP], Bl[128][LDKP];
    int n0 = blockIdx.x * 128, m0 = blockIdx.y * 128;
    int tid = threadIdx.x;
    int srow = tid >> 1, sk = (tid & 1) * 16;
    int lane = tid & 63, wave = tid >> 6;
    int wm = (wave >> 1) * 64, wn = (wave & 1) * 64;
    int ln = lane & 15, quad = lane >> 4;
    f32x4 acc[4][4];
    #pragma unroll
    for (int i = 0; i < 4; i++)
        #pragma unroll
        for (int j = 0; j < 4; j++) acc[i][j] = (f32x4){0.f, 0.f, 0.f, 0.f};
    const float* Ap = A + (size_t)(m0 + srow) * K + sk;
    const unsigned short* Bhp = Bhg + (size_t)(n0 + srow) * K + sk;
    const unsigned short* Blp = Blg + (size_t)(n0 + srow) * K + sk;
    bool bval = (n0 + srow) < N;
    uint4 z4 = make_uint4(0u, 0u, 0u, 0u);
    for (int k0 = 0; k0 < K; k0 += 32) {
        float av[16];
        #pragma unroll
        for (int i = 0; i < 4; i++)
            *(float4*)&av[4 * i] = *(const float4*)(Ap + k0 + 4 * i);
        uint4 bh0 = bval ? *(const uint4*)(Bhp + k0) : z4;
        uint4 bh1 = bval ? *(const uint4*)(Bhp + k0 + 8) : z4;
        uint4 bl0 = bval ? *(const uint4*)(Blp + k0) : z4;
        uint4 bl1 = bval ? *(const uint4*)(Blp + k0 + 8) : z4;
        unsigned hp[8], lp[8];
        #pragma unroll
        for (int j = 0; j < 8; j++) {
            float a0 = av[2 * j], a1 = av[2 * j + 1];
            unsigned u0 = __float_as_uint(a0), u1 = __float_as_uint(a1);
            unsigned h0 = u0 & 0xFFFF0000u, h1 = u1 & 0xFFFF0000u;
            float r0 = a0 - __uint_as_float(h0);
            float r1 = a1 - __uint_as_float(h1);
            hp[j] = (u0 >> 16) | h1;
            lp[j] = (__float_as_uint(r0) >> 16) | (__float_as_uint(r1) & 0xFFFF0000u);
        }
        __syncthreads();
        *(uint4*)&Ah[srow][sk]     = *(uint4*)&hp[0];
        *(uint4*)&Ah[srow][sk + 8] = *(uint4*)&hp[4];
        *(uint4*)&Al[srow][sk]     = *(uint4*)&lp[0];
        *(uint4*)&Al[srow][sk + 8] = *(uint4*)&lp[4];
        *(uint4*)&Bh[srow][sk]     = bh0;
        *(uint4*)&Bh[srow][sk + 8] = bh1;
        *(uint4*)&Bl[srow][sk]     = bl0;
        *(uint4*)&Bl[srow][sk + 8] = bl1;
        __syncthreads();
        bf16x8 fah[4], fal[4], fbh[4], fbl[4];
        #pragma unroll
        for (int t = 0; t < 4; t++) {
            fah[t] = *(const bf16x8*)&Ah[wm + t * 16 + ln][quad * 8];
            fal[t] = *(const bf16x8*)&Al[wm + t * 16 + ln][quad * 8];
            fbh[t] = *(const bf16x8*)&Bh[wn + t * 16 + ln][quad * 8];
            fbl[t] = *(const bf16x8*)&Bl[wn + t * 16 + ln][quad * 8];
        }
        #pragma unroll
        for (int mt = 0; mt < 4; mt++)
            #pragma unroll
            for (int nt = 0; nt < 4; nt++) {
                acc[mt][nt] = __builtin_amdgcn_mfma_f32_16x16x32_bf16(fal[mt], fbh[nt], acc[mt][nt], 0, 0, 0);
                acc[mt][nt] = __builtin_amdgcn_mfma_f32_16x16x32_bf16(fah[mt], fbl[nt], acc[mt][nt], 0, 0, 0);
                acc[mt][nt] = __builtin_amdgcn_mfma_f32_16x16x32_bf16(fah[mt], fbh[nt], acc[mt][nt], 0, 0, 0);
            }
    }
    #pragma unroll
    for (int mt = 0; mt < 4; mt++)
        #pragma unroll
        for (int nt = 0; nt < 4; nt++) {
            int cn = n0 + wn + nt * 16 + ln;
            if (cn < N) {
                #pragma unroll
                for (int r = 0; r < 4; r++) {
                    int cm = m0 + wm + mt * 16 + quad * 4 + r;
                    C[(size_t)cm * N + cn] = acc[mt][nt][r];
                }
            }
        }
}

// ---------------- fallback GEMM: fp32 A and B, in-kernel split ----------------
__global__ __launch_bounds__(256, 2)
void k_gemm_mfma(const float* __restrict__ A, const float* __restrict__ B,
                 float* __restrict__ C, int M, int N, int K) {
    __shared__ unsigned short Ah[128][LDKP], Al[128][LDKP];
    __shared__ unsigned short Bh[128][LDKP], Bl[128][LDKP];
    int n0 = blockIdx.x * 128, m0 = blockIdx.y * 128;
    int tid = threadIdx.x;
    int srow = tid >> 1, sk = (tid & 1) * 16;
    int lane = tid & 63, wave = tid >> 6;
    int wm = (wave >> 1) * 64, wn = (wave & 1) * 64;
    int ln = lane & 15, quad = lane >> 4;
    f32x4 acc[4][4];
    #pragma unroll
    for (int i = 0; i < 4; i++)
        #pragma unroll
        for (int j = 0; j < 4; j++) acc[i][j] = (f32x4){0.f, 0.f, 0.f, 0.f};
    const float* Ap = A + (size_t)(m0 + srow) * K + sk;
    const float* Bp = B + (size_t)(n0 + srow) * K + sk;
    bool bval = (n0 + srow) < N;
    for (int k0 = 0; k0 < K; k0 += 32) {
        float av[16], bv[16];
        #pragma unroll
        for (int i = 0; i < 4; i++) {
            *(float4*)&av[4 * i] = *(const float4*)(Ap + k0 + 4 * i);
            *(float4*)&bv[4 * i] = bval ? *(const float4*)(Bp + k0 + 4 * i)
                                        : make_float4(0.f, 0.f, 0.f, 0.f);
        }
        __syncthreads();
        #pragma unroll
        for (int g = 0; g < 2; g++) {
            unsigned hiA[4], loA[4], hiB[4], loB[4];
            #pragma unroll
            for (int j = 0; j < 4; j++) {
                float a0 = av[8 * g + 2 * j], a1 = av[8 * g + 2 * j + 1];
                unsigned short h0 = f2bf(a0), h1 = f2bf(a1);
                unsigned short l0 = f2bf(a0 - bf2f(h0)), l1 = f2bf(a1 - bf2f(h1));
                hiA[j] = (unsigned)h0 | ((unsigned)h1 << 16);
                loA[j] = (unsigned)l0 | ((unsigned)l1 << 16);
                float b0 = bv[8 * g + 2 * j], b1 = bv[8 * g + 2 * j + 1];
                unsigned short g0 = f2bf(b0), g1 = f2bf(b1);
                unsigned short m0s = f2bf(b0 - bf2f(g0)), m1s = f2bf(b1 - bf2f(g1));
                hiB[j] = (unsigned)g0 | ((unsigned)g1 << 16);
                loB[j] = (unsigned)m0s | ((unsigned)m1s << 16);
            }
            *(uint4*)&Ah[srow][sk + 8 * g] = *(uint4*)hiA;
            *(uint4*)&Al[srow][sk + 8 * g] = *(uint4*)loA;
            *(uint4*)&Bh[srow][sk + 8 * g] = *(uint4*)hiB;
            *(uint4*)&Bl[srow][sk + 8 * g] = *(uint4*)loB;
        }
        __syncthreads();
        bf16x8 fah[4], fal[4], fbh[4], fbl[4];
        #pragma unroll
        for (int t = 0; t < 4; t++) {
            fah[t] = *(const bf16x8*)&Ah[wm + t * 16 + ln][quad * 8];
            fal[t] = *(const bf16x8*)&Al[wm + t * 16 + ln][quad * 8];
            fbh[t] = *(const bf16x8*)&Bh[wn + t * 16 + ln][quad * 8];
            fbl[t] = *(const bf16x8*)&Bl[wn + t * 16 + ln][quad * 8];
        }
        #pragma unroll
        for (int mt = 0; mt < 4; mt++)
            #pragma unroll
            for (int nt = 0; nt < 4; nt++) {
                acc[mt][nt] = __builtin_amdgcn_mfma_f32_16x16x32_bf16(fal[mt], fbh[nt], acc[mt][nt], 0, 0, 0);
                acc[mt][nt] = __builtin_amdgcn_mfma_f32_16x16x32_bf16(fah[mt], fbl[nt], acc[mt][nt], 0, 0, 0);
                acc[mt][nt] = __builtin_amdgcn_mfma_f32_16x16x32_bf16(fah[mt], fbh[nt], acc[mt][nt], 0, 0, 0);
            }
    }
    #pragma unroll
    for (int mt = 0; mt < 4; mt++)
        #pragma unroll
        for (int nt = 0; nt < 4; nt++) {
            int cn = n0 + wn + nt * 16 + ln;
            if (cn < N) {
                #pragma unroll
                for (int r = 0; r < 4; r++) {
                    int cm = m0 + wm + mt * 16 + quad * 4 + r;
                    C[(size_t)cm * N + cn] = acc[mt][nt][r];
                }
            }
        }
}

// ---------------- pack x / pack w ----------------
__global__ __launch_bounds__(256)
void k_pack_x(const float* __restrict__ x, float* __restrict__ xp) {
    size_t idx = (size_t)blockIdx.x * 256 + threadIdx.x;
    int k = (int)(idx & 63);
    size_t m = idx >> 6;
    xp[idx] = (k < D_IN) ? x[m * D_IN + k] : 0.f;
}
__global__ __launch_bounds__(256)
void k_pack_w(const float* __restrict__ w, float* __restrict__ wp) {
    int idx = blockIdx.x * 256 + threadIdx.x;
    int k = idx & 63, n = idx >> 6;
    wp[idx] = (k < D_IN) ? w[n * D_IN + k] : 0.f;
}

// ---------------- h = LN(pre + in_b) ----------------
__global__ __launch_bounds__(256)
void k_lnio(const float* __restrict__ pre, const float* __restrict__ bias,
            const float* __restrict__ gw, const float* __restrict__ gb,
            float* __restrict__ h) {
    int m = blockIdx.x, o = threadIdx.x;
    __shared__ float sred[8];
    float v = pre[(size_t)m * D_MODEL + o] + bias[o];
    float2 s = block_reduce2(v, v * v, sred);
    float mu = s.x * (1.f / D_MODEL);
    float var = s.y * (1.f / D_MODEL) - mu * mu;
    h[(size_t)m * D_MODEL + o] = (v - mu) * rsqrtf(var + EPS) * gw[o] + gb[o];
}

// ---------------- conv (causal depthwise k=4) + silu + dt ----------------
__global__ __launch_bounds__(256)
void k_conv(const float* __restrict__ xbc, const float* __restrict__ cw,
            const float* __restrict__ cb, const float* __restrict__ dtb,
            float* __restrict__ xs, float* __restrict__ Bm, float* __restrict__ Cm,
            float* __restrict__ dtv) {
    int m = blockIdx.x;
    int l = m & (LSEQ - 1);
    int tid = threadIdx.x;
    #pragma unroll
    for (int it = 0; it < 3; it++) {
        int c = tid + it * 256;
        float acc = cb[c];
        #pragma unroll
        for (int k = 0; k < DCONV; k++) {
            int lp = l - (DCONV - 1) + k;
            if (lp >= 0)
                acc = fmaf(cw[k * CONV_CH + c],
                           xbc[(size_t)(m - (DCONV - 1) + k) * XBCDT + c], acc);
        }
        float v = silu_f(acc);
        if (c < D_INNER) xs[(size_t)m * D_INNER + c] = v;
        else if (c < D_INNER + D_STATE) Bm[(size_t)m * D_STATE + (c - D_INNER)] = v;
        else Cm[(size_t)m * D_STATE + (c - D_INNER - D_STATE)] = v;
    }
    if (tid < NH) {
        float draw = xbc[(size_t)m * XBCDT + CONV_CH + tid] + dtb[tid];
        float dt = draw > 20.f ? draw : log1pf(expf(draw));
        dtv[m * NH + tid] = dt;
    }
}

// ---------------- Pass A: segment-local scan, 2p x 16n, staged-prefetch ----------
// Global->reg prefetch of the NEXT chunk's B/C/x/dt is issued right after the
// staging barrier; results are consumed one full chunk (~2k cycles) later, so
// the barrier never drains a cold global load.
__global__ __launch_bounds__(256, 4)
void k_scan_seg(const float* __restrict__ xs, const float* __restrict__ Bm,
                const float* __restrict__ Cm, const float* __restrict__ dtv,
                const float* __restrict__ Alog, const float* __restrict__ Dvec,
                float* __restrict__ y, float* __restrict__ F,
                float* __restrict__ cumdA) {
    int blk = blockIdx.x;
    int bh = blk >> 2;
    int seg = blk & (SSEG - 1);
    int b = bh >> 3, hh = bh & 7;
    int tid = threadIdx.x;
    int q = tid & 7;
    int pl = tid >> 3;              // 0..31
    int q2 = q >> 1;
    __shared__ __align__(16) float sBC[2 * CT * 128];
    __shared__ __align__(16) float sX[CT][HP];
    __shared__ float sdt[CT], sdA[CT], srdA[CT];
    float h0[16], h1[16];
    #pragma unroll
    for (int i = 0; i < 16; i++) { h0[i] = 0.f; h1[i] = 0.f; }
    float Dh = Dvec[hh];
    float Ahv = -expf(Alog[hh]);
    float c_run = 1.f;
    const size_t base = (size_t)b * LSEQ + (size_t)seg * TSEG;
    int col = tid & 127, half = tid >> 7;
    int sw = swz8(col);
    int xc = tid & 63, xh = tid >> 6;

    // staging registers (current chunk)
    float rB[8], rC[8], rX[4], rdt = 0.f;
    // prologue: load chunk 0
    #pragma unroll
    for (int u = 0; u < 8; u++) {
        size_t m = base + 2 * u + half;
        rB[u] = Bm[m * D_STATE + col];
        rC[u] = Cm[m * D_STATE + col];
    }
    #pragma unroll
    for (int u = 0; u < 4; u++)
        rX[u] = xs[(base + 4 * u + xh) * D_INNER + hh * HP + xc];
    if (tid < CT) rdt = dtv[(base + tid) * NH + hh];

    for (int c0 = 0; c0 < TSEG; c0 += CT) {
        // regs -> LDS
        #pragma unroll
        for (int u = 0; u < 8; u++) {
            int s = 2 * u + half;
            sBC[s * 128 + sw] = rB[u];
            sBC[(CT + s) * 128 + sw] = rC[u];
        }
        #pragma unroll
        for (int u = 0; u < 4; u++)
            sX[4 * u + xh][xc] = rX[u];
        if (tid < CT) {
            float e = fmaxf(rdt * Ahv, -37.f);
            sdt[tid] = rdt;
            sdA[tid] = expf(e);
            srdA[tid] = expf(-e);
        }
        __syncthreads();
        // prefetch NEXT chunk into regs (no wait: consumed next iteration)
        if (c0 + CT < TSEG) {
            size_t nb = base + c0 + CT;
            #pragma unroll
            for (int u = 0; u < 8; u++) {
                size_t m = nb + 2 * u + half;
                rB[u] = Bm[m * D_STATE + col];
                rC[u] = Cm[m * D_STATE + col];
            }
            #pragma unroll
            for (int u = 0; u < 4; u++)
                rX[u] = xs[(nb + 4 * u + xh) * D_INNER + hh * HP + xc];
            if (tid < CT) rdt = dtv[(nb + tid) * NH + hh];
        }
        if (tid == 0) {
            float cg = c_run;
            for (int s = 0; s < CT; s++) {
                cg *= sdA[s];
                cumdA[(base + c0 + s) * NH + hh] = cg;
            }
            c_run = cg;
        }
        float cc = 1.f, rc = 1.f;
        #pragma unroll
        for (int s = 0; s < CT; s++) {
            float dAl = sdA[s], dtl = sdt[s];
            float ccn = cc * dAl;
            if (ccn < 1e-18f) {          // rare, wave-uniform rebase
                #pragma unroll
                for (int i = 0; i < 16; i++) { h0[i] *= cc; h1[i] *= cc; }
                rc = srdA[s];
                ccn = dAl;
            } else {
                rc *= srdA[s];
            }
            cc = ccn;
            float xv0 = sX[s][pl];
            float xv1 = sX[s][pl + 32];
            float dr = dtl * rc;
            float t0 = dr * xv0, t1 = dr * xv1;
            float ya0 = 0.f, yb0 = 0.f, ya1 = 0.f, yb1 = 0.f;
            #pragma unroll
            for (int i = 0; i < 4; i++) {
                int off = (q << 4) + (((i + q2) & 3) << 2);
                float4 bv = *(const float4*)&sBC[s * 128 + off];
                float4 cv = *(const float4*)&sBC[(CT + s) * 128 + off];
                h0[4*i+0] = fmaf(t0, bv.x, h0[4*i+0]); ya0 = fmaf(h0[4*i+0], cv.x, ya0);
                h0[4*i+1] = fmaf(t0, bv.y, h0[4*i+1]); yb0 = fmaf(h0[4*i+1], cv.y, yb0);
                h0[4*i+2] = fmaf(t0, bv.z, h0[4*i+2]); ya0 = fmaf(h0[4*i+2], cv.z, ya0);
                h0[4*i+3] = fmaf(t0, bv.w, h0[4*i+3]); yb0 = fmaf(h0[4*i+3], cv.w, yb0);
                h1[4*i+0] = fmaf(t1, bv.x, h1[4*i+0]); ya1 = fmaf(h1[4*i+0], cv.x, ya1);
                h1[4*i+1] = fmaf(t1, bv.y, h1[4*i+1]); yb1 = fmaf(h1[4*i+1], cv.y, yb1);
                h1[4*i+2] = fmaf(t1, bv.z, h1[4*i+2]); ya1 = fmaf(h1[4*i+2], cv.z, ya1);
                h1[4*i+3] = fmaf(t1, bv.w, h1[4*i+3]); yb1 = fmaf(h1[4*i+3], cv.w, yb1);
            }
            float yp0 = ya0 + yb0;
            float yp1 = ya1 + yb1;
            yp0 += __shfl_xor(yp0, 1);  yp1 += __shfl_xor(yp1, 1);
            yp0 += __shfl_xor(yp0, 2);  yp1 += __shfl_xor(yp1, 2);
            yp0 += __shfl_xor(yp0, 4);  yp1 += __shfl_xor(yp1, 4);
            if (q == 0) {
                size_t row = (base + c0 + s) * D_INNER + hh * HP;
                y[row + pl]      = fmaf(Dh, xv0, cc * yp0);
                y[row + pl + 32] = fmaf(Dh, xv1, cc * yp1);
            }
            if ((s & (RS - 1)) == RS - 1) {   // sub-chunk flush -> true state
                #pragma unroll
                for (int i = 0; i < 16; i++) { h0[i] *= cc; h1[i] *= cc; }
                cc = 1.f; rc = 1.f;
            }
        }
        __syncthreads();
    }
    if (seg < SSEG - 1) {
        float* F0 = F + (((size_t)bh * (SSEG - 1) + seg) * HP + pl) * D_STATE + (q << 4);
        float* F1 = F + (((size_t)bh * (SSEG - 1) + seg) * HP + pl + 32) * D_STATE + (q << 4);
        #pragma unroll
        for (int i = 0; i < 4; i++) {
            *(float4*)(F0 + 4 * i) = make_float4(h0[4*i], h0[4*i+1], h0[4*i+2], h0[4*i+3]);
            *(float4*)(F1 + 4 * i) = make_float4(h1[4*i], h1[4*i+1], h1[4*i+2], h1[4*i+3]);
        }
    }
}

// ---------------- Pass C (fused combine), 2p x 16n, staged-prefetch ----------------
__global__ __launch_bounds__(256, 4)
void k_seg_fix(const float* __restrict__ Cm, const float* __restrict__ cumdA,
               const float* __restrict__ F, float* __restrict__ y) {
    int blk = blockIdx.x;
    int bh = blk / (SSEG - 1);
    int seg = blk - bh * (SSEG - 1) + 1;
    int b = bh >> 3, hh = bh & 7;
    int tid = threadIdx.x;
    int q = tid & 7;
    int pl = tid >> 3;
    int q2 = q >> 1;
    float g0[16], g1[16];
    #pragma unroll
    for (int i = 0; i < 16; i++) { g0[i] = 0.f; g1[i] = 0.f; }
    for (int s = 0; s < seg; s++) {
        float P = cumdA[((size_t)b * LSEQ + (size_t)(s + 1) * TSEG - 1) * NH + hh];
        const float* F0 = F + (((size_t)bh * (SSEG - 1) + s) * HP + pl) * D_STATE + (q << 4);
        const float* F1 = F + (((size_t)bh * (SSEG - 1) + s) * HP + pl + 32) * D_STATE + (q << 4);
        #pragma unroll
        for (int i = 0; i < 4; i++) {
            float4 f0 = *(const float4*)(F0 + 4 * i);
            float4 f1 = *(const float4*)(F1 + 4 * i);
            g0[4*i+0] = fmaf(g0[4*i+0], P, f0.x);
            g0[4*i+1] = fmaf(g0[4*i+1], P, f0.y);
            g0[4*i+2] = fmaf(g0[4*i+2], P, f0.z);
            g0[4*i+3] = fmaf(g0[4*i+3], P, f0.w);
            g1[4*i+0] = fmaf(g1[4*i+0], P, f1.x);
            g1[4*i+1] = fmaf(g1[4*i+1], P, f1.y);
            g1[4*i+2] = fmaf(g1[4*i+2], P, f1.z);
            g1[4*i+3] = fmaf(g1[4*i+3], P, f1.w);
        }
    }
    __shared__ __align__(16) float sC[CT * 128];
    __shared__ float scd[CT];
    const size_t base = (size_t)b * LSEQ + (size_t)seg * TSEG;
    int col = tid & 127, half = tid >> 7;
    int sw = swz8(col);
    float rC[8], rcd = 0.f;
    #pragma unroll
    for (int u = 0; u < 8; u++)
        rC[u] = Cm[(base + 2 * u + half) * D_STATE + col];
    if (tid < CT) rcd = cumdA[(base + tid) * NH + hh];

    for (int c0 = 0; c0 < TSEG; c0 += CT) {
        #pragma unroll
        for (int u = 0; u < 8; u++)
            sC[(2 * u + half) * 128 + sw] = rC[u];
        if (tid < CT) scd[tid] = rcd;
        __syncthreads();
        if (c0 + CT < TSEG) {
            size_t nb = base + c0 + CT;
            #pragma unroll
            for (int u = 0; u < 8; u++)
                rC[u] = Cm[(nb + 2 * u + half) * D_STATE + col];
            if (tid < CT) rcd = cumdA[(nb + tid) * NH + hh];
        }
        #pragma unroll 1
        for (int s = 0; s < CT; s++) {
            float ya0 = 0.f, yb0 = 0.f, ya1 = 0.f, yb1 = 0.f;
            #pragma unroll
            for (int i = 0; i < 4; i++) {
                int off = (q << 4) + (((i + q2) & 3) << 2);
                float4 cv = *(const float4*)&sC[s * 128 + off];
                ya0 = fmaf(g0[4*i+0], cv.x, ya0);
                yb0 = fmaf(g0[4*i+1], cv.y, yb0);
                ya0 = fmaf(g0[4*i+2], cv.z, ya0);
                yb0 = fmaf(g0[4*i+3], cv.w, yb0);
                ya1 = fmaf(g1[4*i+0], cv.x, ya1);
                yb1 = fmaf(g1[4*i+1], cv.y, yb1);
                ya1 = fmaf(g1[4*i+2], cv.z, ya1);
                yb1 = fmaf(g1[4*i+3], cv.w, yb1);
            }
            float yp0 = ya0 + yb0;
            float yp1 = ya1 + yb1;
            yp0 += __shfl_xor(yp0, 1);  yp1 += __shfl_xor(yp1, 1);
            yp0 += __shfl_xor(yp0, 2);  yp1 += __shfl_xor(yp1, 2);
            yp0 += __shfl_xor(yp0, 4);  yp1 += __shfl_xor(yp1, 4);
            if (q == 0) {
                size_t row = (base + c0 + s) * D_INNER + hh * HP;
                y[row + pl]      += scd[s] * yp0;
                y[row + pl + 32] += scd[s] * yp1;
            }
        }
        __syncthreads();
    }
}

// ---------------- gated RMSNorm (in-place on y) ----------------
__global__ __launch_bounds__(256)
void k_gate(float* __restrict__ y, const float* __restrict__ zbuf,
            const float* __restrict__ nw) {
    int m = blockIdx.x, tid = threadIdx.x;
    __shared__ float sred[8];
    float g[2];
    #pragma unroll
    for (int j = 0; j < 2; j++) {
        int d = tid + j * 256;
        float z = zbuf[(size_t)m * D_INNER + d];
        g[j] = y[(size_t)m * D_INNER + d] * silu_f(z);
    }
    float2 s = block_reduce2(g[0] * g[0] + g[1] * g[1], 0.f, sred);
    float r = rsqrtf(s.x * (1.f / D_INNER) + EPS);
    #pragma unroll
    for (int j = 0; j < 2; j++) {
        int d = tid + j * 256;
        y[(size_t)m * D_INNER + d] = g[j] * r * nw[d];
    }
}

// ---------------- h = LN(mo + h) ----------------
__global__ __launch_bounds__(256)
void k_addln(const float* __restrict__ mo, float* __restrict__ h,
             const float* __restrict__ w, const float* __restrict__ bias) {
    int m = blockIdx.x, o = threadIdx.x;
    __shared__ float sred[8];
    float v = mo[(size_t)m * D_MODEL + o] + h[(size_t)m * D_MODEL + o];
    float2 s = block_reduce2(v, v * v, sred);
    float mu = s.x * (1.f / D_MODEL);
    float var = s.y * (1.f / D_MODEL) - mu * mu;
    h[(size_t)m * D_MODEL + o] = (v - mu) * rsqrtf(var + EPS) * w[o] + bias[o];
}

// ---------------- pooled partial sums: 16 chunks of 64 tokens per batch ----------
__global__ __launch_bounds__(256)
void k_pool_part(const float* __restrict__ h, const int* __restrict__ len,
                 float* __restrict__ part) {
    int blk = blockIdx.x;
    int b = blk >> 4, ch = blk & 15;
    int d = threadIdx.x;
    int Lb = len[b];
    int l0 = ch * 64;
    int le = min(l0 + 64, Lb);
    float acc = 0.f;
    for (int l = l0; l < le; l++) acc += h[((size_t)b * LSEQ + l) * D_MODEL + d];
    part[(size_t)blk * D_MODEL + d] = acc;
}

// ---------------- final head: pooled mean + 14-way linear ----------------
__global__ __launch_bounds__(256)
void k_head(const float* __restrict__ part, const int* __restrict__ len,
            const float* __restrict__ hw, const float* __restrict__ hb,
            float* __restrict__ out) {
    int b = blockIdx.x, d = threadIdx.x;
    __shared__ float sp[D_MODEL];
    float a = 0.f;
    #pragma unroll
    for (int c = 0; c < 16; c++) a += part[(size_t)(b * 16 + c) * D_MODEL + d];
    sp[d] = a / (float)len[b];
    __syncthreads();
    if (d < N_CLS) {
        float o = hb[d];
        const float* wr = hw + (size_t)d * D_MODEL;
        #pragma unroll 8
        for (int k = 0; k < D_MODEL; k++) o = fmaf(sp[k], wr[k], o);
        out[b * N_CLS + d] = o;
    }
}

extern "C" void kernel_launch(void* const* d_in, const int* in_sizes, int n_in,
                              void* d_out, int out_size, void* d_ws, size_t ws_size,
                              hipStream_t stream) {
    const float* x      = (const float*)d_in[0];
    const float* in_w   = (const float*)d_in[1];
    const float* in_b   = (const float*)d_in[2];
    const float* lnin_w = (const float*)d_in[3];
    const float* lnin_b = (const float*)d_in[4];
    const float* inproj = (const float*)d_in[5];
    const float* conv_w = (const float*)d_in[6];
    const float* conv_b = (const float*)d_in[7];
    const float* dt_bias= (const float*)d_in[8];
    const float* A_log  = (const float*)d_in[9];
    const float* Dv     = (const float*)d_in[10];
    const float* norm_w = (const float*)d_in[11];
    const float* outp_w = (const float*)d_in[12];
    const float* ln_w   = (const float*)d_in[13];
    const float* ln_b   = (const float*)d_in[14];
    const float* head_w = (const float*)d_in[15];
    const float* head_b = (const float*)d_in[16];
    const int*   lengths= (const int*)d_in[17];
    float* out = (float*)d_out;

    float* ws    = (float*)d_ws;
    float* h     = ws;
    float* buf1  = h    + (size_t)NTOK * D_MODEL;
    float* xs    = buf1 + (size_t)NTOK * XBCDT;
    float* Bm    = xs   + (size_t)NTOK * D_INNER;
    float* Cm    = Bm   + (size_t)NTOK * D_STATE;
    float* dtv   = Cm   + (size_t)NTOK * D_STATE;
    float* cumdA = dtv  + (size_t)NTOK * NH;
    float* zbuf  = buf1;
    float* F     = buf1 + (size_t)NTOK * D_INNER;   // 3 segs * 256 bh * 8192 floats
    float* mo    = Bm;
    float* xp    = buf1;
    float* pre   = buf1 + (size_t)NTOK * 64;
    float* poolp = buf1;
    unsigned short* WP = (unsigned short*)(ws + WS_BASE);
    bool use_pk = (ws_size >= WS_NEED);

    dim3 gIO(D_MODEL / 128, NTOK / 128);
    dim3 g1a((XBCDT + 127) / 128, NTOK / 128);
    dim3 g1b(D_INNER / 128, NTOK / 128);
    int gScan = BSZ * NH * SSEG;
    int gFix  = BSZ * NH * (SSEG - 1);

    if (use_pk) {
        k_pack_weights<<<TOTPK / 256, 256, 0, stream>>>(in_w, inproj, outp_w, WP);
        k_pack_x<<<NTOK * 64 / 256, 256, 0, stream>>>(x, xp);
        k_gemm_as<<<gIO, 256, 0, stream>>>(xp, WP + IN_HI, WP + IN_LO, pre,
                                           NTOK, D_MODEL, 64);
        k_lnio<<<NTOK, 256, 0, stream>>>(pre, in_b, lnin_w, lnin_b, h);
        for (int i = 0; i < NL; i++) {
            const unsigned short* iph = WP + IP_HI + (size_t)i * PROJ * D_MODEL;
            const unsigned short* ipl = WP + IP_LO + (size_t)i * PROJ * D_MODEL;
            k_gemm_as<<<g1a, 256, 0, stream>>>(h, iph + (size_t)D_INNER * D_MODEL,
                                               ipl + (size_t)D_INNER * D_MODEL,
                                               buf1, NTOK, XBCDT, D_MODEL);
            k_conv<<<NTOK, 256, 0, stream>>>(buf1, conv_w + i * DCONV * CONV_CH,
                                             conv_b + i * CONV_CH, dt_bias + i * NH,
                                             xs, Bm, Cm, dtv);
            k_gemm_as<<<g1b, 256, 0, stream>>>(h, iph, ipl, zbuf, NTOK, D_INNER, D_MODEL);
            k_scan_seg<<<gScan, 256, 0, stream>>>(xs, Bm, Cm, dtv,
                                                  A_log + i * NH, Dv + i * NH,
                                                  xs, F, cumdA);
            k_seg_fix<<<gFix, 256, 0, stream>>>(Cm, cumdA, F, xs);
            k_gate<<<NTOK, 256, 0, stream>>>(xs, zbuf, norm_w + i * D_INNER);
            k_gemm_as<<<gIO, 256, 0, stream>>>(xs, WP + OP_HI + (size_t)i * D_MODEL * D_INNER,
                                               WP + OP_LO + (size_t)i * D_MODEL * D_INNER,
                                               mo, NTOK, D_MODEL, D_INNER);
            k_addln<<<NTOK, 256, 0, stream>>>(mo, h, ln_w + i * D_MODEL, ln_b + i * D_MODEL);
        }
    } else {
        float* wp = Bm;
        k_pack_x<<<NTOK * 64 / 256, 256, 0, stream>>>(x, xp);
        k_pack_w<<<64, 256, 0, stream>>>(in_w, wp);
        k_gemm_mfma<<<gIO, 256, 0, stream>>>(xp, wp, pre, NTOK, D_MODEL, 64);
        k_lnio<<<NTOK, 256, 0, stream>>>(pre, in_b, lnin_w, lnin_b, h);
        for (int i = 0; i < NL; i++) {
            const float* W = inproj + (size_t)i * PROJ * D_MODEL;
            k_gemm_mfma<<<g1a, 256, 0, stream>>>(h, W + (size_t)D_INNER * D_MODEL,
                                                 buf1, NTOK, XBCDT, D_MODEL);
            k_conv<<<NTOK, 256, 0, stream>>>(buf1, conv_w + i * DCONV * CONV_CH,
                                             conv_b + i * CONV_CH, dt_bias + i * NH,
                                             xs, Bm, Cm, dtv);
            k_gemm_mfma<<<g1b, 256, 0, stream>>>(h, W, zbuf, NTOK, D_INNER, D_MODEL);
            k_scan_seg<<<gScan, 256, 0, stream>>>(xs, Bm, Cm, dtv,
                                                  A_log + i * NH, Dv + i * NH,
                                                  xs, F, cumdA);
            k_seg_fix<<<gFix, 256, 0, stream>>>(Cm, cumdA, F, xs);
            k_gate<<<NTOK, 256, 0, stream>>>(xs, zbuf, norm_w + i * D_INNER);
            k_gemm_mfma<<<gIO, 256, 0, stream>>>(xs, outp_w + (size_t)i * D_MODEL * D_INNER,
                                                 mo, NTOK, D_MODEL, D_INNER);
            k_addln<<<NTOK, 256, 0, stream>>>(mo, h, ln_w + i * D_MODEL, ln_b + i * D_MODEL);
        }
    }

    k_pool_part<<<BSZ * 16, 256, 0, stream>>>(h, lengths, poolp);
    k_head<<<BSZ, 256, 0, stream>>>(poolp, lengths, head_w, head_b, out);
}